// Round 2
// baseline (3063.026 us; speedup 1.0000x reference)
//
#include <hip/hip_runtime.h>
#include <math.h>

typedef __attribute__((ext_vector_type(8))) short short8;
typedef __attribute__((ext_vector_type(4))) float float4v;

// ---------------- utility ----------------
__device__ __forceinline__ float lrelu02(float v){ return v > 0.f ? v : 0.2f*v; }

__device__ __forceinline__ unsigned short f2bf_rtn(float x){
  unsigned u = __float_as_uint(x);
  unsigned r = (u + 0x7fffu + ((u >> 16) & 1u)) >> 16;
  return (unsigned short)r;
}
__device__ __forceinline__ float bf2f(unsigned short h){
  return __uint_as_float(((unsigned)h) << 16);
}

__global__ void fill_int_k(int* p, int v, int n){
  int i = blockIdx.x*blockDim.x + threadIdx.x;
  if (i < n) p[i] = v;
}

__global__ void copy_int_k(int* dst, const int* src, int n){
  int i = blockIdx.x*blockDim.x + threadIdx.x;
  if (i < n) dst[i] = src[i];
}

// ---------------- CSR build (segment-by-dst) ----------------
__global__ void hist_dst_k(const int* __restrict__ ei, int E, int* deg){
  int e = blockIdx.x*blockDim.x + threadIdx.x;
  if (e < E) atomicAdd(&deg[ei[E + e]], 1);
}

__global__ void scan_k(const int* __restrict__ deg, int* rowptr, int n){
  __shared__ int s[1024];
  __shared__ int runS;
  int t = threadIdx.x;
  if (t == 0) runS = 0;
  __syncthreads();
  for (int base = 0; base < n; base += 1024){
    int v = (base + t < n) ? deg[base + t] : 0;
    s[t] = v; __syncthreads();
    for (int off = 1; off < 1024; off <<= 1){
      int x = (t >= off) ? s[t - off] : 0;
      __syncthreads();
      s[t] += x;
      __syncthreads();
    }
    int incl = s[t];
    int run = runS;
    if (base + t < n) rowptr[base + t] = run + incl - v;
    __syncthreads();
    if (t == 1023) runS = run + incl;
    __syncthreads();
  }
  if (t == 0) rowptr[n] = runS;
}

__global__ void fill_csr_k(const int* __restrict__ ei, int E, int* cursor, int* csr){
  int e = blockIdx.x*blockDim.x + threadIdx.x;
  if (e < E){
    int dst = ei[E + e];
    int pos = atomicAdd(&cursor[dst], 1);
    csr[pos] = ei[e];
  }
}

__global__ void self_loop_k(int* cursor, int* csr, int n){
  int i = blockIdx.x*blockDim.x + threadIdx.x;
  if (i < n){ int pos = atomicAdd(&cursor[i], 1); csr[pos] = i; }
}

// ---------------- attention score precompute ----------------
__global__ void make_as1_k(const float* __restrict__ W1, const float* __restrict__ a_src,
                           const float* __restrict__ a_dst, float* As, float* Ad){
  int idx = blockIdx.x*blockDim.x + threadIdx.x;
  if (idx < 78*10){
    int f = idx / 10, h = idx % 10;
    float ss = 0.f, sd = 0.f;
    for (int c = 0; c < 128; ++c){
      float w = W1[f*1280 + h*128 + c];
      ss += w * a_src[h*128 + c];
      sd += w * a_dst[h*128 + c];
    }
    As[idx] = ss; Ad[idx] = sd;
  }
}

__global__ void alpha1_k(const float* __restrict__ x, const float* __restrict__ As,
                         const float* __restrict__ Ad, float* as1, float* ad1, int n){
  int idx = blockIdx.x*blockDim.x + threadIdx.x;
  if (idx < n*10){
    int i = idx / 10, h = idx % 10;
    const float* xr = x + (long long)i*78;
    float ss = 0.f, sd = 0.f;
    for (int f = 0; f < 78; ++f){
      float xv = xr[f];
      ss += xv * As[f*10 + h];
      sd += xv * Ad[f*10 + h];
    }
    as1[idx] = ss; ad1[idx] = sd;
  }
}

__global__ void make_vs2_k(const float* __restrict__ W2, const float* __restrict__ a_src,
                           const float* __restrict__ a_dst, float* vs, float* vd){
  int k = blockIdx.x*blockDim.x + threadIdx.x;
  if (k < 1280){
    float ss = 0.f, sd = 0.f;
    for (int c = 0; c < 128; ++c){
      float w = W2[k*128 + c];
      ss += w * a_src[c]; sd += w * a_dst[c];
    }
    vs[k] = ss; vd[k] = sd;
  }
}

__global__ __launch_bounds__(256)
void alpha2_k(const float* __restrict__ h1e, const float* __restrict__ vs,
              const float* __restrict__ vd, float* as2, float* ad2, int n){
  int i = blockIdx.x, t = threadIdx.x;
  __shared__ float ss[256], sd[256];
  const float* r = h1e + (long long)i*1280;
  float ps = 0.f, pd = 0.f;
  for (int k = t; k < 1280; k += 256){ float v = r[k]; ps += v*vs[k]; pd += v*vd[k]; }
  ss[t] = ps; sd[t] = pd; __syncthreads();
  for (int o = 128; o > 0; o >>= 1){
    if (t < o){ ss[t] += ss[t+o]; sd[t] += sd[t+o]; }
    __syncthreads();
  }
  if (t == 0){ as2[i] = ss[0]; ad2[i] = sd[0]; }
}

// ---------------- GATConv1 softmax + aggregate in input space ----------------
__global__ __launch_bounds__(64)
void gat1_agg_k(const int* __restrict__ rowptr, const int* __restrict__ csr,
                const float* __restrict__ x, const float* __restrict__ as1,
                const float* __restrict__ ad1, float* __restrict__ y, int n){
  int i = blockIdx.x;
  int t = threadIdx.x;
  __shared__ float adi[10], mh[10], rden[10], wE[10], xs[78];
  int beg = rowptr[i], end = rowptr[i+1];
  if (t < 10){
    float a = ad1[i*10 + t];
    adi[t] = a;
    float m = -1e30f;
    for (int e = beg; e < end; ++e){
      int s = csr[e];
      m = fmaxf(m, lrelu02(as1[s*10 + t] + a));
    }
    float den = 0.f;
    for (int e = beg; e < end; ++e){
      int s = csr[e];
      den += expf(lrelu02(as1[s*10 + t] + a) - m);
    }
    mh[t] = m; rden[t] = 1.f/(den + 1e-16f);
  }
  __syncthreads();
  float acc[13];
  int hh[13], cc[13];
  #pragma unroll
  for (int k = 0; k < 13; ++k){
    acc[k] = 0.f;
    int j = t + 64*k;
    hh[k] = (j < 780) ? (j/78) : 0;
    cc[k] = (j < 780) ? (j%78) : 0;
  }
  for (int e = beg; e < end; ++e){
    int s = csr[e];
    if (t < 10) wE[t] = expf(lrelu02(as1[s*10 + t] + adi[t]) - mh[t]) * rden[t];
    for (int c = t; c < 78; c += 64) xs[c] = x[(long long)s*78 + c];
    __syncthreads();
    #pragma unroll
    for (int k = 0; k < 13; ++k){
      int j = t + 64*k;
      if (j < 780) acc[k] += wE[hh[k]] * xs[cc[k]];
    }
    __syncthreads();
  }
  #pragma unroll
  for (int k = 0; k < 13; ++k){
    int j = t + 64*k;
    if (j < 780) y[(long long)i*780 + j] = acc[k];
  }
}

// ---------------- GATConv2 softmax + aggregate (128-wide) ----------------
__global__ __launch_bounds__(64)
void gat2_agg_k(const int* __restrict__ rowptr, const int* __restrict__ csr,
                const float* __restrict__ h2, const float* __restrict__ as2,
                const float* __restrict__ ad2, const float* __restrict__ b2,
                float* __restrict__ h2e, int n){
  int i = blockIdx.x, t = threadIdx.x;
  int beg = rowptr[i], end = rowptr[i+1];
  float adi = ad2[i];
  float m = -1e30f;
  for (int e = beg; e < end; ++e) m = fmaxf(m, lrelu02(as2[csr[e]] + adi));
  float den = 0.f;
  for (int e = beg; e < end; ++e) den += expf(lrelu02(as2[csr[e]] + adi) - m);
  float rden = 1.f/(den + 1e-16f);
  float a0 = 0.f, a1 = 0.f;
  for (int e = beg; e < end; ++e){
    int s = csr[e];
    float w = expf(lrelu02(as2[s] + adi) - m) * rden;
    a0 += w * h2[(long long)s*128 + t];
    a1 += w * h2[(long long)s*128 + 64 + t];
  }
  float o0 = a0 + b2[t];      o0 = o0 > 0.f ? o0 : expm1f(o0);
  float o1 = a1 + b2[64 + t]; o1 = o1 > 0.f ? o1 : expm1f(o1);
  h2e[(long long)i*128 + t]      = o0;
  h2e[(long long)i*128 + 64 + t] = o1;
}

// ---------------- global max pool (batch is sorted) ----------------
__global__ __launch_bounds__(128)
void pool_k(const float* __restrict__ h2e, const int* __restrict__ batch, int n,
            float* __restrict__ pooled){
  int g = blockIdx.x, t = threadIdx.x;
  int lo = 0, hi = n;
  while (lo < hi){ int mid = (lo + hi) >> 1; if (batch[mid] < g) lo = mid + 1; else hi = mid; }
  int a = lo, b = n;
  while (a < b){ int mid = (a + b) >> 1; if (batch[mid] < g + 1) a = mid + 1; else b = mid; }
  float m = -1e30f;
  for (int i = lo; i < a; ++i) m = fmaxf(m, h2e[(long long)i*128 + t]);
  pooled[g*128 + t] = m;
}

// ---------------- row-wise L2 normalize ----------------
__global__ __launch_bounds__(256)
void l2norm_k(const float* __restrict__ in, float* __restrict__ out, int cols){
  int r = blockIdx.x, t = threadIdx.x;
  __shared__ float s[256];
  __shared__ float scaleS;
  const float* rp = in + (long long)r*cols;
  float p = 0.f;
  for (int k = t; k < cols; k += 256){ float v = rp[k]; p += v*v; }
  s[t] = p; __syncthreads();
  for (int o = 128; o > 0; o >>= 1){
    if (t < o) s[t] += s[t+o];
    __syncthreads();
  }
  if (t == 0) scaleS = 1.f / fmaxf(sqrtf(s[0]), 1e-12f);
  __syncthreads();
  float sc = scaleS;
  for (int k = t; k < cols; k += 256) out[(long long)r*cols + k] = rp[k]*sc;
}

__global__ void concat_k(const float* __restrict__ v1, const float* __restrict__ v2,
                         const float* __restrict__ c3, float* __restrict__ xcat, int B){
  int idx = blockIdx.x*blockDim.x + threadIdx.x;
  if (idx < B*512){
    int r = idx >> 9, c = idx & 511;
    float v;
    if (c < 128) v = v1[r*128 + c];
    else if (c < 256) v = v2[r*128 + (c - 128)];
    else v = c3[r*256 + (c - 256)];
    xcat[idx] = v;
  }
}

// ---------------- split-bf16 MFMA GEMM: C = act(A@W + bias) ----------------
// A: [M,K] lda, W: [K,N] ldw, C: [M,N] ldc. Batched via blockIdx.z.
// fp32-accurate: x = hi + lo (bf16 each); x*w = hi*hi + hi*lo + lo*hi (drop lo*lo ~2^-18).
// act: 0=none 1=relu 2=elu
#define TBM 64
#define TBN 64
#define TBK 32
#define LSTR 40   // LDS row stride in shorts (80B: 16B-aligned, 2-way-bank max on reads)

__device__ __forceinline__ int bswz(int n, int k){ return k ^ (((n >> 3) & 3) << 3); }

__global__ __launch_bounds__(256)
void gemm_mfma(const float* __restrict__ A, int lda, long long sA,
               const float* __restrict__ W, int ldw, long long sW,
               float* __restrict__ C, int ldc, long long sC,
               const float* __restrict__ bias, int sBias, int hasBias,
               int M, int Nc, int K, int act){
  int b = blockIdx.z;
  A += (long long)b * sA; W += (long long)b * sW; C += (long long)b * sC;
  if (hasBias) bias += (long long)b * sBias;

  __shared__ unsigned short Ah[TBM*LSTR], Al[TBM*LSTR];
  __shared__ unsigned short Bh[TBN*LSTR], Bl[TBN*LSTR];

  int tid  = threadIdx.x;
  int row0 = blockIdx.y * TBM, col0 = blockIdx.x * TBN;
  int lane = tid & 63, wave = tid >> 6;
  int wm = (wave & 1) * 32, wn = (wave >> 1) * 32;
  int lr = lane & 15, quad = lane >> 4, k0 = quad * 8;

  float4v acc[2][2];
  #pragma unroll
  for (int i = 0; i < 2; ++i)
    #pragma unroll
    for (int j = 0; j < 2; ++j)
      acc[i][j] = (float4v){0.f, 0.f, 0.f, 0.f};

  for (int kt = 0; kt < K; kt += TBK){
    // stage A tile [m][k] (hi/lo) — consecutive tid = consecutive k: coalesced & conflict-free
    #pragma unroll
    for (int idx = tid; idx < TBM*TBK; idx += 256){
      int m = idx >> 5, k = idx & 31;
      int gm = row0 + m, gk = kt + k;
      float v = (gm < M && gk < K) ? A[(long long)gm*lda + gk] : 0.f;
      unsigned short h = f2bf_rtn(v);
      Ah[m*LSTR + k] = h;
      Al[m*LSTR + k] = f2bf_rtn(v - bf2f(h));
    }
    // stage W tile transposed [n][k] with xor-swizzle (kills 8-way write conflict)
    #pragma unroll
    for (int idx = tid; idx < TBK*TBN; idx += 256){
      int k = idx >> 6, n = idx & 63;
      int gk = kt + k, gn = col0 + n;
      float v = (gk < K && gn < Nc) ? W[(long long)gk*ldw + gn] : 0.f;
      unsigned short h = f2bf_rtn(v);
      int c = bswz(n, k);
      Bh[n*LSTR + c] = h;
      Bl[n*LSTR + c] = f2bf_rtn(v - bf2f(h));
    }
    __syncthreads();

    short8 ahf[2], alf[2], bhf[2], blf[2];
    #pragma unroll
    for (int t = 0; t < 2; ++t){
      int am = wm + t*16 + lr;
      ahf[t] = *(const short8*)&Ah[am*LSTR + k0];
      alf[t] = *(const short8*)&Al[am*LSTR + k0];
      int bn = wn + t*16 + lr;
      int bc = bswz(bn, k0);
      bhf[t] = *(const short8*)&Bh[bn*LSTR + bc];
      blf[t] = *(const short8*)&Bl[bn*LSTR + bc];
    }
    #pragma unroll
    for (int i = 0; i < 2; ++i)
      #pragma unroll
      for (int j = 0; j < 2; ++j){
        acc[i][j] = __builtin_amdgcn_mfma_f32_16x16x32_bf16(alf[i], bhf[j], acc[i][j], 0, 0, 0);
        acc[i][j] = __builtin_amdgcn_mfma_f32_16x16x32_bf16(ahf[i], blf[j], acc[i][j], 0, 0, 0);
        acc[i][j] = __builtin_amdgcn_mfma_f32_16x16x32_bf16(ahf[i], bhf[j], acc[i][j], 0, 0, 0);
      }
    __syncthreads();
  }

  // epilogue: C/D layout col=lane&15, row=quad*4+reg
  #pragma unroll
  for (int j = 0; j < 2; ++j){
    int col = col0 + wn + j*16 + lr;
    if (col >= Nc) continue;
    float bv = hasBias ? bias[col] : 0.f;
    #pragma unroll
    for (int i = 0; i < 2; ++i){
      #pragma unroll
      for (int r = 0; r < 4; ++r){
        int row = row0 + wm + i*16 + quad*4 + r;
        if (row < M){
          float v = acc[i][j][r] + bv;
          if (act == 1) v = fmaxf(v, 0.f);
          else if (act == 2) v = v > 0.f ? v : expm1f(v);
          C[(long long)row*ldc + col] = v;
        }
      }
    }
  }
}

// ---------------- host launch ----------------
extern "C" void kernel_launch(void* const* d_in, const int* in_sizes, int n_in,
                              void* d_out, int out_size, void* d_ws, size_t ws_size,
                              hipStream_t stream){
  const float* x1     = (const float*)d_in[0];
  const int*   ei1    = (const int*)  d_in[1];
  const int*   batch1 = (const int*)  d_in[2];
  const float* x2     = (const float*)d_in[3];
  const int*   ei2    = (const int*)  d_in[4];
  const int*   batch2 = (const int*)  d_in[5];
  const float* cell   = (const float*)d_in[6];
  const float* W1     = (const float*)d_in[7];
  const float* a_src1 = (const float*)d_in[8];
  const float* a_dst1 = (const float*)d_in[9];
  const float* b1     = (const float*)d_in[10];
  const float* W2     = (const float*)d_in[11];
  const float* a_src2 = (const float*)d_in[12];
  const float* a_dst2 = (const float*)d_in[13];
  const float* b2     = (const float*)d_in[14];
  const float* Wg     = (const float*)d_in[15];
  const float* bg     = (const float*)d_in[16];
  const float* Wr1    = (const float*)d_in[17];
  const float* br1    = (const float*)d_in[18];
  const float* Wr2    = (const float*)d_in[19];
  const float* br2    = (const float*)d_in[20];
  const float* Wr3    = (const float*)d_in[21];
  const float* br3    = (const float*)d_in[22];
  const float* Wf1    = (const float*)d_in[23];
  const float* bf1    = (const float*)d_in[24];
  const float* Wf2    = (const float*)d_in[25];
  const float* bf2    = (const float*)d_in[26];
  const float* Wf3    = (const float*)d_in[27];
  const float* bf3    = (const float*)d_in[28];
  const float* Wo     = (const float*)d_in[29];
  const float* bo     = (const float*)d_in[30];
  float* out = (float*)d_out;
  (void)n_in; (void)out_size; (void)ws_size;

  const int N  = in_sizes[0] / 78;
  const int E  = in_sizes[1] / 2;
  const int Bg = in_sizes[6] / 954;

  char* wsb = (char*)d_ws;
  size_t off = 0;
  auto alloc = [&](size_t bytes)->void*{
    void* p = wsb + off; off += ((bytes + 255)/256)*256; return p;
  };
  float* y    = (float*)alloc((size_t)N*780*4);     // also hosts aliased buffers below
  float* h1e  = (float*)alloc((size_t)N*1280*4);
  float* as1  = (float*)alloc((size_t)N*10*4);
  float* ad1  = (float*)alloc((size_t)N*10*4);
  float* as2  = (float*)alloc((size_t)N*4);
  float* ad2  = (float*)alloc((size_t)N*4);
  float* AsB  = (float*)alloc(780*4);
  float* AdB  = (float*)alloc(780*4);
  float* vs   = (float*)alloc(1280*4);
  float* vd   = (float*)alloc(1280*4);
  int* deg    = (int*)alloc((size_t)N*4);
  int* rowptr = (int*)alloc((size_t)(N+1)*4);
  int* cursor = (int*)alloc((size_t)N*4);
  int* csr    = (int*)alloc((size_t)(E+N)*4);
  float* pooled = (float*)alloc((size_t)Bg*128*4);
  float* v1   = (float*)alloc((size_t)Bg*128*4);
  float* v2   = (float*)alloc((size_t)Bg*128*4);
  // aliases into y (lifetimes disjoint with y's use as conv1 aggregate):
  float* h2  = y;                       // N*128, written after y consumed by GEMM1
  float* h2e = y + 4*1024*1024;         // N*128
  float* cb  = y + 8*1024*1024;         // cell/final MLP buffers (after both branches)
  float* cn   = cb;
  float* c1   = cn  + (size_t)Bg*954;
  float* c2   = c1  + (size_t)Bg*2048;
  float* c3   = c2  + (size_t)Bg*512;
  float* xcat = c3  + (size_t)Bg*256;
  float* xcn  = xcat+ (size_t)Bg*512;
  float* t1   = xcn + (size_t)Bg*512;
  float* t2   = t1  + (size_t)Bg*1024;
  float* t3   = t2  + (size_t)Bg*512;

  auto gemm = [&](const float* A, int lda, long long sA_,
                  const float* Wm, int ldw, long long sW_,
                  float* C, int ldc, long long sC_,
                  const float* bias, int sBias,
                  int M, int Nc, int K, int batch, int act){
    dim3 grid((Nc + TBN - 1)/TBN, (M + TBM - 1)/TBM, batch);
    gemm_mfma<<<grid, 256, 0, stream>>>(A, lda, sA_, Wm, ldw, sW_, C, ldc, sC_,
                                        bias, sBias, bias != nullptr ? 1 : 0,
                                        M, Nc, K, act);
  };

  make_as1_k<<<(780 + 255)/256, 256, 0, stream>>>(W1, a_src1, a_dst1, AsB, AdB);
  make_vs2_k<<<(1280 + 255)/256, 256, 0, stream>>>(W2, a_src2, a_dst2, vs, vd);

  for (int br = 0; br < 2; ++br){
    const float* x   = br ? x2 : x1;
    const int* ei    = br ? ei2 : ei1;
    const int* batch = br ? batch2 : batch1;
    float* vout      = br ? v2 : v1;

    // CSR by dst (self-loops included via deg init = 1)
    fill_int_k<<<(N + 255)/256, 256, 0, stream>>>(deg, 1, N);
    hist_dst_k<<<(E + 255)/256, 256, 0, stream>>>(ei, E, deg);
    scan_k<<<1, 1024, 0, stream>>>(deg, rowptr, N);
    copy_int_k<<<(N + 255)/256, 256, 0, stream>>>(cursor, rowptr, N);
    fill_csr_k<<<(E + 255)/256, 256, 0, stream>>>(ei, E, cursor, csr);
    self_loop_k<<<(N + 255)/256, 256, 0, stream>>>(cursor, csr, N);

    // conv1
    alpha1_k<<<((N*10) + 255)/256, 256, 0, stream>>>(x, AsB, AdB, as1, ad1, N);
    gat1_agg_k<<<N, 64, 0, stream>>>(rowptr, csr, x, as1, ad1, y, N);
    // batched per-head GEMM: h1e[:, h*128: ] = elu( y[:, h*78: ] @ W1[:, h*128: ] + b1 )
    gemm(y, 780, 78, W1, 1280, 128, h1e, 1280, 128, b1, 128, N, 128, 78, 10, 2);

    // conv2
    alpha2_k<<<N, 256, 0, stream>>>(h1e, vs, vd, as2, ad2, N);
    gemm(h1e, 1280, 0, W2, 128, 0, h2, 128, 0, nullptr, 0, N, 128, 1280, 1, 0);
    gat2_agg_k<<<N, 64, 0, stream>>>(rowptr, csr, h2, as2, ad2, b2, h2e, N);

    // pool + linear
    pool_k<<<Bg, 128, 0, stream>>>(h2e, batch, N, pooled);
    gemm(pooled, 128, 0, Wg, 128, 0, vout, 128, 0, bg, 0, Bg, 128, 128, 1, 1);
  }

  // cell MLP
  l2norm_k<<<Bg, 256, 0, stream>>>(cell, cn, 954);
  gemm(cn, 954, 0, Wr1, 2048, 0, c1, 2048, 0, br1, 0, Bg, 2048, 954, 1, 1);
  gemm(c1, 2048, 0, Wr2, 512, 0, c2, 512, 0, br2, 0, Bg, 512, 2048, 1, 1);
  gemm(c2, 512, 0, Wr3, 256, 0, c3, 256, 0, br3, 0, Bg, 256, 512, 1, 1);

  // final MLP
  concat_k<<<((Bg*512) + 255)/256, 256, 0, stream>>>(v1, v2, c3, xcat, Bg);
  l2norm_k<<<Bg, 256, 0, stream>>>(xcat, xcn, 512);
  gemm(xcn, 512, 0, Wf1, 1024, 0, t1, 1024, 0, bf1, 0, Bg, 1024, 512, 1, 1);
  gemm(t1, 1024, 0, Wf2, 512, 0, t2, 512, 0, bf2, 0, Bg, 512, 1024, 1, 1);
  gemm(t2, 512, 0, Wf3, 128, 0, t3, 128, 0, bf3, 0, Bg, 128, 512, 1, 1);
  gemm(t3, 128, 0, Wo, 2, 0, out, 2, 0, bo, 0, Bg, 2, 128, 1, 0);
}

// Round 4
// 1251.021 us; speedup vs baseline: 2.4484x; 2.4484x over previous
//
#include <hip/hip_runtime.h>
#include <math.h>

typedef unsigned short ushort_t;
typedef __attribute__((ext_vector_type(8))) short short8;
typedef __attribute__((ext_vector_type(4))) float float4v;
typedef __attribute__((ext_vector_type(4))) unsigned short ushort4v;

#define MPAD 30016

// ---------------- utility ----------------
__device__ __forceinline__ float lrelu02(float v){ return v > 0.f ? v : 0.2f*v; }

__device__ __forceinline__ ushort_t f2bf(float x){
  unsigned u = __float_as_uint(x);
  return (ushort_t)((u + 0x7fffu + ((u >> 16) & 1u)) >> 16);
}
__device__ __forceinline__ float bf2f(ushort_t h){ return __uint_as_float(((unsigned)h) << 16); }

__device__ __forceinline__ void gll16(const void* g, void* l){
  __builtin_amdgcn_global_load_lds((const __attribute__((address_space(1))) void*)g,
                                   (__attribute__((address_space(3))) void*)l, 16, 0, 0);
}

__global__ void fill_int_k(int* p, int v, int n){
  int i = blockIdx.x*blockDim.x + threadIdx.x;
  if (i < n) p[i] = v;
}

__global__ void copy_int_k(int* dst, const int* src, int n){
  int i = blockIdx.x*blockDim.x + threadIdx.x;
  if (i < n) dst[i] = src[i];
}

// ---------------- CSR build (segment-by-dst) ----------------
__global__ void hist_dst_k(const int* __restrict__ ei, int E, int* deg){
  int e = blockIdx.x*blockDim.x + threadIdx.x;
  if (e < E) atomicAdd(&deg[ei[E + e]], 1);
}

__global__ void scan_k(const int* __restrict__ deg, int* rowptr, int n){
  __shared__ int s[1024];
  __shared__ int runS;
  int t = threadIdx.x;
  if (t == 0) runS = 0;
  __syncthreads();
  for (int base = 0; base < n; base += 1024){
    int v = (base + t < n) ? deg[base + t] : 0;
    s[t] = v; __syncthreads();
    for (int off = 1; off < 1024; off <<= 1){
      int x = (t >= off) ? s[t - off] : 0;
      __syncthreads();
      s[t] += x;
      __syncthreads();
    }
    int incl = s[t];
    int run = runS;
    if (base + t < n) rowptr[base + t] = run + incl - v;
    __syncthreads();
    if (t == 1023) runS = run + incl;
    __syncthreads();
  }
  if (t == 0) rowptr[n] = runS;
}

__global__ void fill_csr_k(const int* __restrict__ ei, int E, int* cursor, int* csr){
  int e = blockIdx.x*blockDim.x + threadIdx.x;
  if (e < E){
    int dst = ei[E + e];
    int pos = atomicAdd(&cursor[dst], 1);
    csr[pos] = ei[e];
  }
}

__global__ void self_loop_k(int* cursor, int* csr, int n){
  int i = blockIdx.x*blockDim.x + threadIdx.x;
  if (i < n){ int pos = atomicAdd(&cursor[i], 1); csr[pos] = i; }
}

// ---------------- attention score precompute ----------------
__global__ void make_as1_k(const float* __restrict__ W1, const float* __restrict__ a_src,
                           const float* __restrict__ a_dst, float* As, float* Ad){
  int idx = blockIdx.x*blockDim.x + threadIdx.x;
  if (idx < 78*10){
    int f = idx / 10, h = idx % 10;
    float ss = 0.f, sd = 0.f;
    for (int c = 0; c < 128; ++c){
      float w = W1[f*1280 + h*128 + c];
      ss += w * a_src[h*128 + c];
      sd += w * a_dst[h*128 + c];
    }
    As[idx] = ss; Ad[idx] = sd;
  }
}

__global__ void alpha1_k(const float* __restrict__ x, const float* __restrict__ As,
                         const float* __restrict__ Ad, float* as1, float* ad1, int n){
  int idx = blockIdx.x*blockDim.x + threadIdx.x;
  if (idx < n*10){
    int i = idx / 10, h = idx % 10;
    const float* xr = x + (long long)i*78;
    float ss = 0.f, sd = 0.f;
    for (int f = 0; f < 78; ++f){
      float xv = xr[f];
      ss += xv * As[f*10 + h];
      sd += xv * Ad[f*10 + h];
    }
    as1[idx] = ss; ad1[idx] = sd;
  }
}

__global__ void make_vs2_k(const float* __restrict__ W2, const float* __restrict__ a_src,
                           const float* __restrict__ a_dst, float* vs, float* vd){
  int k = blockIdx.x*blockDim.x + threadIdx.x;
  if (k < 1280){
    float ss = 0.f, sd = 0.f;
    for (int c = 0; c < 128; ++c){
      float w = W2[k*128 + c];
      ss += w * a_src[c]; sd += w * a_dst[c];
    }
    vs[k] = ss; vd[k] = sd;
  }
}

// alpha2 from split-bf16 h1e
__global__ __launch_bounds__(256)
void alpha2s_k(const ushort_t* __restrict__ hH, const ushort_t* __restrict__ hL,
               const float* __restrict__ vs, const float* __restrict__ vd,
               float* as2, float* ad2, int n){
  int i = blockIdx.x, t = threadIdx.x;
  __shared__ float ss[256], sd[256];
  size_t base = (size_t)i*1280;
  float ps = 0.f, pd = 0.f;
  for (int k = t; k < 1280; k += 256){
    float v = bf2f(hH[base + k]) + bf2f(hL[base + k]);
    ps += v*vs[k]; pd += v*vd[k];
  }
  ss[t] = ps; sd[t] = pd; __syncthreads();
  for (int o = 128; o > 0; o >>= 1){
    if (t < o){ ss[t] += ss[t+o]; sd[t] += sd[t+o]; }
    __syncthreads();
  }
  if (t == 0){ as2[i] = ss[0]; ad2[i] = sd[0]; }
}

// ---------------- GATConv1 softmax + aggregate in input space ----------------
// processes heads [h0, h0+5); writes split-bf16 y[hg][i][96] (f>=78 zero-padded)
__global__ __launch_bounds__(64)
void gat1_agg_k(const int* __restrict__ rowptr, const int* __restrict__ csr,
                const float* __restrict__ x, const float* __restrict__ as1,
                const float* __restrict__ ad1, ushort_t* __restrict__ yh,
                ushort_t* __restrict__ yl, int n, int h0){
  int i = blockIdx.x;
  int t = threadIdx.x;
  __shared__ float adi[5], mh[5], rden[5], wE[5], xs[78];
  int beg = rowptr[i], end = rowptr[i+1];
  if (t < 5){
    float a = ad1[i*10 + h0 + t];
    adi[t] = a;
    float m = -1e30f;
    for (int e = beg; e < end; ++e){
      int s = csr[e];
      m = fmaxf(m, lrelu02(as1[s*10 + h0 + t] + a));
    }
    float den = 0.f;
    for (int e = beg; e < end; ++e){
      int s = csr[e];
      den += expf(lrelu02(as1[s*10 + h0 + t] + a) - m);
    }
    mh[t] = m; rden[t] = 1.f/(den + 1e-16f);
  }
  __syncthreads();
  float acc[7];
  int hh[7], cc[7];
  #pragma unroll
  for (int k = 0; k < 7; ++k){
    acc[k] = 0.f;
    int j = t + 64*k;
    hh[k] = (j < 390) ? (j/78) : 0;
    cc[k] = (j < 390) ? (j%78) : 0;
  }
  for (int e = beg; e < end; ++e){
    int s = csr[e];
    if (t < 5) wE[t] = expf(lrelu02(as1[s*10 + h0 + t] + adi[t]) - mh[t]) * rden[t];
    for (int c = t; c < 78; c += 64) xs[c] = x[(long long)s*78 + c];
    __syncthreads();
    #pragma unroll
    for (int k = 0; k < 7; ++k){
      int j = t + 64*k;
      if (j < 390) acc[k] += wE[hh[k]] * xs[cc[k]];
    }
    __syncthreads();
  }
  #pragma unroll
  for (int k = 0; k < 7; ++k){
    int j = t + 64*k;
    if (j < 390){
      float v = acc[k];
      ushort_t hb = f2bf(v);
      size_t o = ((size_t)hh[k]*MPAD + i)*96 + cc[k];
      yh[o] = hb; yl[o] = f2bf(v - bf2f(hb));
    }
  }
  for (int p = t; p < 90; p += 64){
    int h = p/18, c = 78 + p%18;
    size_t o = ((size_t)h*MPAD + i)*96 + c;
    yh[o] = 0; yl[o] = 0;
  }
}

// ---------------- GATConv2 softmax + aggregate (128-wide) ----------------
__global__ __launch_bounds__(64)
void gat2_agg_k(const int* __restrict__ rowptr, const int* __restrict__ csr,
                const float* __restrict__ h2, const float* __restrict__ as2,
                const float* __restrict__ ad2, const float* __restrict__ b2,
                float* __restrict__ h2e, int n){
  int i = blockIdx.x, t = threadIdx.x;
  int beg = rowptr[i], end = rowptr[i+1];
  float adi = ad2[i];
  float m = -1e30f;
  for (int e = beg; e < end; ++e) m = fmaxf(m, lrelu02(as2[csr[e]] + adi));
  float den = 0.f;
  for (int e = beg; e < end; ++e) den += expf(lrelu02(as2[csr[e]] + adi) - m);
  float rden = 1.f/(den + 1e-16f);
  float a0 = 0.f, a1 = 0.f;
  for (int e = beg; e < end; ++e){
    int s = csr[e];
    float w = expf(lrelu02(as2[s] + adi) - m) * rden;
    a0 += w * h2[(long long)s*128 + t];
    a1 += w * h2[(long long)s*128 + 64 + t];
  }
  float o0 = a0 + b2[t];      o0 = o0 > 0.f ? o0 : expm1f(o0);
  float o1 = a1 + b2[64 + t]; o1 = o1 > 0.f ? o1 : expm1f(o1);
  h2e[(long long)i*128 + t]      = o0;
  h2e[(long long)i*128 + 64 + t] = o1;
}

// ---------------- global max pool (batch is sorted) → split bf16 ----------------
__global__ __launch_bounds__(128)
void pool_split_k(const float* __restrict__ h2e, const int* __restrict__ batch, int n,
                  ushort_t* __restrict__ ph, ushort_t* __restrict__ pl){
  int g = blockIdx.x, t = threadIdx.x;
  int lo = 0, hi = n;
  while (lo < hi){ int mid = (lo + hi) >> 1; if (batch[mid] < g) lo = mid + 1; else hi = mid; }
  int a = lo, b = n;
  while (a < b){ int mid = (a + b) >> 1; if (batch[mid] < g + 1) a = mid + 1; else b = mid; }
  float m = -1e30f;
  for (int i = lo; i < a; ++i) m = fmaxf(m, h2e[(long long)i*128 + t]);
  ushort_t h = f2bf(m);
  ph[g*128 + t] = h; pl[g*128 + t] = f2bf(m - bf2f(h));
}

// ---------------- row-wise L2 normalize → split bf16 (K-padded) ----------------
__global__ __launch_bounds__(256)
void l2norm_split_k(const float* __restrict__ in, int cols, int Kp,
                    ushort_t* __restrict__ oh, ushort_t* __restrict__ ol){
  int r = blockIdx.x, t = threadIdx.x;
  __shared__ float s[256];
  __shared__ float scaleS;
  const float* rp = in + (size_t)r*cols;
  float p = 0.f;
  for (int k = t; k < cols; k += 256){ float v = rp[k]; p += v*v; }
  s[t] = p; __syncthreads();
  for (int o = 128; o > 0; o >>= 1){
    if (t < o) s[t] += s[t+o];
    __syncthreads();
  }
  if (t == 0) scaleS = 1.f / fmaxf(sqrtf(s[0]), 1e-12f);
  __syncthreads();
  float sc = scaleS;
  for (int k = t; k < Kp; k += 256){
    float v = (k < cols) ? rp[k]*sc : 0.f;
    ushort_t h = f2bf(v);
    size_t o2 = (size_t)r*Kp + k;
    oh[o2] = h; ol[o2] = f2bf(v - bf2f(h));
  }
}

__global__ void concat_k(const float* __restrict__ v1, const float* __restrict__ v2,
                         const float* __restrict__ c3, float* __restrict__ xcat, int B){
  int idx = blockIdx.x*blockDim.x + threadIdx.x;
  if (idx < B*512){
    int r = idx >> 9, c = idx & 511;
    float v;
    if (c < 128) v = v1[r*128 + c];
    else if (c < 256) v = v2[r*128 + (c - 128)];
    else v = c3[r*256 + (c - 256)];
    xcat[idx] = v;
  }
}

// ---------------- weight transpose + split: Bt[n][k] = W[k][n] ----------------
__global__ void split_bt_k(const float* __restrict__ W, int ldw, int colStride,
                           int N, int K, int Np, int Kp,
                           ushort_t* __restrict__ dh, ushort_t* __restrict__ dl, int total){
  int idx = blockIdx.x*blockDim.x + threadIdx.x;
  if (idx >= total) return;
  int n  = idx % Np;
  int r  = idx / Np;
  int k4 = r % (Kp >> 2);
  int b  = r / (Kp >> 2);
  size_t o = ((size_t)b*Np + n)*Kp + (size_t)k4*4;
  ushort4v hv, lv;
  #pragma unroll
  for (int kk = 0; kk < 4; ++kk){
    int k = k4*4 + kk;
    float v = (n < N && k < K) ? W[(size_t)k*ldw + (size_t)b*colStride + n] : 0.f;
    ushort_t h = f2bf(v);
    hv[kk] = h; lv[kk] = f2bf(v - bf2f(h));
  }
  *(ushort4v*)&dh[o] = hv;
  *(ushort4v*)&dl[o] = lv;
}

// ---------------- split-bf16 MFMA GEMM (pre-converted inputs) ----------------
// A (hi/lo): [M x K] bf16 row-major (lda = padded K, mult of 8)
// Bt (hi/lo): [N x K] bf16 row-major (ldb mult of 8) — i.e. W transposed
// C = act(A@W + bias); outMode 0: fp32 C; 1: split bf16 Ch/Cl
__global__ __launch_bounds__(256)
void gemm_split(const ushort_t* __restrict__ Ahp, const ushort_t* __restrict__ Alp, int lda, long long sA,
                const ushort_t* __restrict__ Bhp, const ushort_t* __restrict__ Blp, int ldb, long long sB,
                float* __restrict__ C, ushort_t* __restrict__ Ch, ushort_t* __restrict__ Cl,
                int ldc, long long sC,
                const float* __restrict__ bias, int sBias,
                int M, int Nc, int K, int act, int outMode){
  int b = blockIdx.z;
  Ahp += (long long)b*sA; Alp += (long long)b*sA;
  Bhp += (long long)b*sB; Blp += (long long)b*sB;
  long long cOff = (long long)b*sC;

  __shared__ ushort_t sAh[2048], sAl[2048], sBh[2048], sBl[2048];  // 64 rows x 32 k each

  int tid = threadIdx.x, lane = tid & 63, wave = tid >> 6;
  int row0 = blockIdx.y*64, col0 = blockIdx.x*64;
  int wm = (wave & 1)*32, wn = (wave >> 1)*32;
  int lr = lane & 15, quad = lane >> 4;

  // staging: wave w covers rows w*16..w*16+15; lane l -> row w*16+(l>>2), 16B chunk (l&3)
  int srow = wave*16 + (lane >> 2);
  int skc  = (lane & 3)*8;
  const ushort_t* gAh = Ahp + (long long)(row0 + srow)*lda + skc;
  const ushort_t* gAl = Alp + (long long)(row0 + srow)*lda + skc;
  const ushort_t* gBh = Bhp + (long long)(col0 + srow)*ldb + skc;
  const ushort_t* gBl = Blp + (long long)(col0 + srow)*ldb + skc;
  ushort_t* lAh = &sAh[wave*512];
  ushort_t* lAl = &sAl[wave*512];
  ushort_t* lBh = &sBh[wave*512];
  ushort_t* lBl = &sBl[wave*512];

  float4v acc[2][2];
  #pragma unroll
  for (int i = 0; i < 2; ++i)
    #pragma unroll
    for (int j = 0; j < 2; ++j)
      acc[i][j] = (float4v){0.f, 0.f, 0.f, 0.f};

  for (int kt = 0; kt < K; kt += 32){
    gll16(gAh + kt, lAh);
    gll16(gAl + kt, lAl);
    gll16(gBh + kt, lBh);
    gll16(gBl + kt, lBl);
    __syncthreads();

    short8 ah[2], al[2], bh[2], bl[2];
    #pragma unroll
    for (int t2 = 0; t2 < 2; ++t2){
      ah[t2] = *(const short8*)&sAh[(wm + t2*16 + lr)*32 + quad*8];
      al[t2] = *(const short8*)&sAl[(wm + t2*16 + lr)*32 + quad*8];
      bh[t2] = *(const short8*)&sBh[(wn + t2*16 + lr)*32 + quad*8];
      bl[t2] = *(const short8*)&sBl[(wn + t2*16 + lr)*32 + quad*8];
    }
    #pragma unroll
    for (int i = 0; i < 2; ++i)
      #pragma unroll
      for (int j = 0; j < 2; ++j){
        acc[i][j] = __builtin_amdgcn_mfma_f32_16x16x32_bf16(al[i], bh[j], acc[i][j], 0, 0, 0);
        acc[i][j] = __builtin_amdgcn_mfma_f32_16x16x32_bf16(ah[i], bl[j], acc[i][j], 0, 0, 0);
        acc[i][j] = __builtin_amdgcn_mfma_f32_16x16x32_bf16(ah[i], bh[j], acc[i][j], 0, 0, 0);
      }
    __syncthreads();
  }

  // epilogue: C/D layout col=lane&15, row=quad*4+reg
  #pragma unroll
  for (int j = 0; j < 2; ++j){
    int col = col0 + wn + j*16 + lr;
    if (col >= Nc) continue;
    float bv = bias ? bias[(long long)b*sBias + col] : 0.f;
    #pragma unroll
    for (int i = 0; i < 2; ++i){
      #pragma unroll
      for (int r = 0; r < 4; ++r){
        int row = row0 + wm + i*16 + quad*4 + r;
        if (row >= M) continue;
        float v = acc[i][j][r] + bv;
        if (act == 1) v = fmaxf(v, 0.f);
        else if (act == 2) v = v > 0.f ? v : expm1f(v);
        long long o = cOff + (long long)row*ldc + col;
        if (outMode == 0) C[o] = v;
        else { ushort_t h = f2bf(v); Ch[o] = h; Cl[o] = f2bf(v - bf2f(h)); }
      }
    }
  }
}

// ---------------- host launch ----------------
extern "C" void kernel_launch(void* const* d_in, const int* in_sizes, int n_in,
                              void* d_out, int out_size, void* d_ws, size_t ws_size,
                              hipStream_t stream){
  const float* x1     = (const float*)d_in[0];
  const int*   ei1    = (const int*)  d_in[1];
  const int*   batch1 = (const int*)  d_in[2];
  const float* x2     = (const float*)d_in[3];
  const int*   ei2    = (const int*)  d_in[4];
  const int*   batch2 = (const int*)  d_in[5];
  const float* cell   = (const float*)d_in[6];
  const float* W1     = (const float*)d_in[7];
  const float* a_src1 = (const float*)d_in[8];
  const float* a_dst1 = (const float*)d_in[9];
  const float* b1     = (const float*)d_in[10];
  const float* W2     = (const float*)d_in[11];
  const float* a_src2 = (const float*)d_in[12];
  const float* a_dst2 = (const float*)d_in[13];
  const float* b2     = (const float*)d_in[14];
  const float* Wg     = (const float*)d_in[15];
  const float* bg     = (const float*)d_in[16];
  const float* Wr1    = (const float*)d_in[17];
  const float* br1    = (const float*)d_in[18];
  const float* Wr2    = (const float*)d_in[19];
  const float* br2    = (const float*)d_in[20];
  const float* Wr3    = (const float*)d_in[21];
  const float* br3    = (const float*)d_in[22];
  const float* Wf1    = (const float*)d_in[23];
  const float* bf1    = (const float*)d_in[24];
  const float* Wf2    = (const float*)d_in[25];
  const float* bf2    = (const float*)d_in[26];
  const float* Wf3    = (const float*)d_in[27];
  const float* bf3    = (const float*)d_in[28];
  const float* Wo     = (const float*)d_in[29];
  const float* bo     = (const float*)d_in[30];
  float* out = (float*)d_out;
  (void)n_in; (void)out_size; (void)ws_size;

  const int N  = in_sizes[0] / 78;
  const int E  = in_sizes[1] / 2;
  const int Bg = in_sizes[6] / 954;

  char* wsb = (char*)d_ws;
  size_t off = 0;
  auto alloc = [&](size_t bytes)->char*{
    char* p = wsb + off; off += ((bytes + 255)/256)*256; return p;
  };

  // big persistent buffers
  ushort_t* h1eh = (ushort_t*)alloc((size_t)MPAD*1280*2);
  ushort_t* h1el = (ushort_t*)alloc((size_t)MPAD*1280*2);
  // Y region: yh/yl (5-head group) during conv1; h2/h2e during conv2; MLP buffers after
  char* Yb = alloc((size_t)5*MPAD*96*2*2);
  ushort_t* yh = (ushort_t*)Yb;
  ushort_t* yl = yh + (size_t)5*MPAD*96;
  float* h2  = (float*)Yb;
  float* h2e = (float*)(Yb + (size_t)MPAD*128*4);
  size_t yoff = 0;
  auto yalloc = [&](size_t bytes)->char*{
    char* p = Yb + yoff; yoff += ((bytes + 255)/256)*256; return p;
  };
  ushort_t* cnh  = (ushort_t*)yalloc((size_t)Bg*960*2);
  ushort_t* cnl  = (ushort_t*)yalloc((size_t)Bg*960*2);
  ushort_t* c1h  = (ushort_t*)yalloc((size_t)Bg*2048*2);
  ushort_t* c1l  = (ushort_t*)yalloc((size_t)Bg*2048*2);
  ushort_t* c2h  = (ushort_t*)yalloc((size_t)Bg*512*2);
  ushort_t* c2l  = (ushort_t*)yalloc((size_t)Bg*512*2);
  float*    c3   = (float*)   yalloc((size_t)Bg*256*4);
  float*    xcat = (float*)   yalloc((size_t)Bg*512*4);
  ushort_t* xcnh = (ushort_t*)yalloc((size_t)Bg*512*2);
  ushort_t* xcnl = (ushort_t*)yalloc((size_t)Bg*512*2);
  ushort_t* t1h  = (ushort_t*)yalloc((size_t)Bg*1024*2);
  ushort_t* t1l  = (ushort_t*)yalloc((size_t)Bg*1024*2);
  ushort_t* t2h  = (ushort_t*)yalloc((size_t)Bg*512*2);
  ushort_t* t2l  = (ushort_t*)yalloc((size_t)Bg*512*2);
  ushort_t* t3h  = (ushort_t*)yalloc((size_t)Bg*128*2);
  ushort_t* t3l  = (ushort_t*)yalloc((size_t)Bg*128*2);

  // transposed+split weights
  ushort_t* W1th = (ushort_t*)alloc((size_t)10*128*96*2);
  ushort_t* W1tl = (ushort_t*)alloc((size_t)10*128*96*2);
  ushort_t* W2th = (ushort_t*)alloc((size_t)128*1280*2);
  ushort_t* W2tl = (ushort_t*)alloc((size_t)128*1280*2);
  ushort_t* Wgth = (ushort_t*)alloc((size_t)128*128*2);
  ushort_t* Wgtl = (ushort_t*)alloc((size_t)128*128*2);
  ushort_t* Wr1th= (ushort_t*)alloc((size_t)2048*960*2);
  ushort_t* Wr1tl= (ushort_t*)alloc((size_t)2048*960*2);
  ushort_t* Wr2th= (ushort_t*)alloc((size_t)512*2048*2);
  ushort_t* Wr2tl= (ushort_t*)alloc((size_t)512*2048*2);
  ushort_t* Wr3th= (ushort_t*)alloc((size_t)256*512*2);
  ushort_t* Wr3tl= (ushort_t*)alloc((size_t)256*512*2);
  ushort_t* Wf1th= (ushort_t*)alloc((size_t)1024*512*2);
  ushort_t* Wf1tl= (ushort_t*)alloc((size_t)1024*512*2);
  ushort_t* Wf2th= (ushort_t*)alloc((size_t)512*1024*2);
  ushort_t* Wf2tl= (ushort_t*)alloc((size_t)512*1024*2);
  ushort_t* Wf3th= (ushort_t*)alloc((size_t)128*512*2);
  ushort_t* Wf3tl= (ushort_t*)alloc((size_t)128*512*2);
  ushort_t* Woth = (ushort_t*)alloc((size_t)64*128*2);
  ushort_t* Wotl = (ushort_t*)alloc((size_t)64*128*2);

  float* as1  = (float*)alloc((size_t)N*10*4);
  float* ad1  = (float*)alloc((size_t)N*10*4);
  float* as2  = (float*)alloc((size_t)N*4);
  float* ad2  = (float*)alloc((size_t)N*4);
  float* AsB  = (float*)alloc(780*4);
  float* AdB  = (float*)alloc(780*4);
  float* vs   = (float*)alloc(1280*4);
  float* vd   = (float*)alloc(1280*4);
  int* deg    = (int*)alloc((size_t)N*4);
  int* rowptr = (int*)alloc((size_t)(N+1)*4);
  int* cursor = (int*)alloc((size_t)N*4);
  int* csr    = (int*)alloc((size_t)(E+N)*4);
  ushort_t* pooledh = (ushort_t*)alloc((size_t)Bg*128*2);
  ushort_t* pooledl = (ushort_t*)alloc((size_t)Bg*128*2);
  float* v1   = (float*)alloc((size_t)Bg*128*4);
  float* v2   = (float*)alloc((size_t)Bg*128*4);

  auto gemm = [&](const ushort_t* Ah_, const ushort_t* Al_, int lda, long long sA_,
                  const ushort_t* Bh_, const ushort_t* Bl_, int ldb, long long sB_,
                  float* C_, ushort_t* Ch_, ushort_t* Cl_, int ldc, long long sC_,
                  const float* bias_, int sBias_, int M_, int N_, int K_, int batch_,
                  int act_, int mode_){
    dim3 grid((N_ + 63)/64, (M_ + 63)/64, batch_);
    gemm_split<<<grid, 256, 0, stream>>>(Ah_, Al_, lda, sA_, Bh_, Bl_, ldb, sB_,
                                         C_, Ch_, Cl_, ldc, sC_, bias_, sBias_,
                                         M_, N_, K_, act_, mode_);
  };
  auto splitBt = [&](const float* W_, int ldw_, int colStride_, int N_, int K_,
                     int Np_, int Kp_, ushort_t* dh_, ushort_t* dl_, int batch_){
    int total = batch_*Np_*(Kp_ >> 2);
    split_bt_k<<<(total + 255)/256, 256, 0, stream>>>(W_, ldw_, colStride_, N_, K_,
                                                      Np_, Kp_, dh_, dl_, total);
  };

  // ---- weight prep (once per launch) ----
  splitBt(W1, 1280, 128, 128, 78, 128, 96, W1th, W1tl, 10);
  splitBt(W2, 128, 0, 128, 1280, 128, 1280, W2th, W2tl, 1);
  splitBt(Wg, 128, 0, 128, 128, 128, 128, Wgth, Wgtl, 1);
  splitBt(Wr1, 2048, 0, 2048, 954, 2048, 960, Wr1th, Wr1tl, 1);
  splitBt(Wr2, 512, 0, 512, 2048, 512, 2048, Wr2th, Wr2tl, 1);
  splitBt(Wr3, 256, 0, 256, 512, 256, 512, Wr3th, Wr3tl, 1);
  splitBt(Wf1, 1024, 0, 1024, 512, 1024, 512, Wf1th, Wf1tl, 1);
  splitBt(Wf2, 512, 0, 512, 1024, 512, 1024, Wf2th, Wf2tl, 1);
  splitBt(Wf3, 128, 0, 128, 512, 128, 512, Wf3th, Wf3tl, 1);
  splitBt(Wo, 2, 0, 2, 128, 64, 128, Woth, Wotl, 1);
  make_as1_k<<<(780 + 255)/256, 256, 0, stream>>>(W1, a_src1, a_dst1, AsB, AdB);
  make_vs2_k<<<(1280 + 255)/256, 256, 0, stream>>>(W2, a_src2, a_dst2, vs, vd);

  for (int br = 0; br < 2; ++br){
    const float* x   = br ? x2 : x1;
    const int* ei    = br ? ei2 : ei1;
    const int* batch = br ? batch2 : batch1;
    float* vout      = br ? v2 : v1;

    // CSR by dst (self-loops included via deg init = 1)
    fill_int_k<<<(N + 255)/256, 256, 0, stream>>>(deg, 1, N);
    hist_dst_k<<<(E + 255)/256, 256, 0, stream>>>(ei, E, deg);
    scan_k<<<1, 1024, 0, stream>>>(deg, rowptr, N);
    copy_int_k<<<(N + 255)/256, 256, 0, stream>>>(cursor, rowptr, N);
    fill_csr_k<<<(E + 255)/256, 256, 0, stream>>>(ei, E, cursor, csr);
    self_loop_k<<<(N + 255)/256, 256, 0, stream>>>(cursor, csr, N);

    // conv1 (two head-groups of 5 to cap workspace)
    alpha1_k<<<((N*10) + 255)/256, 256, 0, stream>>>(x, AsB, AdB, as1, ad1, N);
    for (int hg = 0; hg < 2; ++hg){
      int h0 = hg*5;
      gat1_agg_k<<<N, 64, 0, stream>>>(rowptr, csr, x, as1, ad1, yh, yl, N, h0);
      gemm(yh, yl, 96, (long long)MPAD*96, W1th + (size_t)h0*128*96, W1tl + (size_t)h0*128*96,
           96, 128*96, nullptr, h1eh + (size_t)h0*128, h1el + (size_t)h0*128,
           1280, 128, b1 + h0*128, 128, N, 128, 96, 5, 2, 1);
    }

    // conv2
    alpha2s_k<<<N, 256, 0, stream>>>(h1eh, h1el, vs, vd, as2, ad2, N);
    gemm(h1eh, h1el, 1280, 0, W2th, W2tl, 1280, 0,
         h2, nullptr, nullptr, 128, 0, nullptr, 0, N, 128, 1280, 1, 0, 0);
    gat2_agg_k<<<N, 64, 0, stream>>>(rowptr, csr, h2, as2, ad2, b2, h2e, N);

    // pool + linear
    pool_split_k<<<Bg, 128, 0, stream>>>(h2e, batch, N, pooledh, pooledl);
    gemm(pooledh, pooledl, 128, 0, Wgth, Wgtl, 128, 0,
         vout, nullptr, nullptr, 128, 0, bg, 0, Bg, 128, 128, 1, 1, 0);
  }

  // cell MLP
  l2norm_split_k<<<Bg, 256, 0, stream>>>(cell, 954, 960, cnh, cnl);
  gemm(cnh, cnl, 960, 0, Wr1th, Wr1tl, 960, 0, nullptr, c1h, c1l, 2048, 0,
       br1, 0, Bg, 2048, 960, 1, 1, 1);
  gemm(c1h, c1l, 2048, 0, Wr2th, Wr2tl, 2048, 0, nullptr, c2h, c2l, 512, 0,
       br2, 0, Bg, 512, 2048, 1, 1, 1);
  gemm(c2h, c2l, 512, 0, Wr3th, Wr3tl, 512, 0, c3, nullptr, nullptr, 256, 0,
       br3, 0, Bg, 256, 512, 1, 1, 0);

  // final MLP
  concat_k<<<((Bg*512) + 255)/256, 256, 0, stream>>>(v1, v2, c3, xcat, Bg);
  l2norm_split_k<<<Bg, 256, 0, stream>>>(xcat, 512, 512, xcnh, xcnl);
  gemm(xcnh, xcnl, 512, 0, Wf1th, Wf1tl, 512, 0, nullptr, t1h, t1l, 1024, 0,
       bf1, 0, Bg, 1024, 512, 1, 1, 1);
  gemm(t1h, t1l, 1024, 0, Wf2th, Wf2tl, 1024, 0, nullptr, t2h, t2l, 512, 0,
       bf2, 0, Bg, 512, 1024, 1, 1, 1);
  gemm(t2h, t2l, 512, 0, Wf3th, Wf3tl, 512, 0, nullptr, t3h, t3l, 128, 0,
       bf3, 0, Bg, 128, 512, 1, 1, 1);
  gemm(t3h, t3l, 128, 0, Woth, Wotl, 128, 0, out, nullptr, nullptr, 2, 0,
       bo, 0, Bg, 2, 128, 1, 0, 0);
}

// Round 5
// 1146.239 us; speedup vs baseline: 2.6722x; 1.0914x over previous
//
#include <hip/hip_runtime.h>
#include <math.h>

typedef unsigned short ushort_t;
typedef __attribute__((ext_vector_type(8))) short short8;
typedef __attribute__((ext_vector_type(8))) unsigned short ushort8v;
typedef __attribute__((ext_vector_type(4))) float float4v;
typedef __attribute__((ext_vector_type(4))) unsigned short ushort4v;

#define MPAD 30016

// ---------------- utility ----------------
__device__ __forceinline__ float lrelu02(float v){ return v > 0.f ? v : 0.2f*v; }

__device__ __forceinline__ ushort_t f2bf(float x){
  unsigned u = __float_as_uint(x);
  return (ushort_t)((u + 0x7fffu + ((u >> 16) & 1u)) >> 16);
}
__device__ __forceinline__ float bf2f(ushort_t h){ return __uint_as_float(((unsigned)h) << 16); }

__device__ __forceinline__ void gll16(const void* g, void* l){
  __builtin_amdgcn_global_load_lds((const __attribute__((address_space(1))) void*)g,
                                   (__attribute__((address_space(3))) void*)l, 16, 0, 0);
}

__global__ void fill_int_k(int* p, int v, int n){
  int i = blockIdx.x*blockDim.x + threadIdx.x;
  if (i < n) p[i] = v;
}

// ---------------- batched CSR build (both branches) ----------------
__global__ void hist2_k(const int* __restrict__ ei1, const int* __restrict__ ei2,
                        int E, int N, int* deg){
  int idx = blockIdx.x*blockDim.x + threadIdx.x;
  if (idx < 2*E){
    int br = idx / E, e = idx - br*E;
    const int* ei = br ? ei2 : ei1;
    atomicAdd(&deg[br*N + ei[E + e]], 1);
  }
}

__global__ __launch_bounds__(1024)
void scanA_k(const int* __restrict__ deg, int* __restrict__ rowptr, int* __restrict__ bsum, int n){
  int br = blockIdx.y;
  int t = threadIdx.x;
  int i = blockIdx.x*1024 + t;
  __shared__ int s[1024];
  int v = (i < n) ? deg[br*n + i] : 0;
  s[t] = v; __syncthreads();
  for (int off = 1; off < 1024; off <<= 1){
    int x = (t >= off) ? s[t - off] : 0;
    __syncthreads();
    s[t] += x;
    __syncthreads();
  }
  if (i < n) rowptr[br*(n+1) + i] = s[t] - v;
  if (t == 1023) bsum[br*gridDim.x + blockIdx.x] = s[1023];
}

__global__ void scanB_k(int* bsum, int nb){
  int br = threadIdx.x;
  if (br < 2){
    int run = 0;
    for (int i = 0; i < nb; ++i){ int v = bsum[br*nb + i]; bsum[br*nb + i] = run; run += v; }
  }
}

__global__ __launch_bounds__(1024)
void scanC_k(const int* __restrict__ bsum, int* __restrict__ rowptr, int n, int nb, int total){
  int br = blockIdx.y;
  int i = blockIdx.x*1024 + threadIdx.x;
  int add = bsum[br*nb + blockIdx.x];
  if (i < n) rowptr[br*(n+1) + i] += add;
  if (i == 0) rowptr[br*(n+1) + n] = total;
}

__global__ void init_cursor_k(const int* __restrict__ rowptr, int* cursor, int N){
  int idx = blockIdx.x*blockDim.x + threadIdx.x;
  if (idx < 2*N){ int br = idx / N, i = idx - br*N; cursor[idx] = rowptr[br*(N+1) + i]; }
}

__global__ void fill_csr2_k(const int* __restrict__ ei1, const int* __restrict__ ei2,
                            int E, int N, int* cursor, int* csr){
  int idx = blockIdx.x*blockDim.x + threadIdx.x;
  if (idx < 2*E){
    int br = idx / E, e = idx - br*E;
    const int* ei = br ? ei2 : ei1;
    int dst = ei[E + e];
    int pos = atomicAdd(&cursor[br*N + dst], 1);
    csr[br*(E+N) + pos] = ei[e];
  }
}

__global__ void self_loop2_k(int* cursor, int* csr, int E, int N){
  int idx = blockIdx.x*blockDim.x + threadIdx.x;
  if (idx < 2*N){
    int br = idx / N, i = idx - br*N;
    int pos = atomicAdd(&cursor[br*N + i], 1);
    csr[br*(E+N) + pos] = i;
  }
}

// ---------------- attention score precompute ----------------
__global__ void make_as1_k(const float* __restrict__ W1, const float* __restrict__ a_src,
                           const float* __restrict__ a_dst, float* As, float* Ad){
  int idx = blockIdx.x*blockDim.x + threadIdx.x;
  if (idx < 78*10){
    int f = idx / 10, h = idx % 10;
    float ss = 0.f, sd = 0.f;
    for (int c = 0; c < 128; ++c){
      float w = W1[f*1280 + h*128 + c];
      ss += w * a_src[h*128 + c];
      sd += w * a_dst[h*128 + c];
    }
    As[idx] = ss; Ad[idx] = sd;
  }
}

// batched over both branches: as1/ad1 sized 2*n*10
__global__ void alpha1b_k(const float* __restrict__ x1, const float* __restrict__ x2,
                          const float* __restrict__ As, const float* __restrict__ Ad,
                          float* as1, float* ad1, int n){
  int idx = blockIdx.x*blockDim.x + threadIdx.x;
  if (idx < 2*n*10){
    int br = idx / (n*10), r = idx - br*n*10;
    int i = r / 10, h = r - i*10;
    const float* xr = (br ? x2 : x1) + (size_t)i*78;
    float ss = 0.f, sd = 0.f;
    for (int f = 0; f < 78; ++f){
      float xv = xr[f];
      ss += xv * As[f*10 + h];
      sd += xv * Ad[f*10 + h];
    }
    as1[idx] = ss; ad1[idx] = sd;
  }
}

__global__ void make_vs2_k(const float* __restrict__ W2, const float* __restrict__ a_src,
                           const float* __restrict__ a_dst, float* vs, float* vd){
  int k = blockIdx.x*blockDim.x + threadIdx.x;
  if (k < 1280){
    float ss = 0.f, sd = 0.f;
    for (int c = 0; c < 128; ++c){
      float w = W2[k*128 + c];
      ss += w * a_src[c]; sd += w * a_dst[c];
    }
    vs[k] = ss; vd[k] = sd;
  }
}

// alpha2 from split-bf16 h1e (vectorized ushort4 loads)
__global__ __launch_bounds__(256)
void alpha2v_k(const ushort_t* __restrict__ hH, const ushort_t* __restrict__ hL,
               const float* __restrict__ vs, const float* __restrict__ vd,
               float* as2, float* ad2, int n){
  int i = blockIdx.x, t = threadIdx.x;
  __shared__ float ss[256], sd[256];
  size_t base = (size_t)i*1280;
  float ps = 0.f, pd = 0.f;
  #pragma unroll
  for (int it = 0; it < 2; ++it){
    int k0 = it*1024 + t*4;
    if (k0 < 1280){
      ushort4v h4 = *(const ushort4v*)&hH[base + k0];
      ushort4v l4 = *(const ushort4v*)&hL[base + k0];
      #pragma unroll
      for (int c = 0; c < 4; ++c){
        float v = bf2f(h4[c]) + bf2f(l4[c]);
        ps += v*vs[k0 + c]; pd += v*vd[k0 + c];
      }
    }
  }
  ss[t] = ps; sd[t] = pd; __syncthreads();
  for (int o = 128; o > 0; o >>= 1){
    if (t < o){ ss[t] += ss[t+o]; sd[t] += sd[t+o]; }
    __syncthreads();
  }
  if (t == 0){ as2[i] = ss[0]; ad2[i] = sd[0]; }
}

// ---------------- GATConv1 softmax + aggregate in input space ----------------
// heads [h0,h0+5); writes split-bf16 y[hg][i][96] (f>=78 zero-padded)
__global__ __launch_bounds__(64)
void gat1_agg_k(const int* __restrict__ rowptr, const int* __restrict__ csr,
                const float* __restrict__ x, const float* __restrict__ as1,
                const float* __restrict__ ad1, ushort_t* __restrict__ yh,
                ushort_t* __restrict__ yl, int n, int h0){
  int i = blockIdx.x;
  int t = threadIdx.x;
  __shared__ float adi[5], mh[5], rden[5], wE[5], xs[78];
  int beg = rowptr[i], end = rowptr[i+1];
  if (t < 5){
    float a = ad1[i*10 + h0 + t];
    adi[t] = a;
    float m = -1e30f;
    for (int e = beg; e < end; ++e){
      int s = csr[e];
      m = fmaxf(m, lrelu02(as1[s*10 + h0 + t] + a));
    }
    float den = 0.f;
    for (int e = beg; e < end; ++e){
      int s = csr[e];
      den += expf(lrelu02(as1[s*10 + h0 + t] + a) - m);
    }
    mh[t] = m; rden[t] = 1.f/(den + 1e-16f);
  }
  __syncthreads();
  float acc[7];
  int hh[7], cc[7];
  #pragma unroll
  for (int k = 0; k < 7; ++k){
    acc[k] = 0.f;
    int j = t + 64*k;
    hh[k] = (j < 390) ? (j/78) : 0;
    cc[k] = (j < 390) ? (j%78) : 0;
  }
  for (int e = beg; e < end; ++e){
    int s = csr[e];
    if (t < 5) wE[t] = expf(lrelu02(as1[s*10 + h0 + t] + adi[t]) - mh[t]) * rden[t];
    for (int c = t; c < 78; c += 64) xs[c] = x[(long long)s*78 + c];
    __syncthreads();
    #pragma unroll
    for (int k = 0; k < 7; ++k){
      int j = t + 64*k;
      if (j < 390) acc[k] += wE[hh[k]] * xs[cc[k]];
    }
    __syncthreads();
  }
  #pragma unroll
  for (int k = 0; k < 7; ++k){
    int j = t + 64*k;
    if (j < 390){
      float v = acc[k];
      ushort_t hb = f2bf(v);
      size_t o = ((size_t)hh[k]*MPAD + i)*96 + cc[k];
      yh[o] = hb; yl[o] = f2bf(v - bf2f(hb));
    }
  }
  for (int p = t; p < 90; p += 64){
    int h = p/18, c = 78 + p%18;
    size_t o = ((size_t)h*MPAD + i)*96 + c;
    yh[o] = 0; yl[o] = 0;
  }
}

// ---------------- GATConv2 softmax + aggregate (128-wide) ----------------
__global__ __launch_bounds__(64)
void gat2_agg_k(const int* __restrict__ rowptr, const int* __restrict__ csr,
                const float* __restrict__ h2, const float* __restrict__ as2,
                const float* __restrict__ ad2, const float* __restrict__ b2,
                float* __restrict__ h2e, int n){
  int i = blockIdx.x, t = threadIdx.x;
  int beg = rowptr[i], end = rowptr[i+1];
  float adi = ad2[i];
  float m = -1e30f;
  for (int e = beg; e < end; ++e) m = fmaxf(m, lrelu02(as2[csr[e]] + adi));
  float den = 0.f;
  for (int e = beg; e < end; ++e) den += expf(lrelu02(as2[csr[e]] + adi) - m);
  float rden = 1.f/(den + 1e-16f);
  float a0 = 0.f, a1 = 0.f;
  for (int e = beg; e < end; ++e){
    int s = csr[e];
    float w = expf(lrelu02(as2[s] + adi) - m) * rden;
    a0 += w * h2[(long long)s*128 + t];
    a1 += w * h2[(long long)s*128 + 64 + t];
  }
  float o0 = a0 + b2[t];      o0 = o0 > 0.f ? o0 : expm1f(o0);
  float o1 = a1 + b2[64 + t]; o1 = o1 > 0.f ? o1 : expm1f(o1);
  h2e[(long long)i*128 + t]      = o0;
  h2e[(long long)i*128 + 64 + t] = o1;
}

// ---------------- global max pool (batch sorted) → split bf16 ----------------
__global__ __launch_bounds__(128)
void pool_split_k(const float* __restrict__ h2e, const int* __restrict__ batch, int n,
                  ushort_t* __restrict__ ph, ushort_t* __restrict__ pl){
  int g = blockIdx.x, t = threadIdx.x;
  int lo = 0, hi = n;
  while (lo < hi){ int mid = (lo + hi) >> 1; if (batch[mid] < g) lo = mid + 1; else hi = mid; }
  int a = lo, b = n;
  while (a < b){ int mid = (a + b) >> 1; if (batch[mid] < g + 1) a = mid + 1; else b = mid; }
  float m = -1e30f;
  for (int i = lo; i < a; ++i) m = fmaxf(m, h2e[(long long)i*128 + t]);
  ushort_t h = f2bf(m);
  ph[g*128 + t] = h; pl[g*128 + t] = f2bf(m - bf2f(h));
}

// ---------------- row-wise L2 normalize → split bf16 (K-padded) ----------------
__global__ __launch_bounds__(256)
void l2norm_split_k(const float* __restrict__ in, int cols, int Kp,
                    ushort_t* __restrict__ oh, ushort_t* __restrict__ ol){
  int r = blockIdx.x, t = threadIdx.x;
  __shared__ float s[256];
  __shared__ float scaleS;
  const float* rp = in + (size_t)r*cols;
  float p = 0.f;
  for (int k = t; k < cols; k += 256){ float v = rp[k]; p += v*v; }
  s[t] = p; __syncthreads();
  for (int o = 128; o > 0; o >>= 1){
    if (t < o) s[t] += s[t+o];
    __syncthreads();
  }
  if (t == 0) scaleS = 1.f / fmaxf(sqrtf(s[0]), 1e-12f);
  __syncthreads();
  float sc = scaleS;
  for (int k = t; k < Kp; k += 256){
    float v = (k < cols) ? rp[k]*sc : 0.f;
    ushort_t h = f2bf(v);
    size_t o2 = (size_t)r*Kp + k;
    oh[o2] = h; ol[o2] = f2bf(v - bf2f(h));
  }
}

__global__ void concat_k(const float* __restrict__ v1, const float* __restrict__ v2,
                         const float* __restrict__ c3, float* __restrict__ xcat, int B){
  int idx = blockIdx.x*blockDim.x + threadIdx.x;
  if (idx < B*512){
    int r = idx >> 9, c = idx & 511;
    float v;
    if (c < 128) v = v1[r*128 + c];
    else if (c < 256) v = v2[r*128 + (c - 128)];
    else v = c3[r*256 + (c - 256)];
    xcat[idx] = v;
  }
}

// relu + split (post split-K reduction)
__global__ void act_split_k(const float* __restrict__ in, ushort_t* __restrict__ oh,
                            ushort_t* __restrict__ ol, int n){
  int i = blockIdx.x*blockDim.x + threadIdx.x;
  if (i < n){
    float v = fmaxf(in[i], 0.f);
    ushort_t h = f2bf(v);
    oh[i] = h; ol[i] = f2bf(v - bf2f(h));
  }
}

// ---------------- weight transpose + split: Bt[n][k] = W[k][n] ----------------
__global__ void split_bt_k(const float* __restrict__ W, int ldw, int colStride,
                           int N, int K, int Np, int Kp,
                           ushort_t* __restrict__ dh, ushort_t* __restrict__ dl, int total){
  int idx = blockIdx.x*blockDim.x + threadIdx.x;
  if (idx >= total) return;
  int n  = idx % Np;
  int r  = idx / Np;
  int k4 = r % (Kp >> 2);
  int b  = r / (Kp >> 2);
  size_t o = ((size_t)b*Np + n)*Kp + (size_t)k4*4;
  ushort4v hv, lv;
  #pragma unroll
  for (int kk = 0; kk < 4; ++kk){
    int k = k4*4 + kk;
    float v = (n < N && k < K) ? W[(size_t)k*ldw + (size_t)b*colStride + n] : 0.f;
    ushort_t h = f2bf(v);
    hv[kk] = h; lv[kk] = f2bf(v - bf2f(h));
  }
  *(ushort4v*)&dh[o] = hv;
  *(ushort4v*)&dl[o] = lv;
}

// ---------------- split-bf16 MFMA GEMM v2 ----------------
// A (hi/lo): [M x K] bf16 row-major; Bt (hi/lo): [N x K] bf16 row-major.
// outMode 0: fp32 direct (bias+act); 1: split bf16 coalesced (bias+act);
//         2: fp32 atomicAdd (bias at kc==0, act must be 0 — deferred)
// Double-buffered prefetch K-loop; kSplit>1 partitions K across blockIdx.z.
__global__ __launch_bounds__(256)
void gemm_split(const ushort_t* __restrict__ Ahp, const ushort_t* __restrict__ Alp, int lda, long long sA,
                const ushort_t* __restrict__ Bhp, const ushort_t* __restrict__ Blp, int ldb, long long sB,
                float* __restrict__ C, ushort_t* __restrict__ Ch, ushort_t* __restrict__ Cl,
                int ldc, long long sC,
                const float* __restrict__ bias, int sBias,
                int M, int Nc, int K, int act, int outMode, int kSplit){
  int zb = blockIdx.z;
  int b = zb / kSplit, kc = zb - b*kSplit;
  Ahp += (long long)b*sA; Alp += (long long)b*sA;
  Bhp += (long long)b*sB; Blp += (long long)b*sB;
  long long cOff = (long long)b*sC;
  int Kc = K / kSplit;
  int kb = kc*Kc;
  int nIter = Kc / 32;

  // layout: buf p at p*8192 shorts: [Ah 2048][Al 2048][Bh 2048][Bl 2048], rows [64][32]
  __shared__ ushort_t smem[16384];

  int tid = threadIdx.x, lane = tid & 63, wave = tid >> 6;
  int row0 = blockIdx.y*64, col0 = blockIdx.x*64;
  int wm = (wave & 1)*32, wn = (wave >> 1)*32;
  int lr = lane & 15, quad = lane >> 4;

  int srow = wave*16 + (lane >> 2);
  int skc  = (lane & 3)*8;
  const ushort_t* gAh = Ahp + (long long)(row0 + srow)*lda + skc + kb;
  const ushort_t* gAl = Alp + (long long)(row0 + srow)*lda + skc + kb;
  const ushort_t* gBh = Bhp + (long long)(col0 + srow)*ldb + skc + kb;
  const ushort_t* gBl = Blp + (long long)(col0 + srow)*ldb + skc + kb;

  float4v acc[2][2];
  #pragma unroll
  for (int i = 0; i < 2; ++i)
    #pragma unroll
    for (int j = 0; j < 2; ++j)
      acc[i][j] = (float4v){0.f, 0.f, 0.f, 0.f};

  auto issue = [&](int p, int kt){
    ushort_t* base = &smem[p*8192 + wave*512];
    gll16(gAh + kt, base);
    gll16(gAl + kt, base + 2048);
    gll16(gBh + kt, base + 4096);
    gll16(gBl + kt, base + 6144);
  };

  issue(0, 0);
  int p = 0;
  for (int it = 0; it < nIter; ++it){
    __syncthreads();                       // buf p landed (vmcnt drained at barrier)
    if (it + 1 < nIter) issue(p ^ 1, (it + 1)*32);
    const ushort_t* sm = &smem[p*8192];
    short8 ah[2], al[2], bh[2], bl[2];
    #pragma unroll
    for (int t2 = 0; t2 < 2; ++t2){
      int ao = (wm + t2*16 + lr)*32 + quad*8;
      int bo = (wn + t2*16 + lr)*32 + quad*8;
      ah[t2] = *(const short8*)&sm[ao];
      al[t2] = *(const short8*)&sm[2048 + ao];
      bh[t2] = *(const short8*)&sm[4096 + bo];
      bl[t2] = *(const short8*)&sm[6144 + bo];
    }
    #pragma unroll
    for (int i = 0; i < 2; ++i)
      #pragma unroll
      for (int j = 0; j < 2; ++j){
        acc[i][j] = __builtin_amdgcn_mfma_f32_16x16x32_bf16(al[i], bh[j], acc[i][j], 0, 0, 0);
        acc[i][j] = __builtin_amdgcn_mfma_f32_16x16x32_bf16(ah[i], bl[j], acc[i][j], 0, 0, 0);
        acc[i][j] = __builtin_amdgcn_mfma_f32_16x16x32_bf16(ah[i], bh[j], acc[i][j], 0, 0, 0);
      }
    p ^= 1;
  }
  __syncthreads();   // all reads done before smem reuse / epilogue

  if (outMode != 1){
    #pragma unroll
    for (int j = 0; j < 2; ++j){
      int col = col0 + wn + j*16 + lr;
      if (col >= Nc) continue;
      float bv = (bias && kc == 0) ? bias[(long long)b*sBias + col] : 0.f;
      #pragma unroll
      for (int i = 0; i < 2; ++i){
        #pragma unroll
        for (int r = 0; r < 4; ++r){
          int row = row0 + wm + i*16 + quad*4 + r;
          if (row >= M) continue;
          float v = acc[i][j][r] + bv;
          if (act == 1) v = fmaxf(v, 0.f);
          else if (act == 2) v = v > 0.f ? v : expm1f(v);
          long long o = cOff + (long long)row*ldc + col;
          if (outMode == 0) C[o] = v;
          else atomicAdd(&C[o], v);
        }
      }
    }
  } else {
    // coalesced split-bf16 epilogue via LDS fp32 tile (kSplit==1 only)
    float* ftile = (float*)smem;           // 64x64 floats = 16 KB
    #pragma unroll
    for (int i = 0; i < 2; ++i)
      #pragma unroll
      for (int j = 0; j < 2; ++j)
        #pragma unroll
        for (int r = 0; r < 4; ++r)
          ftile[(wm + i*16 + quad*4 + r)*64 + wn + j*16 + lr] = acc[i][j][r];
    __syncthreads();
    int row = tid >> 2, ch = (tid & 3)*16;
    int grow = row0 + row;
    if (grow < M){
      if (col0 + 64 <= Nc){
        long long o = cOff + (long long)grow*ldc + col0 + ch;
        #pragma unroll
        for (int g = 0; g < 2; ++g){
          ushort8v hv, lv;
          #pragma unroll
          for (int c = 0; c < 8; ++c){
            int cc2 = ch + g*8 + c;
            float v = ftile[row*64 + cc2];
            if (bias) v += bias[(long long)b*sBias + col0 + cc2];
            if (act == 1) v = fmaxf(v, 0.f);
            else if (act == 2) v = v > 0.f ? v : expm1f(v);
            ushort_t h = f2bf(v);
            hv[c] = h; lv[c] = f2bf(v - bf2f(h));
          }
          *(ushort8v*)&Ch[o + g*8] = hv;
          *(ushort8v*)&Cl[o + g*8] = lv;
        }
      } else {
        for (int c = 0; c < 16; ++c){
          int col = col0 + ch + c;
          if (col >= Nc) break;
          float v = ftile[row*64 + ch + c];
          if (bias) v += bias[(long long)b*sBias + col];
          if (act == 1) v = fmaxf(v, 0.f);
          else if (act == 2) v = v > 0.f ? v : expm1f(v);
          long long o = cOff + (long long)grow*ldc + col;
          ushort_t h = f2bf(v);
          Ch[o] = h; Cl[o] = f2bf(v - bf2f(h));
        }
      }
    }
  }
}

// ---------------- host launch ----------------
extern "C" void kernel_launch(void* const* d_in, const int* in_sizes, int n_in,
                              void* d_out, int out_size, void* d_ws, size_t ws_size,
                              hipStream_t stream){
  const float* x1     = (const float*)d_in[0];
  const int*   ei1    = (const int*)  d_in[1];
  const int*   batch1 = (const int*)  d_in[2];
  const float* x2     = (const float*)d_in[3];
  const int*   ei2    = (const int*)  d_in[4];
  const int*   batch2 = (const int*)  d_in[5];
  const float* cell   = (const float*)d_in[6];
  const float* W1     = (const float*)d_in[7];
  const float* a_src1 = (const float*)d_in[8];
  const float* a_dst1 = (const float*)d_in[9];
  const float* b1     = (const float*)d_in[10];
  const float* W2     = (const float*)d_in[11];
  const float* a_src2 = (const float*)d_in[12];
  const float* a_dst2 = (const float*)d_in[13];
  const float* b2     = (const float*)d_in[14];
  const float* Wg     = (const float*)d_in[15];
  const float* bg     = (const float*)d_in[16];
  const float* Wr1    = (const float*)d_in[17];
  const float* br1    = (const float*)d_in[18];
  const float* Wr2    = (const float*)d_in[19];
  const float* br2    = (const float*)d_in[20];
  const float* Wr3    = (const float*)d_in[21];
  const float* br3    = (const float*)d_in[22];
  const float* Wf1    = (const float*)d_in[23];
  const float* bf1    = (const float*)d_in[24];
  const float* Wf2    = (const float*)d_in[25];
  const float* bf2    = (const float*)d_in[26];
  const float* Wf3    = (const float*)d_in[27];
  const float* bf3    = (const float*)d_in[28];
  const float* Wo     = (const float*)d_in[29];
  const float* bo     = (const float*)d_in[30];
  float* out = (float*)d_out;
  (void)n_in; (void)out_size; (void)ws_size;

  const int N  = in_sizes[0] / 78;
  const int E  = in_sizes[1] / 2;
  const int Bg = in_sizes[6] / 954;

  char* wsb = (char*)d_ws;
  size_t off = 0;
  auto alloc = [&](size_t bytes)->char*{
    char* p = wsb + off; off += ((bytes + 255)/256)*256; return p;
  };

  // big persistent buffers
  ushort_t* h1eh = (ushort_t*)alloc((size_t)MPAD*1280*2);
  ushort_t* h1el = (ushort_t*)alloc((size_t)MPAD*1280*2);
  // Y region: yh/yl (5-head group) during conv1; h2/h2e during conv2; MLP buffers after
  char* Yb = alloc((size_t)5*MPAD*96*2*2);
  ushort_t* yh = (ushort_t*)Yb;
  ushort_t* yl = yh + (size_t)5*MPAD*96;
  float* h2  = (float*)Yb;
  float* h2e = (float*)(Yb + (size_t)MPAD*128*4);
  size_t yoff = 0;
  auto yalloc = [&](size_t bytes)->char*{
    char* p = Yb + yoff; yoff += ((bytes + 255)/256)*256; return p;
  };
  ushort_t* cnh  = (ushort_t*)yalloc((size_t)Bg*960*2);
  ushort_t* cnl  = (ushort_t*)yalloc((size_t)Bg*960*2);
  ushort_t* c1h  = (ushort_t*)yalloc((size_t)Bg*2048*2);
  ushort_t* c1l  = (ushort_t*)yalloc((size_t)Bg*2048*2);
  float*    c2f  = (float*)   yalloc((size_t)Bg*512*4);
  ushort_t* c2h  = (ushort_t*)yalloc((size_t)Bg*512*2);
  ushort_t* c2l  = (ushort_t*)yalloc((size_t)Bg*512*2);
  float*    c3   = (float*)   yalloc((size_t)Bg*256*4);
  float*    xcat = (float*)   yalloc((size_t)Bg*512*4);
  ushort_t* xcnh = (ushort_t*)yalloc((size_t)Bg*512*2);
  ushort_t* xcnl = (ushort_t*)yalloc((size_t)Bg*512*2);
  ushort_t* t1h  = (ushort_t*)yalloc((size_t)Bg*1024*2);
  ushort_t* t1l  = (ushort_t*)yalloc((size_t)Bg*1024*2);
  float*    t2f  = (float*)   yalloc((size_t)Bg*512*4);
  ushort_t* t2h  = (ushort_t*)yalloc((size_t)Bg*512*2);
  ushort_t* t2l  = (ushort_t*)yalloc((size_t)Bg*512*2);
  float*    t3f  = (float*)   yalloc((size_t)Bg*128*4);
  ushort_t* t3h  = (ushort_t*)yalloc((size_t)Bg*128*2);
  ushort_t* t3l  = (ushort_t*)yalloc((size_t)Bg*128*2);

  // transposed+split weights
  ushort_t* W1th = (ushort_t*)alloc((size_t)10*128*96*2);
  ushort_t* W1tl = (ushort_t*)alloc((size_t)10*128*96*2);
  ushort_t* W2th = (ushort_t*)alloc((size_t)128*1280*2);
  ushort_t* W2tl = (ushort_t*)alloc((size_t)128*1280*2);
  ushort_t* Wgth = (ushort_t*)alloc((size_t)128*128*2);
  ushort_t* Wgtl = (ushort_t*)alloc((size_t)128*128*2);
  ushort_t* Wr1th= (ushort_t*)alloc((size_t)2048*960*2);
  ushort_t* Wr1tl= (ushort_t*)alloc((size_t)2048*960*2);
  ushort_t* Wr2th= (ushort_t*)alloc((size_t)512*2048*2);
  ushort_t* Wr2tl= (ushort_t*)alloc((size_t)512*2048*2);
  ushort_t* Wr3th= (ushort_t*)alloc((size_t)256*512*2);
  ushort_t* Wr3tl= (ushort_t*)alloc((size_t)256*512*2);
  ushort_t* Wf1th= (ushort_t*)alloc((size_t)1024*512*2);
  ushort_t* Wf1tl= (ushort_t*)alloc((size_t)1024*512*2);
  ushort_t* Wf2th= (ushort_t*)alloc((size_t)512*1024*2);
  ushort_t* Wf2tl= (ushort_t*)alloc((size_t)512*1024*2);
  ushort_t* Wf3th= (ushort_t*)alloc((size_t)128*512*2);
  ushort_t* Wf3tl= (ushort_t*)alloc((size_t)128*512*2);
  ushort_t* Woth = (ushort_t*)alloc((size_t)64*128*2);
  ushort_t* Wotl = (ushort_t*)alloc((size_t)64*128*2);

  float* as1b = (float*)alloc((size_t)2*N*10*4);
  float* ad1b = (float*)alloc((size_t)2*N*10*4);
  float* as2  = (float*)alloc((size_t)N*4);
  float* ad2  = (float*)alloc((size_t)N*4);
  float* AsB  = (float*)alloc(780*4);
  float* AdB  = (float*)alloc(780*4);
  float* vs   = (float*)alloc(1280*4);
  float* vd   = (float*)alloc(1280*4);
  int* deg2    = (int*)alloc((size_t)2*N*4);
  int* rowptr2 = (int*)alloc((size_t)2*(N+1)*4);
  int* cursor2 = (int*)alloc((size_t)2*N*4);
  int* csr2    = (int*)alloc((size_t)2*(E+N)*4);
  int* bsum    = (int*)alloc((size_t)2*64*4);
  ushort_t* pooledh = (ushort_t*)alloc((size_t)Bg*128*2);
  ushort_t* pooledl = (ushort_t*)alloc((size_t)Bg*128*2);
  float* v1   = (float*)alloc((size_t)Bg*128*4);
  float* v2   = (float*)alloc((size_t)Bg*128*4);

  auto gemm = [&](const ushort_t* Ah_, const ushort_t* Al_, int lda, long long sA_,
                  const ushort_t* Bh_, const ushort_t* Bl_, int ldb, long long sB_,
                  float* C_, ushort_t* Ch_, ushort_t* Cl_, int ldc, long long sC_,
                  const float* bias_, int sBias_, int M_, int N_, int K_, int batch_,
                  int act_, int mode_, int kSplit_){
    dim3 grid((N_ + 63)/64, (M_ + 63)/64, batch_*kSplit_);
    gemm_split<<<grid, 256, 0, stream>>>(Ah_, Al_, lda, sA_, Bh_, Bl_, ldb, sB_,
                                         C_, Ch_, Cl_, ldc, sC_, bias_, sBias_,
                                         M_, N_, K_, act_, mode_, kSplit_);
  };
  auto splitBt = [&](const float* W_, int ldw_, int colStride_, int N_, int K_,
                     int Np_, int Kp_, ushort_t* dh_, ushort_t* dl_, int batch_){
    int total = batch_*Np_*(Kp_ >> 2);
    split_bt_k<<<(total + 255)/256, 256, 0, stream>>>(W_, ldw_, colStride_, N_, K_,
                                                      Np_, Kp_, dh_, dl_, total);
  };

  // ---- weight prep ----
  splitBt(W1, 1280, 128, 128, 78, 128, 96, W1th, W1tl, 10);
  splitBt(W2, 128, 0, 128, 1280, 128, 1280, W2th, W2tl, 1);
  splitBt(Wg, 128, 0, 128, 128, 128, 128, Wgth, Wgtl, 1);
  splitBt(Wr1, 2048, 0, 2048, 954, 2048, 960, Wr1th, Wr1tl, 1);
  splitBt(Wr2, 512, 0, 512, 2048, 512, 2048, Wr2th, Wr2tl, 1);
  splitBt(Wr3, 256, 0, 256, 512, 256, 512, Wr3th, Wr3tl, 1);
  splitBt(Wf1, 1024, 0, 1024, 512, 1024, 512, Wf1th, Wf1tl, 1);
  splitBt(Wf2, 512, 0, 512, 1024, 512, 1024, Wf2th, Wf2tl, 1);
  splitBt(Wf3, 128, 0, 128, 512, 128, 512, Wf3th, Wf3tl, 1);
  splitBt(Wo, 2, 0, 2, 128, 64, 128, Woth, Wotl, 1);
  make_as1_k<<<(780 + 255)/256, 256, 0, stream>>>(W1, a_src1, a_dst1, AsB, AdB);
  make_vs2_k<<<(1280 + 255)/256, 256, 0, stream>>>(W2, a_src2, a_dst2, vs, vd);
  alpha1b_k<<<((2*N*10) + 255)/256, 256, 0, stream>>>(x1, x2, AsB, AdB, as1b, ad1b, N);

  // ---- batched CSR build (both branches) ----
  const int NB = (N + 1023)/1024;
  fill_int_k<<<((2*N) + 255)/256, 256, 0, stream>>>(deg2, 1, 2*N);
  hist2_k<<<((2*E) + 255)/256, 256, 0, stream>>>(ei1, ei2, E, N, deg2);
  scanA_k<<<dim3(NB, 2), 1024, 0, stream>>>(deg2, rowptr2, bsum, N);
  scanB_k<<<1, 64, 0, stream>>>(bsum, NB);
  scanC_k<<<dim3(NB, 2), 1024, 0, stream>>>(bsum, rowptr2, N, NB, E + N);
  init_cursor_k<<<((2*N) + 255)/256, 256, 0, stream>>>(rowptr2, cursor2, N);
  fill_csr2_k<<<((2*E) + 255)/256, 256, 0, stream>>>(ei1, ei2, E, N, cursor2, csr2);
  self_loop2_k<<<((2*N) + 255)/256, 256, 0, stream>>>(cursor2, csr2, E, N);

  for (int br = 0; br < 2; ++br){
    const float* x   = br ? x2 : x1;
    const int* batch = br ? batch2 : batch1;
    float* vout      = br ? v2 : v1;
    const int* rowptr = rowptr2 + (size_t)br*(N+1);
    const int* csr    = csr2 + (size_t)br*(E+N);
    const float* as1  = as1b + (size_t)br*N*10;
    const float* ad1  = ad1b + (size_t)br*N*10;

    // conv1 (two head-groups of 5 to cap workspace)
    for (int hg = 0; hg < 2; ++hg){
      int h0 = hg*5;
      gat1_agg_k<<<N, 64, 0, stream>>>(rowptr, csr, x, as1, ad1, yh, yl, N, h0);
      gemm(yh, yl, 96, (long long)MPAD*96, W1th + (size_t)h0*128*96, W1tl + (size_t)h0*128*96,
           96, 128*96, nullptr, h1eh + (size_t)h0*128, h1el + (size_t)h0*128,
           1280, 128, b1 + h0*128, 128, N, 128, 96, 5, 2, 1, 1);
    }

    // conv2
    alpha2v_k<<<N, 256, 0, stream>>>(h1eh, h1el, vs, vd, as2, ad2, N);
    hipMemsetAsync(h2, 0, (size_t)N*128*4, stream);
    gemm(h1eh, h1el, 1280, 0, W2th, W2tl, 1280, 0,
         h2, nullptr, nullptr, 128, 0, nullptr, 0, N, 128, 1280, 1, 0, 2, 4);
    gat2_agg_k<<<N, 64, 0, stream>>>(rowptr, csr, h2, as2, ad2, b2, h2e, N);

    // pool + linear
    pool_split_k<<<Bg, 128, 0, stream>>>(h2e, batch, N, pooledh, pooledl);
    gemm(pooledh, pooledl, 128, 0, Wgth, Wgtl, 128, 0,
         vout, nullptr, nullptr, 128, 0, bg, 0, Bg, 128, 128, 1, 1, 0, 1);
  }

  // cell MLP
  l2norm_split_k<<<Bg, 256, 0, stream>>>(cell, 954, 960, cnh, cnl);
  gemm(cnh, cnl, 960, 0, Wr1th, Wr1tl, 960, 0, nullptr, c1h, c1l, 2048, 0,
       br1, 0, Bg, 2048, 960, 1, 1, 1, 1);
  hipMemsetAsync(c2f, 0, (size_t)Bg*512*4, stream);
  gemm(c1h, c1l, 2048, 0, Wr2th, Wr2tl, 2048, 0, c2f, nullptr, nullptr, 512, 0,
       br2, 0, Bg, 512, 2048, 1, 0, 2, 4);
  act_split_k<<<((Bg*512) + 255)/256, 256, 0, stream>>>(c2f, c2h, c2l, Bg*512);
  gemm(c2h, c2l, 512, 0, Wr3th, Wr3tl, 512, 0, c3, nullptr, nullptr, 256, 0,
       br3, 0, Bg, 256, 512, 1, 1, 0, 1);

  // final MLP
  concat_k<<<((Bg*512) + 255)/256, 256, 0, stream>>>(v1, v2, c3, xcat, Bg);
  l2norm_split_k<<<Bg, 256, 0, stream>>>(xcat, 512, 512, xcnh, xcnl);
  gemm(xcnh, xcnl, 512, 0, Wf1th, Wf1tl, 512, 0, nullptr, t1h, t1l, 1024, 0,
       bf1, 0, Bg, 1024, 512, 1, 1, 1, 1);
  hipMemsetAsync(t2f, 0, (size_t)Bg*512*4, stream);
  gemm(t1h, t1l, 1024, 0, Wf2th, Wf2tl, 1024, 0, t2f, nullptr, nullptr, 512, 0,
       bf2, 0, Bg, 512, 1024, 1, 0, 2, 4);
  act_split_k<<<((Bg*512) + 255)/256, 256, 0, stream>>>(t2f, t2h, t2l, Bg*512);
  hipMemsetAsync(t3f, 0, (size_t)Bg*128*4, stream);
  gemm(t2h, t2l, 512, 0, Wf3th, Wf3tl, 512, 0, t3f, nullptr, nullptr, 128, 0,
       bf3, 0, Bg, 128, 512, 1, 0, 2, 4);
  act_split_k<<<((Bg*128) + 255)/256, 256, 0, stream>>>(t3f, t3h, t3l, Bg*128);
  gemm(t3h, t3l, 128, 0, Woth, Wotl, 128, 0, out, nullptr, nullptr, 2, 0,
       bo, 0, Bg, 2, 128, 1, 0, 0, 1);
}

// Round 6
// 896.897 us; speedup vs baseline: 3.4151x; 1.2780x over previous
//
#include <hip/hip_runtime.h>
#include <math.h>

typedef unsigned short ushort_t;
typedef __attribute__((ext_vector_type(8))) short short8;
typedef __attribute__((ext_vector_type(8))) unsigned short ushort8v;
typedef __attribute__((ext_vector_type(4))) float float4v;
typedef __attribute__((ext_vector_type(4))) unsigned short ushort4v;

#define MPAD 30016

// ---------------- utility ----------------
__device__ __forceinline__ float lrelu02(float v){ return v > 0.f ? v : 0.2f*v; }

__device__ __forceinline__ ushort_t f2bf(float x){
  unsigned u = __float_as_uint(x);
  return (ushort_t)((u + 0x7fffu + ((u >> 16) & 1u)) >> 16);
}
__device__ __forceinline__ float bf2f(ushort_t h){ return __uint_as_float(((unsigned)h) << 16); }

__device__ __forceinline__ void gll16(const void* g, void* l){
  __builtin_amdgcn_global_load_lds((const __attribute__((address_space(1))) void*)g,
                                   (__attribute__((address_space(3))) void*)l, 16, 0, 0);
}

__global__ void fill_int_k(int* p, int v, int n){
  int i = blockIdx.x*blockDim.x + threadIdx.x;
  if (i < n) p[i] = v;
}

// ---------------- batched CSR build (both branches) ----------------
__global__ void hist2_k(const int* __restrict__ ei1, const int* __restrict__ ei2,
                        int E, int N, int* deg){
  int idx = blockIdx.x*blockDim.x + threadIdx.x;
  if (idx < 2*E){
    int br = idx / E, e = idx - br*E;
    const int* ei = br ? ei2 : ei1;
    atomicAdd(&deg[br*N + ei[E + e]], 1);
  }
}

__global__ __launch_bounds__(1024)
void scanA_k(const int* __restrict__ deg, int* __restrict__ rowptr, int* __restrict__ bsum, int n){
  int br = blockIdx.y;
  int t = threadIdx.x;
  int i = blockIdx.x*1024 + t;
  __shared__ int s[1024];
  int v = (i < n) ? deg[br*n + i] : 0;
  s[t] = v; __syncthreads();
  for (int off = 1; off < 1024; off <<= 1){
    int x = (t >= off) ? s[t - off] : 0;
    __syncthreads();
    s[t] += x;
    __syncthreads();
  }
  if (i < n) rowptr[br*(n+1) + i] = s[t] - v;
  if (t == 1023) bsum[br*gridDim.x + blockIdx.x] = s[1023];
}

__global__ void scanB_k(int* bsum, int nb){
  int br = threadIdx.x;
  if (br < 2){
    int run = 0;
    for (int i = 0; i < nb; ++i){ int v = bsum[br*nb + i]; bsum[br*nb + i] = run; run += v; }
  }
}

__global__ __launch_bounds__(1024)
void scanC_k(const int* __restrict__ bsum, int* __restrict__ rowptr, int n, int nb, int total){
  int br = blockIdx.y;
  int i = blockIdx.x*1024 + threadIdx.x;
  int add = bsum[br*nb + blockIdx.x];
  if (i < n) rowptr[br*(n+1) + i] += add;
  if (i == 0) rowptr[br*(n+1) + n] = total;
}

__global__ void init_cursor_k(const int* __restrict__ rowptr, int* cursor, int N){
  int idx = blockIdx.x*blockDim.x + threadIdx.x;
  if (idx < 2*N){ int br = idx / N, i = idx - br*N; cursor[idx] = rowptr[br*(N+1) + i]; }
}

__global__ void fill_csr2_k(const int* __restrict__ ei1, const int* __restrict__ ei2,
                            int E, int N, int* cursor, int* csr){
  int idx = blockIdx.x*blockDim.x + threadIdx.x;
  if (idx < 2*E){
    int br = idx / E, e = idx - br*E;
    const int* ei = br ? ei2 : ei1;
    int dst = ei[E + e];
    int pos = atomicAdd(&cursor[br*N + dst], 1);
    csr[br*(E+N) + pos] = ei[e];
  }
}

__global__ void self_loop2_k(int* cursor, int* csr, int E, int N){
  int idx = blockIdx.x*blockDim.x + threadIdx.x;
  if (idx < 2*N){
    int br = idx / N, i = idx - br*N;
    int pos = atomicAdd(&cursor[br*N + i], 1);
    csr[br*(E+N) + pos] = i;
  }
}

// ---------------- attention score precompute ----------------
__global__ void make_as1_k(const float* __restrict__ W1, const float* __restrict__ a_src,
                           const float* __restrict__ a_dst, float* As, float* Ad){
  int idx = blockIdx.x*blockDim.x + threadIdx.x;
  if (idx < 78*10){
    int f = idx / 10, h = idx % 10;
    float ss = 0.f, sd = 0.f;
    for (int c = 0; c < 128; ++c){
      float w = W1[f*1280 + h*128 + c];
      ss += w * a_src[h*128 + c];
      sd += w * a_dst[h*128 + c];
    }
    As[idx] = ss; Ad[idx] = sd;
  }
}

// batched over both branches: as1/ad1 sized 2*n*10
__global__ void alpha1b_k(const float* __restrict__ x1, const float* __restrict__ x2,
                          const float* __restrict__ As, const float* __restrict__ Ad,
                          float* as1, float* ad1, int n){
  int idx = blockIdx.x*blockDim.x + threadIdx.x;
  if (idx < 2*n*10){
    int br = idx / (n*10), r = idx - br*n*10;
    int i = r / 10, h = r - i*10;
    const float* xr = (br ? x2 : x1) + (size_t)i*78;
    float ss = 0.f, sd = 0.f;
    for (int f = 0; f < 78; ++f){
      float xv = xr[f];
      ss += xv * As[f*10 + h];
      sd += xv * Ad[f*10 + h];
    }
    as1[idx] = ss; ad1[idx] = sd;
  }
}

__global__ void make_vs2_k(const float* __restrict__ W2, const float* __restrict__ a_src,
                           const float* __restrict__ a_dst, float* vs, float* vd){
  int k = blockIdx.x*blockDim.x + threadIdx.x;
  if (k < 1280){
    float ss = 0.f, sd = 0.f;
    for (int c = 0; c < 128; ++c){
      float w = W2[k*128 + c];
      ss += w * a_src[c]; sd += w * a_dst[c];
    }
    vs[k] = ss; vd[k] = sd;
  }
}

// alpha2 from bf16 h1e (vectorized ushort4 loads)
__global__ __launch_bounds__(256)
void alpha2v_k(const ushort_t* __restrict__ hH,
               const float* __restrict__ vs, const float* __restrict__ vd,
               float* as2, float* ad2, int n){
  int i = blockIdx.x, t = threadIdx.x;
  __shared__ float ss[256], sd[256];
  size_t base = (size_t)i*1280;
  float ps = 0.f, pd = 0.f;
  #pragma unroll
  for (int it = 0; it < 2; ++it){
    int k0 = it*1024 + t*4;
    if (k0 < 1280){
      ushort4v h4 = *(const ushort4v*)&hH[base + k0];
      #pragma unroll
      for (int c = 0; c < 4; ++c){
        float v = bf2f(h4[c]);
        ps += v*vs[k0 + c]; pd += v*vd[k0 + c];
      }
    }
  }
  ss[t] = ps; sd[t] = pd; __syncthreads();
  for (int o = 128; o > 0; o >>= 1){
    if (t < o){ ss[t] += ss[t+o]; sd[t] += sd[t+o]; }
    __syncthreads();
  }
  if (t == 0){ as2[i] = ss[0]; ad2[i] = sd[0]; }
}

// ---------------- GATConv1 softmax + aggregate in input space ----------------
// all 10 heads; writes bf16 y[h][i][96] (f>=78 zero-padded)
__global__ __launch_bounds__(64)
void gat1_agg_k(const int* __restrict__ rowptr, const int* __restrict__ csr,
                const float* __restrict__ x, const float* __restrict__ as1,
                const float* __restrict__ ad1, ushort_t* __restrict__ yh, int n){
  int i = blockIdx.x;
  int t = threadIdx.x;
  __shared__ float adi[10], mh[10], rden[10], wE[10], xs[78];
  int beg = rowptr[i], end = rowptr[i+1];
  if (t < 10){
    float a = ad1[i*10 + t];
    adi[t] = a;
    float m = -1e30f;
    for (int e = beg; e < end; ++e){
      int s = csr[e];
      m = fmaxf(m, lrelu02(as1[s*10 + t] + a));
    }
    float den = 0.f;
    for (int e = beg; e < end; ++e){
      int s = csr[e];
      den += expf(lrelu02(as1[s*10 + t] + a) - m);
    }
    mh[t] = m; rden[t] = 1.f/(den + 1e-16f);
  }
  __syncthreads();
  float acc[13];
  int hh[13], cc[13];
  #pragma unroll
  for (int k = 0; k < 13; ++k){
    acc[k] = 0.f;
    int j = t + 64*k;
    hh[k] = (j < 780) ? (j/78) : 0;
    cc[k] = (j < 780) ? (j%78) : 0;
  }
  for (int e = beg; e < end; ++e){
    int s = csr[e];
    if (t < 10) wE[t] = expf(lrelu02(as1[s*10 + t] + adi[t]) - mh[t]) * rden[t];
    for (int c = t; c < 78; c += 64) xs[c] = x[(long long)s*78 + c];
    __syncthreads();
    #pragma unroll
    for (int k = 0; k < 13; ++k){
      int j = t + 64*k;
      if (j < 780) acc[k] += wE[hh[k]] * xs[cc[k]];
    }
    __syncthreads();
  }
  #pragma unroll
  for (int k = 0; k < 13; ++k){
    int j = t + 64*k;
    if (j < 780) yh[((size_t)hh[k]*MPAD + i)*96 + cc[k]] = f2bf(acc[k]);
  }
  for (int p = t; p < 180; p += 64){
    int h = p/18, c = 78 + p%18;
    yh[((size_t)h*MPAD + i)*96 + c] = 0;
  }
}

// ---------------- GATConv2 softmax + aggregate (128-wide) ----------------
__global__ __launch_bounds__(64)
void gat2_agg_k(const int* __restrict__ rowptr, const int* __restrict__ csr,
                const float* __restrict__ h2, const float* __restrict__ as2,
                const float* __restrict__ ad2, const float* __restrict__ b2,
                float* __restrict__ h2e, int n){
  int i = blockIdx.x, t = threadIdx.x;
  int beg = rowptr[i], end = rowptr[i+1];
  float adi = ad2[i];
  float m = -1e30f;
  for (int e = beg; e < end; ++e) m = fmaxf(m, lrelu02(as2[csr[e]] + adi));
  float den = 0.f;
  for (int e = beg; e < end; ++e) den += expf(lrelu02(as2[csr[e]] + adi) - m);
  float rden = 1.f/(den + 1e-16f);
  float a0 = 0.f, a1 = 0.f;
  for (int e = beg; e < end; ++e){
    int s = csr[e];
    float w = expf(lrelu02(as2[s] + adi) - m) * rden;
    a0 += w * h2[(long long)s*128 + t];
    a1 += w * h2[(long long)s*128 + 64 + t];
  }
  float o0 = a0 + b2[t];      o0 = o0 > 0.f ? o0 : expm1f(o0);
  float o1 = a1 + b2[64 + t]; o1 = o1 > 0.f ? o1 : expm1f(o1);
  h2e[(long long)i*128 + t]      = o0;
  h2e[(long long)i*128 + 64 + t] = o1;
}

// ---------------- global max pool (batch sorted) → split bf16 ----------------
__global__ __launch_bounds__(128)
void pool_split_k(const float* __restrict__ h2e, const int* __restrict__ batch, int n,
                  ushort_t* __restrict__ ph, ushort_t* __restrict__ pl){
  int g = blockIdx.x, t = threadIdx.x;
  int lo = 0, hi = n;
  while (lo < hi){ int mid = (lo + hi) >> 1; if (batch[mid] < g) lo = mid + 1; else hi = mid; }
  int a = lo, b = n;
  while (a < b){ int mid = (a + b) >> 1; if (batch[mid] < g + 1) a = mid + 1; else b = mid; }
  float m = -1e30f;
  for (int i = lo; i < a; ++i) m = fmaxf(m, h2e[(long long)i*128 + t]);
  ushort_t h = f2bf(m);
  ph[g*128 + t] = h; pl[g*128 + t] = f2bf(m - bf2f(h));
}

// ---------------- row-wise L2 normalize → split bf16 (K-padded) ----------------
__global__ __launch_bounds__(256)
void l2norm_split_k(const float* __restrict__ in, int cols, int Kp,
                    ushort_t* __restrict__ oh, ushort_t* __restrict__ ol){
  int r = blockIdx.x, t = threadIdx.x;
  __shared__ float s[256];
  __shared__ float scaleS;
  const float* rp = in + (size_t)r*cols;
  float p = 0.f;
  for (int k = t; k < cols; k += 256){ float v = rp[k]; p += v*v; }
  s[t] = p; __syncthreads();
  for (int o = 128; o > 0; o >>= 1){
    if (t < o) s[t] += s[t+o];
    __syncthreads();
  }
  if (t == 0) scaleS = 1.f / fmaxf(sqrtf(s[0]), 1e-12f);
  __syncthreads();
  float sc = scaleS;
  for (int k = t; k < Kp; k += 256){
    float v = (k < cols) ? rp[k]*sc : 0.f;
    ushort_t h = f2bf(v);
    size_t o2 = (size_t)r*Kp + k;
    oh[o2] = h; ol[o2] = f2bf(v - bf2f(h));
  }
}

__global__ void concat_k(const float* __restrict__ v1, const float* __restrict__ v2,
                         const float* __restrict__ c3, float* __restrict__ xcat, int B){
  int idx = blockIdx.x*blockDim.x + threadIdx.x;
  if (idx < B*512){
    int r = idx >> 9, c = idx & 511;
    float v;
    if (c < 128) v = v1[r*128 + c];
    else if (c < 256) v = v2[r*128 + (c - 128)];
    else v = c3[r*256 + (c - 256)];
    xcat[idx] = v;
  }
}

// relu + split (post split-K reduction)
__global__ void act_split_k(const float* __restrict__ in, ushort_t* __restrict__ oh,
                            ushort_t* __restrict__ ol, int n){
  int i = blockIdx.x*blockDim.x + threadIdx.x;
  if (i < n){
    float v = fmaxf(in[i], 0.f);
    ushort_t h = f2bf(v);
    oh[i] = h; ol[i] = f2bf(v - bf2f(h));
  }
}

// ---------------- weight transpose + split: Bt[n][k] = W[k][n] ----------------
__global__ void split_bt_k(const float* __restrict__ W, int ldw, int colStride,
                           int N, int K, int Np, int Kp,
                           ushort_t* __restrict__ dh, ushort_t* __restrict__ dl, int total){
  int idx = blockIdx.x*blockDim.x + threadIdx.x;
  if (idx >= total) return;
  int n  = idx % Np;
  int r  = idx / Np;
  int k4 = r % (Kp >> 2);
  int b  = r / (Kp >> 2);
  size_t o = ((size_t)b*Np + n)*Kp + (size_t)k4*4;
  ushort4v hv, lv;
  #pragma unroll
  for (int kk = 0; kk < 4; ++kk){
    int k = k4*4 + kk;
    float v = (n < N && k < K) ? W[(size_t)k*ldw + (size_t)b*colStride + n] : 0.f;
    ushort_t h = f2bf(v);
    hv[kk] = h; lv[kk] = f2bf(v - bf2f(h));
  }
  *(ushort4v*)&dh[o] = hv;
  *(ushort4v*)&dl[o] = lv;
}

// ---------------- split-bf16 MFMA GEMM v3 ----------------
// A: [M x K] bf16 row-major (hi, + optional lo if aSplit); Bt: [N x K] bf16 hi/lo.
// outMode 0: fp32 direct; 1: split bf16 coalesced; 2: fp32 atomicAdd (act deferred);
//         3: bf16 hi-only coalesced
__global__ __launch_bounds__(256)
void gemm_split(const ushort_t* __restrict__ Ahp, const ushort_t* __restrict__ Alp, int lda, long long sA,
                const ushort_t* __restrict__ Bhp, const ushort_t* __restrict__ Blp, int ldb, long long sB,
                float* __restrict__ C, ushort_t* __restrict__ Ch, ushort_t* __restrict__ Cl,
                int ldc, long long sC,
                const float* __restrict__ bias, int sBias,
                int M, int Nc, int K, int act, int outMode, int kSplit, int aSplit){
  int zb = blockIdx.z;
  int b = zb / kSplit, kc = zb - b*kSplit;
  Ahp += (long long)b*sA;
  Bhp += (long long)b*sB; Blp += (long long)b*sB;
  long long cOff = (long long)b*sC;
  int Kc = K / kSplit;
  int kb = kc*Kc;
  int nIter = Kc / 32;

  // layout: buf p at p*8192 shorts: [Ah 2048][Al 2048][Bh 2048][Bl 2048], rows [64][32]
  __shared__ ushort_t smem[16384];

  int tid = threadIdx.x, lane = tid & 63, wave = tid >> 6;
  int row0 = blockIdx.y*64, col0 = blockIdx.x*64;
  int wm = (wave & 1)*32, wn = (wave >> 1)*32;
  int lr = lane & 15, quad = lane >> 4;

  int srow = wave*16 + (lane >> 2);
  int skc  = (lane & 3)*8;
  const ushort_t* gAh = Ahp + (long long)(row0 + srow)*lda + skc + kb;
  const ushort_t* gAl = aSplit ? (Alp + (long long)b*sA + (long long)(row0 + srow)*lda + skc + kb) : gAh;
  const ushort_t* gBh = Bhp + (long long)(col0 + srow)*ldb + skc + kb;
  const ushort_t* gBl = Blp + (long long)(col0 + srow)*ldb + skc + kb;

  float4v acc[2][2];
  #pragma unroll
  for (int i = 0; i < 2; ++i)
    #pragma unroll
    for (int j = 0; j < 2; ++j)
      acc[i][j] = (float4v){0.f, 0.f, 0.f, 0.f};

  auto issue = [&](int p, int kt){
    ushort_t* base = &smem[p*8192 + wave*512];
    gll16(gAh + kt, base);
    if (aSplit) gll16(gAl + kt, base + 2048);
    gll16(gBh + kt, base + 4096);
    gll16(gBl + kt, base + 6144);
  };

  issue(0, 0);
  int p = 0;
  for (int it = 0; it < nIter; ++it){
    __syncthreads();                       // buf p landed (vmcnt drained at barrier)
    if (it + 1 < nIter) issue(p ^ 1, (it + 1)*32);
    const ushort_t* sm = &smem[p*8192];
    short8 ah[2], al[2], bh[2], bl[2];
    #pragma unroll
    for (int t2 = 0; t2 < 2; ++t2){
      int ao = (wm + t2*16 + lr)*32 + quad*8;
      int bo = (wn + t2*16 + lr)*32 + quad*8;
      ah[t2] = *(const short8*)&sm[ao];
      if (aSplit) al[t2] = *(const short8*)&sm[2048 + ao];
      bh[t2] = *(const short8*)&sm[4096 + bo];
      bl[t2] = *(const short8*)&sm[6144 + bo];
    }
    #pragma unroll
    for (int i = 0; i < 2; ++i)
      #pragma unroll
      for (int j = 0; j < 2; ++j){
        if (aSplit)
          acc[i][j] = __builtin_amdgcn_mfma_f32_16x16x32_bf16(al[i], bh[j], acc[i][j], 0, 0, 0);
        acc[i][j] = __builtin_amdgcn_mfma_f32_16x16x32_bf16(ah[i], bl[j], acc[i][j], 0, 0, 0);
        acc[i][j] = __builtin_amdgcn_mfma_f32_16x16x32_bf16(ah[i], bh[j], acc[i][j], 0, 0, 0);
      }
    p ^= 1;
  }
  __syncthreads();   // all reads done before smem reuse / epilogue

  if (outMode == 0 || outMode == 2){
    #pragma unroll
    for (int j = 0; j < 2; ++j){
      int col = col0 + wn + j*16 + lr;
      if (col >= Nc) continue;
      float bv = (bias && kc == 0) ? bias[(long long)b*sBias + col] : 0.f;
      #pragma unroll
      for (int i = 0; i < 2; ++i){
        #pragma unroll
        for (int r = 0; r < 4; ++r){
          int row = row0 + wm + i*16 + quad*4 + r;
          if (row >= M) continue;
          float v = acc[i][j][r] + bv;
          if (act == 1) v = fmaxf(v, 0.f);
          else if (act == 2) v = v > 0.f ? v : expm1f(v);
          long long o = cOff + (long long)row*ldc + col;
          if (outMode == 0) C[o] = v;
          else atomicAdd(&C[o], v);
        }
      }
    }
  } else {
    // coalesced bf16 epilogue via LDS fp32 tile (mode 1: hi+lo, mode 3: hi only)
    float* ftile = (float*)smem;           // 64x64 floats = 16 KB
    #pragma unroll
    for (int i = 0; i < 2; ++i)
      #pragma unroll
      for (int j = 0; j < 2; ++j)
        #pragma unroll
        for (int r = 0; r < 4; ++r)
          ftile[(wm + i*16 + quad*4 + r)*64 + wn + j*16 + lr] = acc[i][j][r];
    __syncthreads();
    int row = tid >> 2, ch = (tid & 3)*16;
    int grow = row0 + row;
    if (grow < M){
      if (col0 + 64 <= Nc){
        long long o = cOff + (long long)grow*ldc + col0 + ch;
        #pragma unroll
        for (int g = 0; g < 2; ++g){
          ushort8v hv, lv;
          #pragma unroll
          for (int c = 0; c < 8; ++c){
            int cc2 = ch + g*8 + c;
            float v = ftile[row*64 + cc2];
            if (bias) v += bias[(long long)b*sBias + col0 + cc2];
            if (act == 1) v = fmaxf(v, 0.f);
            else if (act == 2) v = v > 0.f ? v : expm1f(v);
            ushort_t h = f2bf(v);
            hv[c] = h; lv[c] = f2bf(v - bf2f(h));
          }
          *(ushort8v*)&Ch[o + g*8] = hv;
          if (outMode == 1) *(ushort8v*)&Cl[o + g*8] = lv;
        }
      } else {
        for (int c = 0; c < 16; ++c){
          int col = col0 + ch + c;
          if (col >= Nc) break;
          float v = ftile[row*64 + ch + c];
          if (bias) v += bias[(long long)b*sBias + col];
          if (act == 1) v = fmaxf(v, 0.f);
          else if (act == 2) v = v > 0.f ? v : expm1f(v);
          long long o = cOff + (long long)grow*ldc + col;
          ushort_t h = f2bf(v);
          Ch[o] = h;
          if (outMode == 1) Cl[o] = f2bf(v - bf2f(h));
        }
      }
    }
  }
}

// ---------------- host launch ----------------
extern "C" void kernel_launch(void* const* d_in, const int* in_sizes, int n_in,
                              void* d_out, int out_size, void* d_ws, size_t ws_size,
                              hipStream_t stream){
  const float* x1     = (const float*)d_in[0];
  const int*   ei1    = (const int*)  d_in[1];
  const int*   batch1 = (const int*)  d_in[2];
  const float* x2     = (const float*)d_in[3];
  const int*   ei2    = (const int*)  d_in[4];
  const int*   batch2 = (const int*)  d_in[5];
  const float* cell   = (const float*)d_in[6];
  const float* W1     = (const float*)d_in[7];
  const float* a_src1 = (const float*)d_in[8];
  const float* a_dst1 = (const float*)d_in[9];
  const float* b1     = (const float*)d_in[10];
  const float* W2     = (const float*)d_in[11];
  const float* a_src2 = (const float*)d_in[12];
  const float* a_dst2 = (const float*)d_in[13];
  const float* b2     = (const float*)d_in[14];
  const float* Wg     = (const float*)d_in[15];
  const float* bg     = (const float*)d_in[16];
  const float* Wr1    = (const float*)d_in[17];
  const float* br1    = (const float*)d_in[18];
  const float* Wr2    = (const float*)d_in[19];
  const float* br2    = (const float*)d_in[20];
  const float* Wr3    = (const float*)d_in[21];
  const float* br3    = (const float*)d_in[22];
  const float* Wf1    = (const float*)d_in[23];
  const float* bf1    = (const float*)d_in[24];
  const float* Wf2    = (const float*)d_in[25];
  const float* bf2    = (const float*)d_in[26];
  const float* Wf3    = (const float*)d_in[27];
  const float* bf3    = (const float*)d_in[28];
  const float* Wo     = (const float*)d_in[29];
  const float* bo     = (const float*)d_in[30];
  float* out = (float*)d_out;
  (void)n_in; (void)out_size; (void)ws_size;

  const int N  = in_sizes[0] / 78;
  const int E  = in_sizes[1] / 2;
  const int Bg = in_sizes[6] / 954;

  char* wsb = (char*)d_ws;
  size_t off = 0;
  auto alloc = [&](size_t bytes)->char*{
    char* p = wsb + off; off += ((bytes + 255)/256)*256; return p;
  };

  // big persistent buffers
  ushort_t* h1eh = (ushort_t*)alloc((size_t)MPAD*1280*2);
  // Y region: yh (all 10 heads, bf16) during conv1; h2/h2e during conv2; MLP buffers after
  char* Yb = alloc((size_t)10*MPAD*96*2);
  ushort_t* yh = (ushort_t*)Yb;
  float* h2  = (float*)Yb;
  float* h2e = (float*)(Yb + (size_t)MPAD*128*4);
  size_t yoff = 0;
  auto yalloc = [&](size_t bytes)->char*{
    char* p = Yb + yoff; yoff += ((bytes + 255)/256)*256; return p;
  };
  ushort_t* cnh  = (ushort_t*)yalloc((size_t)Bg*960*2);
  ushort_t* cnl  = (ushort_t*)yalloc((size_t)Bg*960*2);
  ushort_t* c1h  = (ushort_t*)yalloc((size_t)Bg*2048*2);
  ushort_t* c1l  = (ushort_t*)yalloc((size_t)Bg*2048*2);
  float*    c2f  = (float*)   yalloc((size_t)Bg*512*4);
  ushort_t* c2h  = (ushort_t*)yalloc((size_t)Bg*512*2);
  ushort_t* c2l  = (ushort_t*)yalloc((size_t)Bg*512*2);
  float*    c3   = (float*)   yalloc((size_t)Bg*256*4);
  float*    xcat = (float*)   yalloc((size_t)Bg*512*4);
  ushort_t* xcnh = (ushort_t*)yalloc((size_t)Bg*512*2);
  ushort_t* xcnl = (ushort_t*)yalloc((size_t)Bg*512*2);
  ushort_t* t1h  = (ushort_t*)yalloc((size_t)Bg*1024*2);
  ushort_t* t1l  = (ushort_t*)yalloc((size_t)Bg*1024*2);
  float*    t2f  = (float*)   yalloc((size_t)Bg*512*4);
  ushort_t* t2h  = (ushort_t*)yalloc((size_t)Bg*512*2);
  ushort_t* t2l  = (ushort_t*)yalloc((size_t)Bg*512*2);
  float*    t3f  = (float*)   yalloc((size_t)Bg*128*4);
  ushort_t* t3h  = (ushort_t*)yalloc((size_t)Bg*128*2);
  ushort_t* t3l  = (ushort_t*)yalloc((size_t)Bg*128*2);

  // transposed+split weights
  ushort_t* W1th = (ushort_t*)alloc((size_t)10*128*96*2);
  ushort_t* W1tl = (ushort_t*)alloc((size_t)10*128*96*2);
  ushort_t* W2th = (ushort_t*)alloc((size_t)128*1280*2);
  ushort_t* W2tl = (ushort_t*)alloc((size_t)128*1280*2);
  ushort_t* Wgth = (ushort_t*)alloc((size_t)128*128*2);
  ushort_t* Wgtl = (ushort_t*)alloc((size_t)128*128*2);
  ushort_t* Wr1th= (ushort_t*)alloc((size_t)2048*960*2);
  ushort_t* Wr1tl= (ushort_t*)alloc((size_t)2048*960*2);
  ushort_t* Wr2th= (ushort_t*)alloc((size_t)512*2048*2);
  ushort_t* Wr2tl= (ushort_t*)alloc((size_t)512*2048*2);
  ushort_t* Wr3th= (ushort_t*)alloc((size_t)256*512*2);
  ushort_t* Wr3tl= (ushort_t*)alloc((size_t)256*512*2);
  ushort_t* Wf1th= (ushort_t*)alloc((size_t)1024*512*2);
  ushort_t* Wf1tl= (ushort_t*)alloc((size_t)1024*512*2);
  ushort_t* Wf2th= (ushort_t*)alloc((size_t)512*1024*2);
  ushort_t* Wf2tl= (ushort_t*)alloc((size_t)512*1024*2);
  ushort_t* Wf3th= (ushort_t*)alloc((size_t)128*512*2);
  ushort_t* Wf3tl= (ushort_t*)alloc((size_t)128*512*2);
  ushort_t* Woth = (ushort_t*)alloc((size_t)64*128*2);
  ushort_t* Wotl = (ushort_t*)alloc((size_t)64*128*2);

  float* as1b = (float*)alloc((size_t)2*N*10*4);
  float* ad1b = (float*)alloc((size_t)2*N*10*4);
  float* as2  = (float*)alloc((size_t)N*4);
  float* ad2  = (float*)alloc((size_t)N*4);
  float* AsB  = (float*)alloc(780*4);
  float* AdB  = (float*)alloc(780*4);
  float* vs   = (float*)alloc(1280*4);
  float* vd   = (float*)alloc(1280*4);
  int* deg2    = (int*)alloc((size_t)2*N*4);
  int* rowptr2 = (int*)alloc((size_t)2*(N+1)*4);
  int* cursor2 = (int*)alloc((size_t)2*N*4);
  int* csr2    = (int*)alloc((size_t)2*(E+N)*4);
  int* bsum    = (int*)alloc((size_t)2*64*4);
  ushort_t* pooledh = (ushort_t*)alloc((size_t)Bg*128*2);
  ushort_t* pooledl = (ushort_t*)alloc((size_t)Bg*128*2);
  float* v1   = (float*)alloc((size_t)Bg*128*4);
  float* v2   = (float*)alloc((size_t)Bg*128*4);

  auto gemm = [&](const ushort_t* Ah_, const ushort_t* Al_, int lda, long long sA_,
                  const ushort_t* Bh_, const ushort_t* Bl_, int ldb, long long sB_,
                  float* C_, ushort_t* Ch_, ushort_t* Cl_, int ldc, long long sC_,
                  const float* bias_, int sBias_, int M_, int N_, int K_, int batch_,
                  int act_, int mode_, int kSplit_, int aSplit_){
    dim3 grid((N_ + 63)/64, (M_ + 63)/64, batch_*kSplit_);
    gemm_split<<<grid, 256, 0, stream>>>(Ah_, Al_, lda, sA_, Bh_, Bl_, ldb, sB_,
                                         C_, Ch_, Cl_, ldc, sC_, bias_, sBias_,
                                         M_, N_, K_, act_, mode_, kSplit_, aSplit_);
  };
  auto splitBt = [&](const float* W_, int ldw_, int colStride_, int N_, int K_,
                     int Np_, int Kp_, ushort_t* dh_, ushort_t* dl_, int batch_){
    int total = batch_*Np_*(Kp_ >> 2);
    split_bt_k<<<(total + 255)/256, 256, 0, stream>>>(W_, ldw_, colStride_, N_, K_,
                                                      Np_, Kp_, dh_, dl_, total);
  };

  // ---- weight prep ----
  splitBt(W1, 1280, 128, 128, 78, 128, 96, W1th, W1tl, 10);
  splitBt(W2, 128, 0, 128, 1280, 128, 1280, W2th, W2tl, 1);
  splitBt(Wg, 128, 0, 128, 128, 128, 128, Wgth, Wgtl, 1);
  splitBt(Wr1, 2048, 0, 2048, 954, 2048, 960, Wr1th, Wr1tl, 1);
  splitBt(Wr2, 512, 0, 512, 2048, 512, 2048, Wr2th, Wr2tl, 1);
  splitBt(Wr3, 256, 0, 256, 512, 256, 512, Wr3th, Wr3tl, 1);
  splitBt(Wf1, 1024, 0, 1024, 512, 1024, 512, Wf1th, Wf1tl, 1);
  splitBt(Wf2, 512, 0, 512, 1024, 512, 1024, Wf2th, Wf2tl, 1);
  splitBt(Wf3, 128, 0, 128, 512, 128, 512, Wf3th, Wf3tl, 1);
  splitBt(Wo, 2, 0, 2, 128, 64, 128, Woth, Wotl, 1);
  make_as1_k<<<(780 + 255)/256, 256, 0, stream>>>(W1, a_src1, a_dst1, AsB, AdB);
  make_vs2_k<<<(1280 + 255)/256, 256, 0, stream>>>(W2, a_src2, a_dst2, vs, vd);
  alpha1b_k<<<((2*N*10) + 255)/256, 256, 0, stream>>>(x1, x2, AsB, AdB, as1b, ad1b, N);

  // ---- batched CSR build (both branches) ----
  const int NB = (N + 1023)/1024;
  fill_int_k<<<((2*N) + 255)/256, 256, 0, stream>>>(deg2, 1, 2*N);
  hist2_k<<<((2*E) + 255)/256, 256, 0, stream>>>(ei1, ei2, E, N, deg2);
  scanA_k<<<dim3(NB, 2), 1024, 0, stream>>>(deg2, rowptr2, bsum, N);
  scanB_k<<<1, 64, 0, stream>>>(bsum, NB);
  scanC_k<<<dim3(NB, 2), 1024, 0, stream>>>(bsum, rowptr2, N, NB, E + N);
  init_cursor_k<<<((2*N) + 255)/256, 256, 0, stream>>>(rowptr2, cursor2, N);
  fill_csr2_k<<<((2*E) + 255)/256, 256, 0, stream>>>(ei1, ei2, E, N, cursor2, csr2);
  self_loop2_k<<<((2*N) + 255)/256, 256, 0, stream>>>(cursor2, csr2, E, N);

  for (int br = 0; br < 2; ++br){
    const float* x   = br ? x2 : x1;
    const int* batch = br ? batch2 : batch1;
    float* vout      = br ? v2 : v1;
    const int* rowptr = rowptr2 + (size_t)br*(N+1);
    const int* csr    = csr2 + (size_t)br*(E+N);
    const float* as1  = as1b + (size_t)br*N*10;
    const float* ad1  = ad1b + (size_t)br*N*10;

    // conv1: one aggregate pass (10 heads, bf16) + one batch-10 GEMM
    gat1_agg_k<<<N, 64, 0, stream>>>(rowptr, csr, x, as1, ad1, yh, N);
    gemm(yh, nullptr, 96, (long long)MPAD*96, W1th, W1tl, 96, 128*96,
         nullptr, h1eh, nullptr, 1280, 128, b1, 128, N, 128, 96, 10, 2, 3, 1, 0);

    // conv2 (A = bf16 h1e, W split => W effectively fp32)
    alpha2v_k<<<N, 256, 0, stream>>>(h1eh, vs, vd, as2, ad2, N);
    gemm(h1eh, nullptr, 1280, 0, W2th, W2tl, 1280, 0,
         h2, nullptr, nullptr, 128, 0, nullptr, 0, N, 128, 1280, 1, 0, 0, 1, 0);
    gat2_agg_k<<<N, 64, 0, stream>>>(rowptr, csr, h2, as2, ad2, b2, h2e, N);

    // pool + linear
    pool_split_k<<<Bg, 128, 0, stream>>>(h2e, batch, N, pooledh, pooledl);
    gemm(pooledh, pooledl, 128, 0, Wgth, Wgtl, 128, 0,
         vout, nullptr, nullptr, 128, 0, bg, 0, Bg, 128, 128, 1, 1, 0, 1, 1);
  }

  // cell MLP
  l2norm_split_k<<<Bg, 256, 0, stream>>>(cell, 954, 960, cnh, cnl);
  gemm(cnh, cnl, 960, 0, Wr1th, Wr1tl, 960, 0, nullptr, c1h, c1l, 2048, 0,
       br1, 0, Bg, 2048, 960, 1, 1, 1, 1, 1);
  hipMemsetAsync(c2f, 0, (size_t)Bg*512*4, stream);
  gemm(c1h, c1l, 2048, 0, Wr2th, Wr2tl, 2048, 0, c2f, nullptr, nullptr, 512, 0,
       br2, 0, Bg, 512, 2048, 1, 0, 2, 4, 1);
  act_split_k<<<((Bg*512) + 255)/256, 256, 0, stream>>>(c2f, c2h, c2l, Bg*512);
  gemm(c2h, c2l, 512, 0, Wr3th, Wr3tl, 512, 0, c3, nullptr, nullptr, 256, 0,
       br3, 0, Bg, 256, 512, 1, 1, 0, 1, 1);

  // final MLP
  concat_k<<<((Bg*512) + 255)/256, 256, 0, stream>>>(v1, v2, c3, xcat, Bg);
  l2norm_split_k<<<Bg, 256, 0, stream>>>(xcat, 512, 512, xcnh, xcnl);
  gemm(xcnh, xcnl, 512, 0, Wf1th, Wf1tl, 512, 0, nullptr, t1h, t1l, 1024, 0,
       bf1, 0, Bg, 1024, 512, 1, 1, 1, 1, 1);
  hipMemsetAsync(t2f, 0, (size_t)Bg*512*4, stream);
  gemm(t1h, t1l, 1024, 0, Wf2th, Wf2tl, 1024, 0, t2f, nullptr, nullptr, 512, 0,
       bf2, 0, Bg, 512, 1024, 1, 0, 2, 4, 1);
  act_split_k<<<((Bg*512) + 255)/256, 256, 0, stream>>>(t2f, t2h, t2l, Bg*512);
  hipMemsetAsync(t3f, 0, (size_t)Bg*128*4, stream);
  gemm(t2h, t2l, 512, 0, Wf3th, Wf3tl, 512, 0, t3f, nullptr, nullptr, 128, 0,
       bf3, 0, Bg, 128, 512, 1, 0, 2, 4, 1);
  act_split_k<<<((Bg*128) + 255)/256, 256, 0, stream>>>(t3f, t3h, t3l, Bg*128);
  gemm(t3h, t3l, 128, 0, Woth, Wotl, 128, 0, out, nullptr, nullptr, 2, 0,
       bo, 0, Bg, 2, 128, 1, 0, 0, 1, 1);
}

// Round 7
// 769.716 us; speedup vs baseline: 3.9794x; 1.1652x over previous
//
#include <hip/hip_runtime.h>
#include <math.h>

typedef unsigned short ushort_t;
typedef __attribute__((ext_vector_type(8))) short short8;
typedef __attribute__((ext_vector_type(8))) unsigned short ushort8v;
typedef __attribute__((ext_vector_type(4))) float float4v;
typedef __attribute__((ext_vector_type(4))) unsigned short ushort4v;

#define MPAD 30016

// ---------------- utility ----------------
__device__ __forceinline__ float lrelu02(float v){ return v > 0.f ? v : 0.2f*v; }
__device__ __forceinline__ float elu_fast(float v){ return v > 0.f ? v : (__expf(v) - 1.f); }

__device__ __forceinline__ ushort_t f2bf(float x){
  unsigned u = __float_as_uint(x);
  return (ushort_t)((u + 0x7fffu + ((u >> 16) & 1u)) >> 16);
}
__device__ __forceinline__ float bf2f(ushort_t h){ return __uint_as_float(((unsigned)h) << 16); }

__device__ __forceinline__ void gll16(const void* g, void* l){
  __builtin_amdgcn_global_load_lds((const __attribute__((address_space(1))) void*)g,
                                   (__attribute__((address_space(3))) void*)l, 16, 0, 0);
}

__global__ void fill_int_k(int* p, int v, int n){
  int i = blockIdx.x*blockDim.x + threadIdx.x;
  if (i < n) p[i] = v;
}

// ---------------- batched CSR build (both branches) ----------------
__global__ void hist2_k(const int* __restrict__ ei1, const int* __restrict__ ei2,
                        int E, int N, int* deg){
  int idx = blockIdx.x*blockDim.x + threadIdx.x;
  if (idx < 2*E){
    int br = idx / E, e = idx - br*E;
    const int* ei = br ? ei2 : ei1;
    atomicAdd(&deg[br*N + ei[E + e]], 1);
  }
}

__global__ __launch_bounds__(1024)
void scanA_k(const int* __restrict__ deg, int* __restrict__ rowptr, int* __restrict__ bsum, int n){
  int br = blockIdx.y;
  int t = threadIdx.x;
  int i = blockIdx.x*1024 + t;
  __shared__ int s[1024];
  int v = (i < n) ? deg[br*n + i] : 0;
  s[t] = v; __syncthreads();
  for (int off = 1; off < 1024; off <<= 1){
    int x = (t >= off) ? s[t - off] : 0;
    __syncthreads();
    s[t] += x;
    __syncthreads();
  }
  if (i < n) rowptr[br*(n+1) + i] = s[t] - v;
  if (t == 1023) bsum[br*gridDim.x + blockIdx.x] = s[1023];
}

__global__ void scanB_k(int* bsum, int nb){
  int br = threadIdx.x;
  if (br < 2){
    int run = 0;
    for (int i = 0; i < nb; ++i){ int v = bsum[br*nb + i]; bsum[br*nb + i] = run; run += v; }
  }
}

__global__ __launch_bounds__(1024)
void scanC_k(const int* __restrict__ bsum, int* __restrict__ rowptr, int n, int nb, int total){
  int br = blockIdx.y;
  int i = blockIdx.x*1024 + threadIdx.x;
  int add = bsum[br*nb + blockIdx.x];
  if (i < n) rowptr[br*(n+1) + i] += add;
  if (i == 0) rowptr[br*(n+1) + n] = total;
}

__global__ void init_cursor_k(const int* __restrict__ rowptr, int* cursor, int N){
  int idx = blockIdx.x*blockDim.x + threadIdx.x;
  if (idx < 2*N){ int br = idx / N, i = idx - br*N; cursor[idx] = rowptr[br*(N+1) + i]; }
}

__global__ void fill_csr2_k(const int* __restrict__ ei1, const int* __restrict__ ei2,
                            int E, int N, int* cursor, int* csr){
  int idx = blockIdx.x*blockDim.x + threadIdx.x;
  if (idx < 2*E){
    int br = idx / E, e = idx - br*E;
    const int* ei = br ? ei2 : ei1;
    int dst = ei[E + e];
    int pos = atomicAdd(&cursor[br*N + dst], 1);
    csr[br*(E+N) + pos] = ei[e];
  }
}

__global__ void self_loop2_k(int* cursor, int* csr, int E, int N){
  int idx = blockIdx.x*blockDim.x + threadIdx.x;
  if (idx < 2*N){
    int br = idx / N, i = idx - br*N;
    int pos = atomicAdd(&cursor[br*N + i], 1);
    csr[br*(E+N) + pos] = i;
  }
}

// ---------------- attention score precompute (merged) ----------------
__global__ void mkattn_k(const float* __restrict__ W1, const float* __restrict__ a_src1,
                         const float* __restrict__ a_dst1,
                         const float* __restrict__ W2, const float* __restrict__ a_src2,
                         const float* __restrict__ a_dst2,
                         float* As, float* Ad, float* vs, float* vd){
  int idx = blockIdx.x*blockDim.x + threadIdx.x;
  if (idx < 780){
    int f = idx / 10, h = idx % 10;
    float ss = 0.f, sd = 0.f;
    for (int c = 0; c < 128; ++c){
      float w = W1[f*1280 + h*128 + c];
      ss += w * a_src1[h*128 + c];
      sd += w * a_dst1[h*128 + c];
    }
    As[idx] = ss; Ad[idx] = sd;
  } else if (idx < 2060){
    int k = idx - 780;
    float ss = 0.f, sd = 0.f;
    for (int c = 0; c < 128; ++c){
      float w = W2[k*128 + c];
      ss += w * a_src2[c]; sd += w * a_dst2[c];
    }
    vs[k] = ss; vd[k] = sd;
  }
}

// node-per-thread alpha1 (both branches); As/Ad staged in LDS
__global__ __launch_bounds__(256)
void alpha1b_k(const float* __restrict__ x1, const float* __restrict__ x2,
               const float* __restrict__ As, const float* __restrict__ Ad,
               float* as1, float* ad1, int n){
  __shared__ float sAs[780], sAd[780];
  int t = threadIdx.x;
  for (int k = t; k < 780; k += 256){ sAs[k] = As[k]; sAd[k] = Ad[k]; }
  __syncthreads();
  int idx = blockIdx.x*256 + t;
  if (idx >= 2*n) return;
  int br = idx / n, i = idx - br*n;
  const float* xr = (br ? x2 : x1) + (size_t)i*78;
  float ss[10], sd[10];
  #pragma unroll
  for (int h = 0; h < 10; ++h){ ss[h] = 0.f; sd[h] = 0.f; }
  for (int f = 0; f < 78; ++f){
    float xv = xr[f];
    #pragma unroll
    for (int h = 0; h < 10; ++h){
      ss[h] += xv * sAs[f*10 + h];
      sd[h] += xv * sAd[f*10 + h];
    }
  }
  #pragma unroll
  for (int h = 0; h < 10; ++h){
    as1[(size_t)idx*10 + h] = ss[h];
    ad1[(size_t)idx*10 + h] = sd[h];
  }
}

// ---------------- GATConv1 softmax + aggregate in input space ----------------
// all 10 heads; writes bf16 y[h][i][96] (f>=78 zero-padded)
__global__ __launch_bounds__(64)
void gat1_agg_k(const int* __restrict__ rowptr, const int* __restrict__ csr,
                const float* __restrict__ x, const float* __restrict__ as1,
                const float* __restrict__ ad1, ushort_t* __restrict__ yh, int n){
  int i = blockIdx.x;
  int t = threadIdx.x;
  __shared__ float adi[10], mh[10], rden[10], wE[10], xs[78];
  int beg = rowptr[i], end = rowptr[i+1];
  if (t < 10){
    float a = ad1[i*10 + t];
    adi[t] = a;
    float m = -1e30f;
    for (int e = beg; e < end; ++e){
      int s = csr[e];
      m = fmaxf(m, lrelu02(as1[s*10 + t] + a));
    }
    float den = 0.f;
    for (int e = beg; e < end; ++e){
      int s = csr[e];
      den += __expf(lrelu02(as1[s*10 + t] + a) - m);
    }
    mh[t] = m; rden[t] = 1.f/(den + 1e-16f);
  }
  __syncthreads();
  float acc[13];
  int hh[13], cc[13];
  #pragma unroll
  for (int k = 0; k < 13; ++k){
    acc[k] = 0.f;
    int j = t + 64*k;
    hh[k] = (j < 780) ? (j/78) : 0;
    cc[k] = (j < 780) ? (j%78) : 0;
  }
  for (int e = beg; e < end; ++e){
    int s = csr[e];
    if (t < 10) wE[t] = __expf(lrelu02(as1[s*10 + t] + adi[t]) - mh[t]) * rden[t];
    for (int c = t; c < 78; c += 64) xs[c] = x[(long long)s*78 + c];
    __syncthreads();
    #pragma unroll
    for (int k = 0; k < 13; ++k){
      int j = t + 64*k;
      if (j < 780) acc[k] += wE[hh[k]] * xs[cc[k]];
    }
    __syncthreads();
  }
  #pragma unroll
  for (int k = 0; k < 13; ++k){
    int j = t + 64*k;
    if (j < 780) yh[((size_t)hh[k]*MPAD + i)*96 + cc[k]] = f2bf(acc[k]);
  }
  for (int p = t; p < 180; p += 64){
    int h = p/18, c = 78 + p%18;
    yh[((size_t)h*MPAD + i)*96 + c] = 0;
  }
}

// ---------------- fused conv2 GEMM + alpha2 ----------------
// A = h1eh [MPAD x 1280] bf16 hi; B = W2t hi/lo [128 x 1280]; out h2 fp32 [M x 128]
// plus per-row as2/ad2 = h1e . vs / vd
__global__ __launch_bounds__(256)
void conv2_fused_k(const ushort_t* __restrict__ Ahp,
                   const ushort_t* __restrict__ Bhp, const ushort_t* __restrict__ Blp,
                   const float* __restrict__ vs, const float* __restrict__ vd,
                   float* __restrict__ h2, float* __restrict__ as2, float* __restrict__ ad2,
                   int M){
  // buf p at p*10240 shorts: [Ah 2048][Bh 4096][Bl 4096]; rows x 32 k
  __shared__ ushort_t smem[20480];
  int tid = threadIdx.x, lane = tid & 63, wave = tid >> 6;
  int row0 = blockIdx.x*64;
  int wm = (wave & 1)*32, wn = (wave >> 1)*64;
  int lr = lane & 15, quad = lane >> 4;

  int sr = lane >> 2;
  int skc = (lane & 3)*8;
  const ushort_t* gA   = Ahp + (size_t)(row0 + wave*16 + sr)*1280 + skc;
  const ushort_t* gB1  = Bhp + (size_t)(wave*32 + sr)*1280 + skc;
  const ushort_t* gB2  = Bhp + (size_t)(wave*32 + 16 + sr)*1280 + skc;
  const ushort_t* gB1l = Blp + (size_t)(wave*32 + sr)*1280 + skc;
  const ushort_t* gB2l = Blp + (size_t)(wave*32 + 16 + sr)*1280 + skc;

  float4v acc[2][4];
  #pragma unroll
  for (int i = 0; i < 2; ++i)
    #pragma unroll
    for (int j = 0; j < 4; ++j)
      acc[i][j] = (float4v){0.f, 0.f, 0.f, 0.f};

  float ps = 0.f, pd = 0.f;
  int arow = tid >> 2;          // 0..63: my alpha row
  int akc  = (tid & 3)*8;       // my 8-k chunk

  auto issue = [&](int p, int kt){
    ushort_t* base = &smem[p*10240];
    gll16(gA   + kt, base + wave*512);
    gll16(gB1  + kt, base + 2048 + wave*1024);
    gll16(gB2  + kt, base + 2048 + wave*1024 + 512);
    gll16(gB1l + kt, base + 6144 + wave*1024);
    gll16(gB2l + kt, base + 6144 + wave*1024 + 512);
  };

  issue(0, 0);
  int p = 0;
  for (int it = 0; it < 40; ++it){
    __syncthreads();
    if (it + 1 < 40) issue(p ^ 1, (it + 1)*32);
    const ushort_t* sm = &smem[p*10240];
    short8 ah[2], bh[4], bl[4];
    #pragma unroll
    for (int t2 = 0; t2 < 2; ++t2)
      ah[t2] = *(const short8*)&sm[(wm + t2*16 + lr)*32 + quad*8];
    #pragma unroll
    for (int j = 0; j < 4; ++j){
      int nb = (wn + j*16 + lr)*32 + quad*8;
      bh[j] = *(const short8*)&sm[2048 + nb];
      bl[j] = *(const short8*)&sm[6144 + nb];
    }
    #pragma unroll
    for (int i = 0; i < 2; ++i)
      #pragma unroll
      for (int j = 0; j < 4; ++j){
        acc[i][j] = __builtin_amdgcn_mfma_f32_16x16x32_bf16(ah[i], bl[j], acc[i][j], 0, 0, 0);
        acc[i][j] = __builtin_amdgcn_mfma_f32_16x16x32_bf16(ah[i], bh[j], acc[i][j], 0, 0, 0);
      }
    // alpha2 partial from A tile in LDS
    {
      const ushort_t* ar = &sm[arow*32 + akc];
      int kg = it*32 + akc;
      #pragma unroll
      for (int c = 0; c < 8; ++c){
        float v = bf2f(ar[c]);
        ps += v*vs[kg + c]; pd += v*vd[kg + c];
      }
    }
    p ^= 1;
  }
  __syncthreads();

  // h2 store (fp32 direct)
  #pragma unroll
  for (int j = 0; j < 4; ++j){
    int col = wn + j*16 + lr;
    #pragma unroll
    for (int i = 0; i < 2; ++i){
      #pragma unroll
      for (int r = 0; r < 4; ++r){
        int row = row0 + wm + i*16 + quad*4 + r;
        if (row < M) h2[(size_t)row*128 + col] = acc[i][j][r];
      }
    }
  }
  // alpha2 reduce (4 partials per row)
  float* sc = (float*)smem;
  sc[tid] = ps; sc[256 + tid] = pd;
  __syncthreads();
  if (tid < 64){
    int grow = row0 + tid;
    if (grow < M){
      as2[grow] = sc[tid*4] + sc[tid*4+1] + sc[tid*4+2] + sc[tid*4+3];
      ad2[grow] = sc[256+tid*4] + sc[256+tid*4+1] + sc[256+tid*4+2] + sc[256+tid*4+3];
    }
  }
}

// ---------------- GATConv2 softmax + aggregate (128-wide) ----------------
__global__ __launch_bounds__(64)
void gat2_agg_k(const int* __restrict__ rowptr, const int* __restrict__ csr,
                const float* __restrict__ h2, const float* __restrict__ as2,
                const float* __restrict__ ad2, const float* __restrict__ b2,
                float* __restrict__ h2e, int n){
  int i = blockIdx.x, t = threadIdx.x;
  int beg = rowptr[i], end = rowptr[i+1];
  float adi = ad2[i];
  float m = -1e30f;
  for (int e = beg; e < end; ++e) m = fmaxf(m, lrelu02(as2[csr[e]] + adi));
  float den = 0.f;
  for (int e = beg; e < end; ++e) den += __expf(lrelu02(as2[csr[e]] + adi) - m);
  float rden = 1.f/(den + 1e-16f);
  float a0 = 0.f, a1 = 0.f;
  for (int e = beg; e < end; ++e){
    int s = csr[e];
    float w = __expf(lrelu02(as2[s] + adi) - m) * rden;
    a0 += w * h2[(long long)s*128 + t];
    a1 += w * h2[(long long)s*128 + 64 + t];
  }
  h2e[(long long)i*128 + t]      = elu_fast(a0 + b2[t]);
  h2e[(long long)i*128 + 64 + t] = elu_fast(a1 + b2[64 + t]);
}

// ---------------- global max pool (batch sorted) → split bf16 ----------------
__global__ __launch_bounds__(128)
void pool_split_k(const float* __restrict__ h2e, const int* __restrict__ batch, int n,
                  ushort_t* __restrict__ ph, ushort_t* __restrict__ pl){
  int g = blockIdx.x, t = threadIdx.x;
  int lo = 0, hi = n;
  while (lo < hi){ int mid = (lo + hi) >> 1; if (batch[mid] < g) lo = mid + 1; else hi = mid; }
  int a = lo, b = n;
  while (a < b){ int mid = (a + b) >> 1; if (batch[mid] < g + 1) a = mid + 1; else b = mid; }
  float m = -1e30f;
  for (int i = lo; i < a; ++i) m = fmaxf(m, h2e[(long long)i*128 + t]);
  ushort_t h = f2bf(m);
  ph[g*128 + t] = h; pl[g*128 + t] = f2bf(m - bf2f(h));
}

// ---------------- row-wise L2 normalize → split bf16 (K-padded) ----------------
__global__ __launch_bounds__(256)
void l2norm_split_k(const float* __restrict__ in, int cols, int Kp,
                    ushort_t* __restrict__ oh, ushort_t* __restrict__ ol){
  int r = blockIdx.x, t = threadIdx.x;
  __shared__ float s[256];
  __shared__ float scaleS;
  const float* rp = in + (size_t)r*cols;
  float p = 0.f;
  for (int k = t; k < cols; k += 256){ float v = rp[k]; p += v*v; }
  s[t] = p; __syncthreads();
  for (int o = 128; o > 0; o >>= 1){
    if (t < o) s[t] += s[t+o];
    __syncthreads();
  }
  if (t == 0) scaleS = 1.f / fmaxf(sqrtf(s[0]), 1e-12f);
  __syncthreads();
  float sc = scaleS;
  for (int k = t; k < Kp; k += 256){
    float v = (k < cols) ? rp[k]*sc : 0.f;
    ushort_t h = f2bf(v);
    size_t o2 = (size_t)r*Kp + k;
    oh[o2] = h; ol[o2] = f2bf(v - bf2f(h));
  }
}

__global__ void concat_k(const float* __restrict__ v1, const float* __restrict__ v2,
                         const float* __restrict__ c3, float* __restrict__ xcat, int B){
  int idx = blockIdx.x*blockDim.x + threadIdx.x;
  if (idx < B*512){
    int r = idx >> 9, c = idx & 511;
    float v;
    if (c < 128) v = v1[r*128 + c];
    else if (c < 256) v = v2[r*128 + (c - 128)];
    else v = c3[r*256 + (c - 256)];
    xcat[idx] = v;
  }
}

// relu + split (post split-K reduction)
__global__ void act_split_k(const float* __restrict__ in, ushort_t* __restrict__ oh,
                            ushort_t* __restrict__ ol, int n){
  int i = blockIdx.x*blockDim.x + threadIdx.x;
  if (i < n){
    float v = fmaxf(in[i], 0.f);
    ushort_t h = f2bf(v);
    oh[i] = h; ol[i] = f2bf(v - bf2f(h));
  }
}

// ---------------- merged weight transpose + split ----------------
__device__ __forceinline__ void split_one(const float* __restrict__ W, int ldw, int colStride,
                                          int N, int K, int Np, int Kp,
                                          ushort_t* __restrict__ dh, ushort_t* __restrict__ dl,
                                          int idx){
  int n  = idx % Np;
  int r  = idx / Np;
  int k4 = r % (Kp >> 2);
  int b  = r / (Kp >> 2);
  size_t o = ((size_t)b*Np + n)*Kp + (size_t)k4*4;
  ushort4v hv, lv;
  #pragma unroll
  for (int kk = 0; kk < 4; ++kk){
    int k = k4*4 + kk;
    float v = (n < N && k < K) ? W[(size_t)k*ldw + (size_t)b*colStride + n] : 0.f;
    ushort_t h = f2bf(v);
    hv[kk] = h; lv[kk] = f2bf(v - bf2f(h));
  }
  *(ushort4v*)&dh[o] = hv;
  *(ushort4v*)&dl[o] = lv;
}

struct SplitTable {
  const float *W1, *W2, *Wg, *Wr1, *Wr2, *Wr3, *Wf1, *Wf2, *Wf3, *Wo;
  ushort_t *W1h,*W1l,*W2h,*W2l,*Wgh,*Wgl,*Wr1h,*Wr1l,*Wr2h,*Wr2l;
  ushort_t *Wr3h,*Wr3l,*Wf1h,*Wf1l,*Wf2h,*Wf2l,*Wf3h,*Wf3l,*Woh,*Wol;
};

__global__ void split_all_k(SplitTable T){
  int idx = blockIdx.x*blockDim.x + threadIdx.x;
  if      (idx <   30720) split_one(T.W1, 1280, 128, 128,   78,  128,   96, T.W1h, T.W1l, idx);
  else if (idx <   71680) split_one(T.W2,  128,   0, 128, 1280,  128, 1280, T.W2h, T.W2l, idx -   30720);
  else if (idx <   75776) split_one(T.Wg,  128,   0, 128,  128,  128,  128, T.Wgh, T.Wgl, idx -   71680);
  else if (idx <  567296) split_one(T.Wr1,2048,   0,2048,  954, 2048,  960, T.Wr1h,T.Wr1l,idx -   75776);
  else if (idx <  829440) split_one(T.Wr2, 512,   0, 512, 2048,  512, 2048, T.Wr2h,T.Wr2l,idx -  567296);
  else if (idx <  862208) split_one(T.Wr3, 256,   0, 256,  512,  256,  512, T.Wr3h,T.Wr3l,idx -  829440);
  else if (idx <  993280) split_one(T.Wf1,1024,   0,1024,  512, 1024,  512, T.Wf1h,T.Wf1l,idx -  862208);
  else if (idx < 1124352) split_one(T.Wf2, 512,   0, 512, 1024,  512, 1024, T.Wf2h,T.Wf2l,idx -  993280);
  else if (idx < 1140736) split_one(T.Wf3, 128,   0, 128,  512,  128,  512, T.Wf3h,T.Wf3l,idx - 1124352);
  else if (idx < 1142784) split_one(T.Wo,    2,   0,   2,  128,   64,  128, T.Woh, T.Wol, idx - 1140736);
}

// ---------------- split-bf16 MFMA GEMM ----------------
// A: [M x K] bf16 row-major (hi, + optional lo if aSplit); Bt: [N x K] bf16 hi/lo.
// outMode 0: fp32 direct; 1: split bf16 coalesced; 2: fp32 atomicAdd (act deferred);
//         3: bf16 hi-only coalesced
__global__ __launch_bounds__(256)
void gemm_split(const ushort_t* __restrict__ Ahp, const ushort_t* __restrict__ Alp, int lda, long long sA,
                const ushort_t* __restrict__ Bhp, const ushort_t* __restrict__ Blp, int ldb, long long sB,
                float* __restrict__ C, ushort_t* __restrict__ Ch, ushort_t* __restrict__ Cl,
                int ldc, long long sC,
                const float* __restrict__ bias, int sBias,
                int M, int Nc, int K, int act, int outMode, int kSplit, int aSplit){
  int zb = blockIdx.z;
  int b = zb / kSplit, kc = zb - b*kSplit;
  Ahp += (long long)b*sA;
  Bhp += (long long)b*sB; Blp += (long long)b*sB;
  long long cOff = (long long)b*sC;
  int Kc = K / kSplit;
  int kb = kc*Kc;
  int nIter = Kc / 32;

  // layout: buf p at p*8192 shorts: [Ah 2048][Al 2048][Bh 2048][Bl 2048], rows [64][32]
  __shared__ ushort_t smem[18048];   // max(2*8192, 64*68 floats = 4352*2 shorts ... ) fp32 tile needs 64*68*4B = 17408B = 8704 shorts; dbuf needs 16384

  int tid = threadIdx.x, lane = tid & 63, wave = tid >> 6;
  int row0 = blockIdx.y*64, col0 = blockIdx.x*64;
  int wm = (wave & 1)*32, wn = (wave >> 1)*32;
  int lr = lane & 15, quad = lane >> 4;

  int srow = wave*16 + (lane >> 2);
  int skc  = (lane & 3)*8;
  const ushort_t* gAh = Ahp + (long long)(row0 + srow)*lda + skc + kb;
  const ushort_t* gAl = aSplit ? (Alp + (long long)b*sA + (long long)(row0 + srow)*lda + skc + kb) : gAh;
  const ushort_t* gBh = Bhp + (long long)(col0 + srow)*ldb + skc + kb;
  const ushort_t* gBl = Blp + (long long)(col0 + srow)*ldb + skc + kb;

  float4v acc[2][2];
  #pragma unroll
  for (int i = 0; i < 2; ++i)
    #pragma unroll
    for (int j = 0; j < 2; ++j)
      acc[i][j] = (float4v){0.f, 0.f, 0.f, 0.f};

  auto issue = [&](int p, int kt){
    ushort_t* base = &smem[p*8192 + wave*512];
    gll16(gAh + kt, base);
    if (aSplit) gll16(gAl + kt, base + 2048);
    gll16(gBh + kt, base + 4096);
    gll16(gBl + kt, base + 6144);
  };

  issue(0, 0);
  int p = 0;
  for (int it = 0; it < nIter; ++it){
    __syncthreads();
    if (it + 1 < nIter) issue(p ^ 1, (it + 1)*32);
    const ushort_t* sm = &smem[p*8192];
    short8 ah[2], al[2], bh[2], bl[2];
    #pragma unroll
    for (int t2 = 0; t2 < 2; ++t2){
      int ao = (wm + t2*16 + lr)*32 + quad*8;
      int bo = (wn + t2*16 + lr)*32 + quad*8;
      ah[t2] = *(const short8*)&sm[ao];
      if (aSplit) al[t2] = *(const short8*)&sm[2048 + ao];
      bh[t2] = *(const short8*)&sm[4096 + bo];
      bl[t2] = *(const short8*)&sm[6144 + bo];
    }
    #pragma unroll
    for (int i = 0; i < 2; ++i)
      #pragma unroll
      for (int j = 0; j < 2; ++j){
        if (aSplit)
          acc[i][j] = __builtin_amdgcn_mfma_f32_16x16x32_bf16(al[i], bh[j], acc[i][j], 0, 0, 0);
        acc[i][j] = __builtin_amdgcn_mfma_f32_16x16x32_bf16(ah[i], bl[j], acc[i][j], 0, 0, 0);
        acc[i][j] = __builtin_amdgcn_mfma_f32_16x16x32_bf16(ah[i], bh[j], acc[i][j], 0, 0, 0);
      }
    p ^= 1;
  }
  __syncthreads();

  if (outMode == 0 || outMode == 2){
    #pragma unroll
    for (int j = 0; j < 2; ++j){
      int col = col0 + wn + j*16 + lr;
      if (col >= Nc) continue;
      float bv = (bias && kc == 0) ? bias[(long long)b*sBias + col] : 0.f;
      #pragma unroll
      for (int i = 0; i < 2; ++i){
        #pragma unroll
        for (int r = 0; r < 4; ++r){
          int row = row0 + wm + i*16 + quad*4 + r;
          if (row >= M) continue;
          float v = acc[i][j][r] + bv;
          if (act == 1) v = fmaxf(v, 0.f);
          else if (act == 2) v = elu_fast(v);
          long long o = cOff + (long long)row*ldc + col;
          if (outMode == 0) C[o] = v;
          else atomicAdd(&C[o], v);
        }
      }
    }
  } else {
    // coalesced bf16 epilogue via LDS fp32 tile, stride 68 (mode 1: hi+lo, mode 3: hi only)
    float* ftile = (float*)smem;           // 64 x 68 floats = 17408 B
    #pragma unroll
    for (int i = 0; i < 2; ++i)
      #pragma unroll
      for (int j = 0; j < 2; ++j)
        #pragma unroll
        for (int r = 0; r < 4; ++r)
          ftile[(wm + i*16 + quad*4 + r)*68 + wn + j*16 + lr] = acc[i][j][r];
    __syncthreads();
    int row = tid >> 2, ch = (tid & 3)*16;
    int grow = row0 + row;
    if (grow < M){
      if (col0 + 64 <= Nc){
        long long o = cOff + (long long)grow*ldc + col0 + ch;
        #pragma unroll
        for (int g = 0; g < 2; ++g){
          ushort8v hv, lv;
          #pragma unroll
          for (int c = 0; c < 8; ++c){
            int cc2 = ch + g*8 + c;
            float v = ftile[row*68 + cc2];
            if (bias) v += bias[(long long)b*sBias + col0 + cc2];
            if (act == 1) v = fmaxf(v, 0.f);
            else if (act == 2) v = elu_fast(v);
            hv[c] = f2bf(v);
            if (outMode == 1) lv[c] = f2bf(v - bf2f(hv[c]));
          }
          *(ushort8v*)&Ch[o + g*8] = hv;
          if (outMode == 1) *(ushort8v*)&Cl[o + g*8] = lv;
        }
      } else {
        for (int c = 0; c < 16; ++c){
          int col = col0 + ch + c;
          if (col >= Nc) break;
          float v = ftile[row*68 + ch + c];
          if (bias) v += bias[(long long)b*sBias + col];
          if (act == 1) v = fmaxf(v, 0.f);
          else if (act == 2) v = elu_fast(v);
          long long o = cOff + (long long)grow*ldc + col;
          ushort_t h = f2bf(v);
          Ch[o] = h;
          if (outMode == 1) Cl[o] = f2bf(v - bf2f(h));
        }
      }
    }
  }
}

// ---------------- host launch ----------------
extern "C" void kernel_launch(void* const* d_in, const int* in_sizes, int n_in,
                              void* d_out, int out_size, void* d_ws, size_t ws_size,
                              hipStream_t stream){
  const float* x1     = (const float*)d_in[0];
  const int*   ei1    = (const int*)  d_in[1];
  const int*   batch1 = (const int*)  d_in[2];
  const float* x2     = (const float*)d_in[3];
  const int*   ei2    = (const int*)  d_in[4];
  const int*   batch2 = (const int*)  d_in[5];
  const float* cell   = (const float*)d_in[6];
  const float* W1     = (const float*)d_in[7];
  const float* a_src1 = (const float*)d_in[8];
  const float* a_dst1 = (const float*)d_in[9];
  const float* b1     = (const float*)d_in[10];
  const float* W2     = (const float*)d_in[11];
  const float* a_src2 = (const float*)d_in[12];
  const float* a_dst2 = (const float*)d_in[13];
  const float* b2     = (const float*)d_in[14];
  const float* Wg     = (const float*)d_in[15];
  const float* bg     = (const float*)d_in[16];
  const float* Wr1    = (const float*)d_in[17];
  const float* br1    = (const float*)d_in[18];
  const float* Wr2    = (const float*)d_in[19];
  const float* br2    = (const float*)d_in[20];
  const float* Wr3    = (const float*)d_in[21];
  const float* br3    = (const float*)d_in[22];
  const float* Wf1    = (const float*)d_in[23];
  const float* bf1    = (const float*)d_in[24];
  const float* Wf2    = (const float*)d_in[25];
  const float* bf2    = (const float*)d_in[26];
  const float* Wf3    = (const float*)d_in[27];
  const float* bf3    = (const float*)d_in[28];
  const float* Wo     = (const float*)d_in[29];
  const float* bo     = (const float*)d_in[30];
  float* out = (float*)d_out;
  (void)n_in; (void)out_size; (void)ws_size;

  const int N  = in_sizes[0] / 78;
  const int E  = in_sizes[1] / 2;
  const int Bg = in_sizes[6] / 954;

  char* wsb = (char*)d_ws;
  size_t off = 0;
  auto alloc = [&](size_t bytes)->char*{
    char* p = wsb + off; off += ((bytes + 255)/256)*256; return p;
  };

  // big persistent buffers
  ushort_t* h1eh = (ushort_t*)alloc((size_t)MPAD*1280*2);
  // Y region: yh (all 10 heads, bf16) during conv1; h2/h2e during conv2; MLP buffers after
  char* Yb = alloc((size_t)10*MPAD*96*2);
  ushort_t* yh = (ushort_t*)Yb;
  float* h2  = (float*)Yb;
  float* h2e = (float*)(Yb + (size_t)MPAD*128*4);
  size_t yoff = 0;
  auto yalloc = [&](size_t bytes)->char*{
    char* p = Yb + yoff; yoff += ((bytes + 255)/256)*256; return p;
  };
  ushort_t* cnh  = (ushort_t*)yalloc((size_t)Bg*960*2);
  ushort_t* cnl  = (ushort_t*)yalloc((size_t)Bg*960*2);
  ushort_t* c1h  = (ushort_t*)yalloc((size_t)Bg*2048*2);
  ushort_t* c1l  = (ushort_t*)yalloc((size_t)Bg*2048*2);
  float*    c2f  = (float*)   yalloc((size_t)Bg*512*4);
  ushort_t* c2h  = (ushort_t*)yalloc((size_t)Bg*512*2);
  ushort_t* c2l  = (ushort_t*)yalloc((size_t)Bg*512*2);
  float*    c3   = (float*)   yalloc((size_t)Bg*256*4);
  float*    xcat = (float*)   yalloc((size_t)Bg*512*4);
  ushort_t* xcnh = (ushort_t*)yalloc((size_t)Bg*512*2);
  ushort_t* xcnl = (ushort_t*)yalloc((size_t)Bg*512*2);
  ushort_t* t1h  = (ushort_t*)yalloc((size_t)Bg*1024*2);
  ushort_t* t1l  = (ushort_t*)yalloc((size_t)Bg*1024*2);
  float*    t2f  = (float*)   yalloc((size_t)Bg*512*4);
  ushort_t* t2h  = (ushort_t*)yalloc((size_t)Bg*512*2);
  ushort_t* t2l  = (ushort_t*)yalloc((size_t)Bg*512*2);
  float*    t3f  = (float*)   yalloc((size_t)Bg*128*4);
  ushort_t* t3h  = (ushort_t*)yalloc((size_t)Bg*128*2);
  ushort_t* t3l  = (ushort_t*)yalloc((size_t)Bg*128*2);

  // transposed+split weights
  ushort_t* W1th = (ushort_t*)alloc((size_t)10*128*96*2);
  ushort_t* W1tl = (ushort_t*)alloc((size_t)10*128*96*2);
  ushort_t* W2th = (ushort_t*)alloc((size_t)128*1280*2);
  ushort_t* W2tl = (ushort_t*)alloc((size_t)128*1280*2);
  ushort_t* Wgth = (ushort_t*)alloc((size_t)128*128*2);
  ushort_t* Wgtl = (ushort_t*)alloc((size_t)128*128*2);
  ushort_t* Wr1th= (ushort_t*)alloc((size_t)2048*960*2);
  ushort_t* Wr1tl= (ushort_t*)alloc((size_t)2048*960*2);
  ushort_t* Wr2th= (ushort_t*)alloc((size_t)512*2048*2);
  ushort_t* Wr2tl= (ushort_t*)alloc((size_t)512*2048*2);
  ushort_t* Wr3th= (ushort_t*)alloc((size_t)256*512*2);
  ushort_t* Wr3tl= (ushort_t*)alloc((size_t)256*512*2);
  ushort_t* Wf1th= (ushort_t*)alloc((size_t)1024*512*2);
  ushort_t* Wf1tl= (ushort_t*)alloc((size_t)1024*512*2);
  ushort_t* Wf2th= (ushort_t*)alloc((size_t)512*1024*2);
  ushort_t* Wf2tl= (ushort_t*)alloc((size_t)512*1024*2);
  ushort_t* Wf3th= (ushort_t*)alloc((size_t)128*512*2);
  ushort_t* Wf3tl= (ushort_t*)alloc((size_t)128*512*2);
  ushort_t* Woth = (ushort_t*)alloc((size_t)64*128*2);
  ushort_t* Wotl = (ushort_t*)alloc((size_t)64*128*2);

  float* as1b = (float*)alloc((size_t)2*N*10*4);
  float* ad1b = (float*)alloc((size_t)2*N*10*4);
  float* as2  = (float*)alloc((size_t)N*4);
  float* ad2  = (float*)alloc((size_t)N*4);
  float* AsB  = (float*)alloc(780*4);
  float* AdB  = (float*)alloc(780*4);
  float* vs   = (float*)alloc(1280*4);
  float* vd   = (float*)alloc(1280*4);
  int* deg2    = (int*)alloc((size_t)2*N*4);
  int* rowptr2 = (int*)alloc((size_t)2*(N+1)*4);
  int* cursor2 = (int*)alloc((size_t)2*N*4);
  int* csr2    = (int*)alloc((size_t)2*(E+N)*4);
  int* bsum    = (int*)alloc((size_t)2*64*4);
  ushort_t* pooledh = (ushort_t*)alloc((size_t)Bg*128*2);
  ushort_t* pooledl = (ushort_t*)alloc((size_t)Bg*128*2);
  float* v1   = (float*)alloc((size_t)Bg*128*4);
  float* v2   = (float*)alloc((size_t)Bg*128*4);

  auto gemm = [&](const ushort_t* Ah_, const ushort_t* Al_, int lda, long long sA_,
                  const ushort_t* Bh_, const ushort_t* Bl_, int ldb, long long sB_,
                  float* C_, ushort_t* Ch_, ushort_t* Cl_, int ldc, long long sC_,
                  const float* bias_, int sBias_, int M_, int N_, int K_, int batch_,
                  int act_, int mode_, int kSplit_, int aSplit_){
    dim3 grid((N_ + 63)/64, (M_ + 63)/64, batch_*kSplit_);
    gemm_split<<<grid, 256, 0, stream>>>(Ah_, Al_, lda, sA_, Bh_, Bl_, ldb, sB_,
                                         C_, Ch_, Cl_, ldc, sC_, bias_, sBias_,
                                         M_, N_, K_, act_, mode_, kSplit_, aSplit_);
  };

  // ---- weight prep (single merged launch) ----
  SplitTable T;
  T.W1 = W1; T.W2 = W2; T.Wg = Wg; T.Wr1 = Wr1; T.Wr2 = Wr2; T.Wr3 = Wr3;
  T.Wf1 = Wf1; T.Wf2 = Wf2; T.Wf3 = Wf3; T.Wo = Wo;
  T.W1h = W1th; T.W1l = W1tl; T.W2h = W2th; T.W2l = W2tl; T.Wgh = Wgth; T.Wgl = Wgtl;
  T.Wr1h = Wr1th; T.Wr1l = Wr1tl; T.Wr2h = Wr2th; T.Wr2l = Wr2tl;
  T.Wr3h = Wr3th; T.Wr3l = Wr3tl; T.Wf1h = Wf1th; T.Wf1l = Wf1tl;
  T.Wf2h = Wf2th; T.Wf2l = Wf2tl; T.Wf3h = Wf3th; T.Wf3l = Wf3tl;
  T.Woh = Woth; T.Wol = Wotl;
  split_all_k<<<(1142784 + 255)/256, 256, 0, stream>>>(T);
  mkattn_k<<<(2060 + 255)/256, 256, 0, stream>>>(W1, a_src1, a_dst1, W2, a_src2, a_dst2,
                                                 AsB, AdB, vs, vd);
  alpha1b_k<<<((2*N) + 255)/256, 256, 0, stream>>>(x1, x2, AsB, AdB, as1b, ad1b, N);

  // ---- batched CSR build (both branches) ----
  const int NB = (N + 1023)/1024;
  fill_int_k<<<((2*N) + 255)/256, 256, 0, stream>>>(deg2, 1, 2*N);
  hist2_k<<<((2*E) + 255)/256, 256, 0, stream>>>(ei1, ei2, E, N, deg2);
  scanA_k<<<dim3(NB, 2), 1024, 0, stream>>>(deg2, rowptr2, bsum, N);
  scanB_k<<<1, 64, 0, stream>>>(bsum, NB);
  scanC_k<<<dim3(NB, 2), 1024, 0, stream>>>(bsum, rowptr2, N, NB, E + N);
  init_cursor_k<<<((2*N) + 255)/256, 256, 0, stream>>>(rowptr2, cursor2, N);
  fill_csr2_k<<<((2*E) + 255)/256, 256, 0, stream>>>(ei1, ei2, E, N, cursor2, csr2);
  self_loop2_k<<<((2*N) + 255)/256, 256, 0, stream>>>(cursor2, csr2, E, N);

  for (int br = 0; br < 2; ++br){
    const float* x   = br ? x2 : x1;
    const int* batch = br ? batch2 : batch1;
    float* vout      = br ? v2 : v1;
    const int* rowptr = rowptr2 + (size_t)br*(N+1);
    const int* csr    = csr2 + (size_t)br*(E+N);
    const float* as1  = as1b + (size_t)br*N*10;
    const float* ad1  = ad1b + (size_t)br*N*10;

    // conv1: aggregate (10 heads, bf16) + batch-10 GEMM (bf16-hi out)
    gat1_agg_k<<<N, 64, 0, stream>>>(rowptr, csr, x, as1, ad1, yh, N);
    gemm(yh, nullptr, 96, (long long)MPAD*96, W1th, W1tl, 96, 128*96,
         nullptr, h1eh, nullptr, 1280, 128, b1, 128, N, 128, 96, 10, 2, 3, 1, 0);

    // conv2 GEMM fused with alpha2
    conv2_fused_k<<<(N + 63)/64, 256, 0, stream>>>(h1eh, W2th, W2tl, vs, vd,
                                                   h2, as2, ad2, N);
    gat2_agg_k<<<N, 64, 0, stream>>>(rowptr, csr, h2, as2, ad2, b2, h2e, N);

    // pool + linear
    pool_split_k<<<Bg, 128, 0, stream>>>(h2e, batch, N, pooledh, pooledl);
    gemm(pooledh, pooledl, 128, 0, Wgth, Wgtl, 128, 0,
         vout, nullptr, nullptr, 128, 0, bg, 0, Bg, 128, 128, 1, 1, 0, 1, 1);
  }

  // cell MLP
  l2norm_split_k<<<Bg, 256, 0, stream>>>(cell, 954, 960, cnh, cnl);
  gemm(cnh, cnl, 960, 0, Wr1th, Wr1tl, 960, 0, nullptr, c1h, c1l, 2048, 0,
       br1, 0, Bg, 2048, 960, 1, 1, 1, 1, 1);
  hipMemsetAsync(c2f, 0, (size_t)Bg*512*4, stream);
  gemm(c1h, c1l, 2048, 0, Wr2th, Wr2tl, 2048, 0, c2f, nullptr, nullptr, 512, 0,
       br2, 0, Bg, 512, 2048, 1, 0, 2, 4, 1);
  act_split_k<<<((Bg*512) + 255)/256, 256, 0, stream>>>(c2f, c2h, c2l, Bg*512);
  gemm(c2h, c2l, 512, 0, Wr3th, Wr3tl, 512, 0, c3, nullptr, nullptr, 256, 0,
       br3, 0, Bg, 256, 512, 1, 1, 0, 1, 1);

  // final MLP
  concat_k<<<((Bg*512) + 255)/256, 256, 0, stream>>>(v1, v2, c3, xcat, Bg);
  l2norm_split_k<<<Bg, 256, 0, stream>>>(xcat, 512, 512, xcnh, xcnl);
  gemm(xcnh, xcnl, 512, 0, Wf1th, Wf1tl, 512, 0, nullptr, t1h, t1l, 1024, 0,
       bf1, 0, Bg, 1024, 512, 1, 1, 1, 1, 1);
  hipMemsetAsync(t2f, 0, (size_t)Bg*512*4, stream);
  gemm(t1h, t1l, 1024, 0, Wf2th, Wf2tl, 1024, 0, t2f, nullptr, nullptr, 512, 0,
       bf2, 0, Bg, 512, 1024, 1, 0, 2, 4, 1);
  act_split_k<<<((Bg*512) + 255)/256, 256, 0, stream>>>(t2f, t2h, t2l, Bg*512);
  hipMemsetAsync(t3f, 0, (size_t)Bg*128*4, stream);
  gemm(t2h, t2l, 512, 0, Wf3th, Wf3tl, 512, 0, t3f, nullptr, nullptr, 128, 0,
       bf3, 0, Bg, 128, 512, 1, 0, 2, 4, 1);
  act_split_k<<<((Bg*128) + 255)/256, 256, 0, stream>>>(t3f, t3h, t3l, Bg*128);
  gemm(t3h, t3l, 128, 0, Woth, Wotl, 128, 0, out, nullptr, nullptr, 2, 0,
       bo, 0, Bg, 2, 128, 1, 0, 0, 1, 1);
}

// Round 8
// 686.753 us; speedup vs baseline: 4.4602x; 1.1208x over previous
//
#include <hip/hip_runtime.h>
#include <math.h>

typedef unsigned short ushort_t;
typedef __attribute__((ext_vector_type(8))) short short8;
typedef __attribute__((ext_vector_type(8))) unsigned short ushort8v;
typedef __attribute__((ext_vector_type(4))) float float4v;
typedef __attribute__((ext_vector_type(4))) unsigned short ushort4v;

#define MPAD 30016
#define H1STR 136

// ---------------- utility ----------------
__device__ __forceinline__ float lrelu02(float v){ return v > 0.f ? v : 0.2f*v; }
__device__ __forceinline__ float elu_fast(float v){ return v > 0.f ? v : (__expf(v) - 1.f); }

__device__ __forceinline__ ushort_t f2bf(float x){
  unsigned u = __float_as_uint(x);
  return (ushort_t)((u + 0x7fffu + ((u >> 16) & 1u)) >> 16);
}
__device__ __forceinline__ float bf2f(ushort_t h){ return __uint_as_float(((unsigned)h) << 16); }

__device__ __forceinline__ void gll16(const void* g, void* l){
  __builtin_amdgcn_global_load_lds((const __attribute__((address_space(1))) void*)g,
                                   (__attribute__((address_space(3))) void*)l, 16, 0, 0);
}

__global__ void fill_int_k(int* p, int v, int n){
  int i = blockIdx.x*blockDim.x + threadIdx.x;
  if (i < n) p[i] = v;
}

// ---------------- batched CSR build (both branches) ----------------
__global__ void hist2_k(const int* __restrict__ ei1, const int* __restrict__ ei2,
                        int E, int N, int* deg){
  int idx = blockIdx.x*blockDim.x + threadIdx.x;
  if (idx < 2*E){
    int br = idx / E, e = idx - br*E;
    const int* ei = br ? ei2 : ei1;
    atomicAdd(&deg[br*N + ei[E + e]], 1);
  }
}

__global__ __launch_bounds__(1024)
void scanA_k(const int* __restrict__ deg, int* __restrict__ rowptr, int* __restrict__ bsum, int n){
  int br = blockIdx.y;
  int t = threadIdx.x;
  int i = blockIdx.x*1024 + t;
  __shared__ int s[1024];
  int v = (i < n) ? deg[br*n + i] : 0;
  s[t] = v; __syncthreads();
  for (int off = 1; off < 1024; off <<= 1){
    int x = (t >= off) ? s[t - off] : 0;
    __syncthreads();
    s[t] += x;
    __syncthreads();
  }
  if (i < n) rowptr[br*(n+1) + i] = s[t] - v;
  if (t == 1023) bsum[br*gridDim.x + blockIdx.x] = s[1023];
}

__global__ void scanB_k(int* bsum, int nb){
  int br = threadIdx.x;
  if (br < 2){
    int run = 0;
    for (int i = 0; i < nb; ++i){ int v = bsum[br*nb + i]; bsum[br*nb + i] = run; run += v; }
  }
}

__global__ __launch_bounds__(1024)
void scanC_k(const int* __restrict__ bsum, int* __restrict__ rowptr, int n, int nb, int total){
  int br = blockIdx.y;
  int i = blockIdx.x*1024 + threadIdx.x;
  int add = bsum[br*nb + blockIdx.x];
  if (i < n) rowptr[br*(n+1) + i] += add;
  if (i == 0) rowptr[br*(n+1) + n] = total;
}

__global__ void init_cursor_k(const int* __restrict__ rowptr, int* cursor, int N){
  int idx = blockIdx.x*blockDim.x + threadIdx.x;
  if (idx < 2*N){ int br = idx / N, i = idx - br*N; cursor[idx] = rowptr[br*(N+1) + i]; }
}

__global__ void fill_csr2_k(const int* __restrict__ ei1, const int* __restrict__ ei2,
                            int E, int N, int* cursor, int* csr){
  int idx = blockIdx.x*blockDim.x + threadIdx.x;
  if (idx < 2*E){
    int br = idx / E, e = idx - br*E;
    const int* ei = br ? ei2 : ei1;
    int dst = ei[E + e];
    int pos = atomicAdd(&cursor[br*N + dst], 1);
    csr[br*(E+N) + pos] = ei[e];
  }
}

__global__ void self_loop2_k(int* cursor, int* csr, int E, int N){
  int idx = blockIdx.x*blockDim.x + threadIdx.x;
  if (idx < 2*N){
    int br = idx / N, i = idx - br*N;
    int pos = atomicAdd(&cursor[br*N + i], 1);
    csr[br*(E+N) + pos] = i;
  }
}

// ---------------- attention score precompute (merged) ----------------
__global__ void mkattn_k(const float* __restrict__ W1, const float* __restrict__ a_src1,
                         const float* __restrict__ a_dst1,
                         const float* __restrict__ W2, const float* __restrict__ a_src2,
                         const float* __restrict__ a_dst2,
                         float* As, float* Ad, float* vs, float* vd){
  int idx = blockIdx.x*blockDim.x + threadIdx.x;
  if (idx < 780){
    int f = idx / 10, h = idx % 10;
    float ss = 0.f, sd = 0.f;
    for (int c = 0; c < 128; ++c){
      float w = W1[f*1280 + h*128 + c];
      ss += w * a_src1[h*128 + c];
      sd += w * a_dst1[h*128 + c];
    }
    As[idx] = ss; Ad[idx] = sd;
  } else if (idx < 2060){
    int k = idx - 780;
    float ss = 0.f, sd = 0.f;
    for (int c = 0; c < 128; ++c){
      float w = W2[k*128 + c];
      ss += w * a_src2[c]; sd += w * a_dst2[c];
    }
    vs[k] = ss; vd[k] = sd;
  }
}

// node-per-thread alpha1 (both branches); As/Ad staged in LDS
__global__ __launch_bounds__(256)
void alpha1b_k(const float* __restrict__ x1, const float* __restrict__ x2,
               const float* __restrict__ As, const float* __restrict__ Ad,
               float* as1, float* ad1, int n){
  __shared__ float sAs[780], sAd[780];
  int t = threadIdx.x;
  for (int k = t; k < 780; k += 256){ sAs[k] = As[k]; sAd[k] = Ad[k]; }
  __syncthreads();
  int idx = blockIdx.x*256 + t;
  if (idx >= 2*n) return;
  int br = idx / n, i = idx - br*n;
  const float* xr = (br ? x2 : x1) + (size_t)i*78;
  float ss[10], sd[10];
  #pragma unroll
  for (int h = 0; h < 10; ++h){ ss[h] = 0.f; sd[h] = 0.f; }
  for (int f = 0; f < 78; ++f){
    float xv = xr[f];
    #pragma unroll
    for (int h = 0; h < 10; ++h){
      ss[h] += xv * sAs[f*10 + h];
      sd[h] += xv * sAd[f*10 + h];
    }
  }
  #pragma unroll
  for (int h = 0; h < 10; ++h){
    as1[(size_t)idx*10 + h] = ss[h];
    ad1[(size_t)idx*10 + h] = sd[h];
  }
}

// ---------------- GATConv1 softmax + aggregate in input space ----------------
// all 10 heads; writes bf16 y[h][i][96] (f>=78 zero-padded)
__global__ __launch_bounds__(64)
void gat1_agg_k(const int* __restrict__ rowptr, const int* __restrict__ csr,
                const float* __restrict__ x, const float* __restrict__ as1,
                const float* __restrict__ ad1, ushort_t* __restrict__ yh, int n){
  int i = blockIdx.x;
  int t = threadIdx.x;
  __shared__ float adi[10], mh[10], rden[10], wE[10], xs[78];
  int beg = rowptr[i], end = rowptr[i+1];
  if (t < 10){
    float a = ad1[i*10 + t];
    adi[t] = a;
    float m = -1e30f;
    for (int e = beg; e < end; ++e){
      int s = csr[e];
      m = fmaxf(m, lrelu02(as1[s*10 + t] + a));
    }
    float den = 0.f;
    for (int e = beg; e < end; ++e){
      int s = csr[e];
      den += __expf(lrelu02(as1[s*10 + t] + a) - m);
    }
    mh[t] = m; rden[t] = 1.f/(den + 1e-16f);
  }
  __syncthreads();
  float acc[13];
  int hh[13], cc[13];
  #pragma unroll
  for (int k = 0; k < 13; ++k){
    acc[k] = 0.f;
    int j = t + 64*k;
    hh[k] = (j < 780) ? (j/78) : 0;
    cc[k] = (j < 780) ? (j%78) : 0;
  }
  for (int e = beg; e < end; ++e){
    int s = csr[e];
    if (t < 10) wE[t] = __expf(lrelu02(as1[s*10 + t] + adi[t]) - mh[t]) * rden[t];
    for (int c = t; c < 78; c += 64) xs[c] = x[(long long)s*78 + c];
    __syncthreads();
    #pragma unroll
    for (int k = 0; k < 13; ++k){
      int j = t + 64*k;
      if (j < 780) acc[k] += wE[hh[k]] * xs[cc[k]];
    }
    __syncthreads();
  }
  #pragma unroll
  for (int k = 0; k < 13; ++k){
    int j = t + 64*k;
    if (j < 780) yh[((size_t)hh[k]*MPAD + i)*96 + cc[k]] = f2bf(acc[k]);
  }
  for (int p = t; p < 180; p += 64){
    int h = p/18, c = 78 + p%18;
    yh[((size_t)h*MPAD + i)*96 + c] = 0;
  }
}

// ---------------- fused branch conv: conv1 GEMM + ELU + conv2 GEMM + alpha2 ----------------
// y [10][MPAD][96] bf16; W1t hi/lo [10][128][96]; W2t hi/lo [128][1280]
// out: h2 fp32 [M][128], as2, ad2. h1e never leaves the CU.
__global__ __launch_bounds__(256)
void branch_conv_k(const ushort_t* __restrict__ y,
                   const ushort_t* __restrict__ W1h, const ushort_t* __restrict__ W1l,
                   const ushort_t* __restrict__ W2h, const ushort_t* __restrict__ W2l,
                   const float* __restrict__ b1, const float* __restrict__ vs,
                   const float* __restrict__ vd,
                   float* __restrict__ h2, float* __restrict__ as2, float* __restrict__ ad2,
                   int M){
  __shared__ ushort_t stage[2][10240];   // [A 2048][Bh 4096][Bl 4096] shorts
  __shared__ ushort_t h1t[64*H1STR];
  __shared__ float red[256];

  int tid = threadIdx.x, lane = tid & 63, wave = tid >> 6;
  int row0 = blockIdx.x*64;
  int wm = (wave & 1)*32, wn = (wave >> 1)*64;
  int lr = lane & 15, quad = lane >> 4;
  int sr = lane >> 2;
  int skc = (((lane & 3) ^ ((lane >> 3) & 3)) * 8);   // xor-swizzled source k-offset
  int qs  = (quad ^ ((lr >> 1) & 3)) * 8;             // frag-read slot

  float4v acc2[2][4];
  #pragma unroll
  for (int i = 0; i < 2; ++i)
    #pragma unroll
    for (int j = 0; j < 4; ++j)
      acc2[i][j] = (float4v){0.f, 0.f, 0.f, 0.f};
  float rps[8], rpd[8];
  #pragma unroll
  for (int z = 0; z < 8; ++z){ rps[z] = 0.f; rpd[z] = 0.f; }

  for (int h = 0; h < 10; ++h){
    const ushort_t* gA   = y   + ((size_t)h*MPAD + row0 + wave*16 + sr)*96 + skc;
    const ushort_t* gB0h = W1h + ((size_t)(h*128 + wave*32      + sr))*96 + skc;
    const ushort_t* gB1h = W1h + ((size_t)(h*128 + wave*32 + 16 + sr))*96 + skc;
    const ushort_t* gB0l = W1l + ((size_t)(h*128 + wave*32      + sr))*96 + skc;
    const ushort_t* gB1l = W1l + ((size_t)(h*128 + wave*32 + 16 + sr))*96 + skc;
    const ushort_t* gC0h = W2h + ((size_t)(wave*32      + sr))*1280 + h*128 + skc;
    const ushort_t* gC1h = W2h + ((size_t)(wave*32 + 16 + sr))*1280 + h*128 + skc;
    const ushort_t* gC0l = W2l + ((size_t)(wave*32      + sr))*1280 + h*128 + skc;
    const ushort_t* gC1l = W2l + ((size_t)(wave*32 + 16 + sr))*1280 + h*128 + skc;

    auto issue1 = [&](int p, int kt){
      ushort_t* st = &stage[p][0];
      gll16(gA   + kt, st + wave*512);
      gll16(gB0h + kt, st + 2048 + wave*1024);
      gll16(gB1h + kt, st + 2048 + wave*1024 + 512);
      gll16(gB0l + kt, st + 6144 + wave*1024);
      gll16(gB1l + kt, st + 6144 + wave*1024 + 512);
    };
    auto issue2 = [&](int p, int kt){
      ushort_t* st = &stage[p][0];
      gll16(gC0h + kt, st + 2048 + wave*1024);
      gll16(gC1h + kt, st + 2048 + wave*1024 + 512);
      gll16(gC0l + kt, st + 6144 + wave*1024);
      gll16(gC1l + kt, st + 6144 + wave*1024 + 512);
    };

    // ---- P1: h1e_h = y_h @ W1_h (K=96) ----
    __syncthreads();                 // prior-phase stage reads complete
    issue1(0, 0);
    float4v acc1[2][4];
    #pragma unroll
    for (int i = 0; i < 2; ++i)
      #pragma unroll
      for (int j = 0; j < 4; ++j)
        acc1[i][j] = (float4v){0.f, 0.f, 0.f, 0.f};
    int p = 0;
    #pragma unroll
    for (int it = 0; it < 3; ++it){
      __syncthreads();
      if (it < 2) issue1(p ^ 1, (it + 1)*32);
      const ushort_t* sm = &stage[p][0];
      short8 af[2], bhf[4], blf[4];
      #pragma unroll
      for (int t2 = 0; t2 < 2; ++t2)
        af[t2] = *(const short8*)&sm[(wm + t2*16 + lr)*32 + qs];
      #pragma unroll
      for (int j = 0; j < 4; ++j){
        int nb = (wn + j*16 + lr)*32 + qs;
        bhf[j] = *(const short8*)&sm[2048 + nb];
        blf[j] = *(const short8*)&sm[6144 + nb];
      }
      #pragma unroll
      for (int i = 0; i < 2; ++i)
        #pragma unroll
        for (int j = 0; j < 4; ++j){
          acc1[i][j] = __builtin_amdgcn_mfma_f32_16x16x32_bf16(af[i], blf[j], acc1[i][j], 0, 0, 0);
          acc1[i][j] = __builtin_amdgcn_mfma_f32_16x16x32_bf16(af[i], bhf[j], acc1[i][j], 0, 0, 0);
        }
      p ^= 1;
    }

    // ---- ELU + bias; write h1t; accumulate alpha2 from fp32 values ----
    #pragma unroll
    for (int j = 0; j < 4; ++j){
      int col = wn + j*16 + lr;
      float bv  = b1[h*128 + col];
      float vsv = vs[h*128 + col];
      float vdv = vd[h*128 + col];
      #pragma unroll
      for (int i = 0; i < 2; ++i){
        #pragma unroll
        for (int r = 0; r < 4; ++r){
          float v = elu_fast(acc1[i][j][r] + bv);
          h1t[(wm + i*16 + quad*4 + r)*H1STR + col] = f2bf(v);
          rps[i*4 + r] += v * vsv;
          rpd[i*4 + r] += v * vdv;
        }
      }
    }
    __syncthreads();                 // h1t ready; P1 stage reads done

    // ---- P2: h2 += h1e_tile @ W2[h*128:(h+1)*128, :] (K=128) ----
    issue2(0, 0);
    p = 0;
    #pragma unroll
    for (int it = 0; it < 4; ++it){
      __syncthreads();
      if (it < 3) issue2(p ^ 1, (it + 1)*32);
      const ushort_t* sm = &stage[p][0];
      int kt = it*32;
      short8 af[2], bhf[4], blf[4];
      #pragma unroll
      for (int t2 = 0; t2 < 2; ++t2)
        af[t2] = *(const short8*)&h1t[(wm + t2*16 + lr)*H1STR + kt + quad*8];
      #pragma unroll
      for (int j = 0; j < 4; ++j){
        int nb = (wn + j*16 + lr)*32 + qs;
        bhf[j] = *(const short8*)&sm[2048 + nb];
        blf[j] = *(const short8*)&sm[6144 + nb];
      }
      #pragma unroll
      for (int i = 0; i < 2; ++i)
        #pragma unroll
        for (int j = 0; j < 4; ++j){
          acc2[i][j] = __builtin_amdgcn_mfma_f32_16x16x32_bf16(af[i], blf[j], acc2[i][j], 0, 0, 0);
          acc2[i][j] = __builtin_amdgcn_mfma_f32_16x16x32_bf16(af[i], bhf[j], acc2[i][j], 0, 0, 0);
        }
      p ^= 1;
    }
  }

  // ---- h2 store ----
  #pragma unroll
  for (int j = 0; j < 4; ++j){
    int col = wn + j*16 + lr;
    #pragma unroll
    for (int i = 0; i < 2; ++i){
      #pragma unroll
      for (int r = 0; r < 4; ++r){
        int row = row0 + wm + i*16 + quad*4 + r;
        if (row < M) h2[(size_t)row*128 + col] = acc2[i][j][r];
      }
    }
  }
  // ---- alpha2 reduce: shuffle over lr (16-lane groups), then LDS across wn-waves ----
  __syncthreads();
  #pragma unroll
  for (int z = 0; z < 8; ++z){
    float a = rps[z], d = rpd[z];
    #pragma unroll
    for (int mk = 1; mk <= 8; mk <<= 1){
      a += __shfl_xor(a, mk);
      d += __shfl_xor(d, mk);
    }
    if (lr == 0){
      int i = z >> 2, r = z & 3;
      int row = wm + i*16 + quad*4 + r;
      red[row*2 + (wave >> 1)] = a;
      red[128 + row*2 + (wave >> 1)] = d;
    }
  }
  __syncthreads();
  if (tid < 64){
    int grow = row0 + tid;
    if (grow < M){
      as2[grow] = red[tid*2] + red[tid*2 + 1];
      ad2[grow] = red[128 + tid*2] + red[128 + tid*2 + 1];
    }
  }
}

// ---------------- GATConv2 softmax + aggregate (128-wide) ----------------
__global__ __launch_bounds__(64)
void gat2_agg_k(const int* __restrict__ rowptr, const int* __restrict__ csr,
                const float* __restrict__ h2, const float* __restrict__ as2,
                const float* __restrict__ ad2, const float* __restrict__ b2,
                float* __restrict__ h2e, int n){
  int i = blockIdx.x, t = threadIdx.x;
  int beg = rowptr[i], end = rowptr[i+1];
  float adi = ad2[i];
  float m = -1e30f;
  for (int e = beg; e < end; ++e) m = fmaxf(m, lrelu02(as2[csr[e]] + adi));
  float den = 0.f;
  for (int e = beg; e < end; ++e) den += __expf(lrelu02(as2[csr[e]] + adi) - m);
  float rden = 1.f/(den + 1e-16f);
  float a0 = 0.f, a1 = 0.f;
  for (int e = beg; e < end; ++e){
    int s = csr[e];
    float w = __expf(lrelu02(as2[s] + adi) - m) * rden;
    a0 += w * h2[(long long)s*128 + t];
    a1 += w * h2[(long long)s*128 + 64 + t];
  }
  h2e[(long long)i*128 + t]      = elu_fast(a0 + b2[t]);
  h2e[(long long)i*128 + 64 + t] = elu_fast(a1 + b2[64 + t]);
}

// ---------------- global max pool (batch sorted) → split bf16 ----------------
__global__ __launch_bounds__(128)
void pool_split_k(const float* __restrict__ h2e, const int* __restrict__ batch, int n,
                  ushort_t* __restrict__ ph, ushort_t* __restrict__ pl){
  int g = blockIdx.x, t = threadIdx.x;
  int lo = 0, hi = n;
  while (lo < hi){ int mid = (lo + hi) >> 1; if (batch[mid] < g) lo = mid + 1; else hi = mid; }
  int a = lo, b = n;
  while (a < b){ int mid = (a + b) >> 1; if (batch[mid] < g + 1) a = mid + 1; else b = mid; }
  float m = -1e30f;
  for (int i = lo; i < a; ++i) m = fmaxf(m, h2e[(long long)i*128 + t]);
  ushort_t h = f2bf(m);
  ph[g*128 + t] = h; pl[g*128 + t] = f2bf(m - bf2f(h));
}

// ---------------- row-wise L2 normalize → split bf16 (K-padded) ----------------
__global__ __launch_bounds__(256)
void l2norm_split_k(const float* __restrict__ in, int cols, int Kp,
                    ushort_t* __restrict__ oh, ushort_t* __restrict__ ol){
  int r = blockIdx.x, t = threadIdx.x;
  __shared__ float s[256];
  __shared__ float scaleS;
  const float* rp = in + (size_t)r*cols;
  float p = 0.f;
  for (int k = t; k < cols; k += 256){ float v = rp[k]; p += v*v; }
  s[t] = p; __syncthreads();
  for (int o = 128; o > 0; o >>= 1){
    if (t < o) s[t] += s[t+o];
    __syncthreads();
  }
  if (t == 0) scaleS = 1.f / fmaxf(sqrtf(s[0]), 1e-12f);
  __syncthreads();
  float sc = scaleS;
  for (int k = t; k < Kp; k += 256){
    float v = (k < cols) ? rp[k]*sc : 0.f;
    ushort_t h = f2bf(v);
    size_t o2 = (size_t)r*Kp + k;
    oh[o2] = h; ol[o2] = f2bf(v - bf2f(h));
  }
}

__global__ void concat_k(const float* __restrict__ v1, const float* __restrict__ v2,
                         const float* __restrict__ c3, float* __restrict__ xcat, int B){
  int idx = blockIdx.x*blockDim.x + threadIdx.x;
  if (idx < B*512){
    int r = idx >> 9, c = idx & 511;
    float v;
    if (c < 128) v = v1[r*128 + c];
    else if (c < 256) v = v2[r*128 + (c - 128)];
    else v = c3[r*256 + (c - 256)];
    xcat[idx] = v;
  }
}

// relu + split (post split-K reduction)
__global__ void act_split_k(const float* __restrict__ in, ushort_t* __restrict__ oh,
                            ushort_t* __restrict__ ol, int n){
  int i = blockIdx.x*blockDim.x + threadIdx.x;
  if (i < n){
    float v = fmaxf(in[i], 0.f);
    ushort_t h = f2bf(v);
    oh[i] = h; ol[i] = f2bf(v - bf2f(h));
  }
}

// ---------------- merged weight transpose + split ----------------
__device__ __forceinline__ void split_one(const float* __restrict__ W, int ldw, int colStride,
                                          int N, int K, int Np, int Kp,
                                          ushort_t* __restrict__ dh, ushort_t* __restrict__ dl,
                                          int idx){
  int n  = idx % Np;
  int r  = idx / Np;
  int k4 = r % (Kp >> 2);
  int b  = r / (Kp >> 2);
  size_t o = ((size_t)b*Np + n)*Kp + (size_t)k4*4;
  ushort4v hv, lv;
  #pragma unroll
  for (int kk = 0; kk < 4; ++kk){
    int k = k4*4 + kk;
    float v = (n < N && k < K) ? W[(size_t)k*ldw + (size_t)b*colStride + n] : 0.f;
    ushort_t h = f2bf(v);
    hv[kk] = h; lv[kk] = f2bf(v - bf2f(h));
  }
  *(ushort4v*)&dh[o] = hv;
  *(ushort4v*)&dl[o] = lv;
}

struct SplitTable {
  const float *W1, *W2, *Wg, *Wr1, *Wr2, *Wr3, *Wf1, *Wf2, *Wf3, *Wo;
  ushort_t *W1h,*W1l,*W2h,*W2l,*Wgh,*Wgl,*Wr1h,*Wr1l,*Wr2h,*Wr2l;
  ushort_t *Wr3h,*Wr3l,*Wf1h,*Wf1l,*Wf2h,*Wf2l,*Wf3h,*Wf3l,*Woh,*Wol;
};

__global__ void split_all_k(SplitTable T){
  int idx = blockIdx.x*blockDim.x + threadIdx.x;
  if      (idx <   30720) split_one(T.W1, 1280, 128, 128,   78,  128,   96, T.W1h, T.W1l, idx);
  else if (idx <   71680) split_one(T.W2,  128,   0, 128, 1280,  128, 1280, T.W2h, T.W2l, idx -   30720);
  else if (idx <   75776) split_one(T.Wg,  128,   0, 128,  128,  128,  128, T.Wgh, T.Wgl, idx -   71680);
  else if (idx <  567296) split_one(T.Wr1,2048,   0,2048,  954, 2048,  960, T.Wr1h,T.Wr1l,idx -   75776);
  else if (idx <  829440) split_one(T.Wr2, 512,   0, 512, 2048,  512, 2048, T.Wr2h,T.Wr2l,idx -  567296);
  else if (idx <  862208) split_one(T.Wr3, 256,   0, 256,  512,  256,  512, T.Wr3h,T.Wr3l,idx -  829440);
  else if (idx <  993280) split_one(T.Wf1,1024,   0,1024,  512, 1024,  512, T.Wf1h,T.Wf1l,idx -  862208);
  else if (idx < 1124352) split_one(T.Wf2, 512,   0, 512, 1024,  512, 1024, T.Wf2h,T.Wf2l,idx -  993280);
  else if (idx < 1140736) split_one(T.Wf3, 128,   0, 128,  512,  128,  512, T.Wf3h,T.Wf3l,idx - 1124352);
  else if (idx < 1142784) split_one(T.Wo,    2,   0,   2,  128,   64,  128, T.Woh, T.Wol, idx - 1140736);
}

// ---------------- split-bf16 MFMA GEMM (MLP path) ----------------
// A: [M x K] bf16 row-major (hi, + optional lo if aSplit); Bt: [N x K] bf16 hi/lo.
// outMode 0: fp32 direct; 1: split bf16 coalesced; 2: fp32 atomicAdd (act deferred)
__global__ __launch_bounds__(256)
void gemm_split(const ushort_t* __restrict__ Ahp, const ushort_t* __restrict__ Alp, int lda, long long sA,
                const ushort_t* __restrict__ Bhp, const ushort_t* __restrict__ Blp, int ldb, long long sB,
                float* __restrict__ C, ushort_t* __restrict__ Ch, ushort_t* __restrict__ Cl,
                int ldc, long long sC,
                const float* __restrict__ bias, int sBias,
                int M, int Nc, int K, int act, int outMode, int kSplit, int aSplit){
  int zb = blockIdx.z;
  int b = zb / kSplit, kc = zb - b*kSplit;
  Ahp += (long long)b*sA;
  Bhp += (long long)b*sB; Blp += (long long)b*sB;
  long long cOff = (long long)b*sC;
  int Kc = K / kSplit;
  int kb = kc*Kc;
  int nIter = Kc / 32;

  __shared__ ushort_t smem[18048];

  int tid = threadIdx.x, lane = tid & 63, wave = tid >> 6;
  int row0 = blockIdx.y*64, col0 = blockIdx.x*64;
  int wm = (wave & 1)*32, wn = (wave >> 1)*32;
  int lr = lane & 15, quad = lane >> 4;
  int qs = (quad ^ ((lr >> 1) & 3)) * 8;

  int srow = wave*16 + (lane >> 2);
  int skc  = (((lane & 3) ^ ((lane >> 3) & 3)) * 8);
  const ushort_t* gAh = Ahp + (long long)(row0 + srow)*lda + skc + kb;
  const ushort_t* gAl = aSplit ? (Alp + (long long)b*sA + (long long)(row0 + srow)*lda + skc + kb) : gAh;
  const ushort_t* gBh = Bhp + (long long)(col0 + srow)*ldb + skc + kb;
  const ushort_t* gBl = Blp + (long long)(col0 + srow)*ldb + skc + kb;

  float4v acc[2][2];
  #pragma unroll
  for (int i = 0; i < 2; ++i)
    #pragma unroll
    for (int j = 0; j < 2; ++j)
      acc[i][j] = (float4v){0.f, 0.f, 0.f, 0.f};

  auto issue = [&](int p, int kt){
    ushort_t* base = &smem[p*8192 + wave*512];
    gll16(gAh + kt, base);
    if (aSplit) gll16(gAl + kt, base + 2048);
    gll16(gBh + kt, base + 4096);
    gll16(gBl + kt, base + 6144);
  };

  issue(0, 0);
  int p = 0;
  for (int it = 0; it < nIter; ++it){
    __syncthreads();
    if (it + 1 < nIter) issue(p ^ 1, (it + 1)*32);
    const ushort_t* sm = &smem[p*8192];
    short8 ah[2], al[2], bh[2], bl[2];
    #pragma unroll
    for (int t2 = 0; t2 < 2; ++t2){
      int ao = (wm + t2*16 + lr)*32 + qs;
      int bo = (wn + t2*16 + lr)*32 + qs;
      ah[t2] = *(const short8*)&sm[ao];
      if (aSplit) al[t2] = *(const short8*)&sm[2048 + ao];
      bh[t2] = *(const short8*)&sm[4096 + bo];
      bl[t2] = *(const short8*)&sm[6144 + bo];
    }
    #pragma unroll
    for (int i = 0; i < 2; ++i)
      #pragma unroll
      for (int j = 0; j < 2; ++j){
        if (aSplit)
          acc[i][j] = __builtin_amdgcn_mfma_f32_16x16x32_bf16(al[i], bh[j], acc[i][j], 0, 0, 0);
        acc[i][j] = __builtin_amdgcn_mfma_f32_16x16x32_bf16(ah[i], bl[j], acc[i][j], 0, 0, 0);
        acc[i][j] = __builtin_amdgcn_mfma_f32_16x16x32_bf16(ah[i], bh[j], acc[i][j], 0, 0, 0);
      }
    p ^= 1;
  }
  __syncthreads();

  if (outMode == 0 || outMode == 2){
    #pragma unroll
    for (int j = 0; j < 2; ++j){
      int col = col0 + wn + j*16 + lr;
      if (col >= Nc) continue;
      float bv = (bias && kc == 0) ? bias[(long long)b*sBias + col] : 0.f;
      #pragma unroll
      for (int i = 0; i < 2; ++i){
        #pragma unroll
        for (int r = 0; r < 4; ++r){
          int row = row0 + wm + i*16 + quad*4 + r;
          if (row >= M) continue;
          float v = acc[i][j][r] + bv;
          if (act == 1) v = fmaxf(v, 0.f);
          else if (act == 2) v = elu_fast(v);
          long long o = cOff + (long long)row*ldc + col;
          if (outMode == 0) C[o] = v;
          else atomicAdd(&C[o], v);
        }
      }
    }
  } else {
    float* ftile = (float*)smem;           // 64 x 68 floats
    #pragma unroll
    for (int i = 0; i < 2; ++i)
      #pragma unroll
      for (int j = 0; j < 2; ++j)
        #pragma unroll
        for (int r = 0; r < 4; ++r)
          ftile[(wm + i*16 + quad*4 + r)*68 + wn + j*16 + lr] = acc[i][j][r];
    __syncthreads();
    int row = tid >> 2, ch = (tid & 3)*16;
    int grow = row0 + row;
    if (grow < M){
      if (col0 + 64 <= Nc){
        long long o = cOff + (long long)grow*ldc + col0 + ch;
        #pragma unroll
        for (int g = 0; g < 2; ++g){
          ushort8v hv, lv;
          #pragma unroll
          for (int c = 0; c < 8; ++c){
            int cc2 = ch + g*8 + c;
            float v = ftile[row*68 + cc2];
            if (bias) v += bias[(long long)b*sBias + col0 + cc2];
            if (act == 1) v = fmaxf(v, 0.f);
            else if (act == 2) v = elu_fast(v);
            hv[c] = f2bf(v);
            lv[c] = f2bf(v - bf2f(hv[c]));
          }
          *(ushort8v*)&Ch[o + g*8] = hv;
          *(ushort8v*)&Cl[o + g*8] = lv;
        }
      } else {
        for (int c = 0; c < 16; ++c){
          int col = col0 + ch + c;
          if (col >= Nc) break;
          float v = ftile[row*68 + ch + c];
          if (bias) v += bias[(long long)b*sBias + col];
          if (act == 1) v = fmaxf(v, 0.f);
          else if (act == 2) v = elu_fast(v);
          long long o = cOff + (long long)grow*ldc + col;
          ushort_t h = f2bf(v);
          Ch[o] = h;
          Cl[o] = f2bf(v - bf2f(h));
        }
      }
    }
  }
}

// ---------------- host launch ----------------
extern "C" void kernel_launch(void* const* d_in, const int* in_sizes, int n_in,
                              void* d_out, int out_size, void* d_ws, size_t ws_size,
                              hipStream_t stream){
  const float* x1     = (const float*)d_in[0];
  const int*   ei1    = (const int*)  d_in[1];
  const int*   batch1 = (const int*)  d_in[2];
  const float* x2     = (const float*)d_in[3];
  const int*   ei2    = (const int*)  d_in[4];
  const int*   batch2 = (const int*)  d_in[5];
  const float* cell   = (const float*)d_in[6];
  const float* W1     = (const float*)d_in[7];
  const float* a_src1 = (const float*)d_in[8];
  const float* a_dst1 = (const float*)d_in[9];
  const float* b1     = (const float*)d_in[10];
  const float* W2     = (const float*)d_in[11];
  const float* a_src2 = (const float*)d_in[12];
  const float* a_dst2 = (const float*)d_in[13];
  const float* b2     = (const float*)d_in[14];
  const float* Wg     = (const float*)d_in[15];
  const float* bg     = (const float*)d_in[16];
  const float* Wr1    = (const float*)d_in[17];
  const float* br1    = (const float*)d_in[18];
  const float* Wr2    = (const float*)d_in[19];
  const float* br2    = (const float*)d_in[20];
  const float* Wr3    = (const float*)d_in[21];
  const float* br3    = (const float*)d_in[22];
  const float* Wf1    = (const float*)d_in[23];
  const float* bf1    = (const float*)d_in[24];
  const float* Wf2    = (const float*)d_in[25];
  const float* bf2    = (const float*)d_in[26];
  const float* Wf3    = (const float*)d_in[27];
  const float* bf3    = (const float*)d_in[28];
  const float* Wo     = (const float*)d_in[29];
  const float* bo     = (const float*)d_in[30];
  float* out = (float*)d_out;
  (void)n_in; (void)out_size; (void)ws_size;

  const int N  = in_sizes[0] / 78;
  const int E  = in_sizes[1] / 2;
  const int Bg = in_sizes[6] / 954;

  char* wsb = (char*)d_ws;
  size_t off = 0;
  auto alloc = [&](size_t bytes)->char*{
    char* p = wsb + off; off += ((bytes + 255)/256)*256; return p;
  };

  // Y region: yh (10 heads bf16) during branches; MLP buffers after
  char* Yb = alloc((size_t)10*MPAD*96*2);
  ushort_t* yh = (ushort_t*)Yb;
  size_t yoff = 0;
  auto yalloc = [&](size_t bytes)->char*{
    char* p = Yb + yoff; yoff += ((bytes + 255)/256)*256; return p;
  };
  ushort_t* cnh  = (ushort_t*)yalloc((size_t)Bg*960*2);
  ushort_t* cnl  = (ushort_t*)yalloc((size_t)Bg*960*2);
  ushort_t* c1h  = (ushort_t*)yalloc((size_t)Bg*2048*2);
  ushort_t* c1l  = (ushort_t*)yalloc((size_t)Bg*2048*2);
  float*    c2f  = (float*)   yalloc((size_t)Bg*512*4);
  ushort_t* c2h  = (ushort_t*)yalloc((size_t)Bg*512*2);
  ushort_t* c2l  = (ushort_t*)yalloc((size_t)Bg*512*2);
  float*    c3   = (float*)   yalloc((size_t)Bg*256*4);
  float*    xcat = (float*)   yalloc((size_t)Bg*512*4);
  ushort_t* xcnh = (ushort_t*)yalloc((size_t)Bg*512*2);
  ushort_t* xcnl = (ushort_t*)yalloc((size_t)Bg*512*2);
  ushort_t* t1h  = (ushort_t*)yalloc((size_t)Bg*1024*2);
  ushort_t* t1l  = (ushort_t*)yalloc((size_t)Bg*1024*2);
  float*    t2f  = (float*)   yalloc((size_t)Bg*512*4);
  ushort_t* t2h  = (ushort_t*)yalloc((size_t)Bg*512*2);
  ushort_t* t2l  = (ushort_t*)yalloc((size_t)Bg*512*2);
  float*    t3f  = (float*)   yalloc((size_t)Bg*128*4);
  ushort_t* t3h  = (ushort_t*)yalloc((size_t)Bg*128*2);
  ushort_t* t3l  = (ushort_t*)yalloc((size_t)Bg*128*2);

  float* h2  = (float*)alloc((size_t)MPAD*128*4);
  float* h2e = (float*)alloc((size_t)MPAD*128*4);

  // transposed+split weights
  ushort_t* W1th = (ushort_t*)alloc((size_t)10*128*96*2);
  ushort_t* W1tl = (ushort_t*)alloc((size_t)10*128*96*2);
  ushort_t* W2th = (ushort_t*)alloc((size_t)128*1280*2);
  ushort_t* W2tl = (ushort_t*)alloc((size_t)128*1280*2);
  ushort_t* Wgth = (ushort_t*)alloc((size_t)128*128*2);
  ushort_t* Wgtl = (ushort_t*)alloc((size_t)128*128*2);
  ushort_t* Wr1th= (ushort_t*)alloc((size_t)2048*960*2);
  ushort_t* Wr1tl= (ushort_t*)alloc((size_t)2048*960*2);
  ushort_t* Wr2th= (ushort_t*)alloc((size_t)512*2048*2);
  ushort_t* Wr2tl= (ushort_t*)alloc((size_t)512*2048*2);
  ushort_t* Wr3th= (ushort_t*)alloc((size_t)256*512*2);
  ushort_t* Wr3tl= (ushort_t*)alloc((size_t)256*512*2);
  ushort_t* Wf1th= (ushort_t*)alloc((size_t)1024*512*2);
  ushort_t* Wf1tl= (ushort_t*)alloc((size_t)1024*512*2);
  ushort_t* Wf2th= (ushort_t*)alloc((size_t)512*1024*2);
  ushort_t* Wf2tl= (ushort_t*)alloc((size_t)512*1024*2);
  ushort_t* Wf3th= (ushort_t*)alloc((size_t)128*512*2);
  ushort_t* Wf3tl= (ushort_t*)alloc((size_t)128*512*2);
  ushort_t* Woth = (ushort_t*)alloc((size_t)64*128*2);
  ushort_t* Wotl = (ushort_t*)alloc((size_t)64*128*2);

  float* as1b = (float*)alloc((size_t)2*N*10*4);
  float* ad1b = (float*)alloc((size_t)2*N*10*4);
  float* as2  = (float*)alloc((size_t)N*4);
  float* ad2  = (float*)alloc((size_t)N*4);
  float* AsB  = (float*)alloc(780*4);
  float* AdB  = (float*)alloc(780*4);
  float* vs   = (float*)alloc(1280*4);
  float* vd   = (float*)alloc(1280*4);
  int* deg2    = (int*)alloc((size_t)2*N*4);
  int* rowptr2 = (int*)alloc((size_t)2*(N+1)*4);
  int* cursor2 = (int*)alloc((size_t)2*N*4);
  int* csr2    = (int*)alloc((size_t)2*(E+N)*4);
  int* bsum    = (int*)alloc((size_t)2*64*4);
  ushort_t* pooledh = (ushort_t*)alloc((size_t)Bg*128*2);
  ushort_t* pooledl = (ushort_t*)alloc((size_t)Bg*128*2);
  float* v1   = (float*)alloc((size_t)Bg*128*4);
  float* v2   = (float*)alloc((size_t)Bg*128*4);

  auto gemm = [&](const ushort_t* Ah_, const ushort_t* Al_, int lda, long long sA_,
                  const ushort_t* Bh_, const ushort_t* Bl_, int ldb, long long sB_,
                  float* C_, ushort_t* Ch_, ushort_t* Cl_, int ldc, long long sC_,
                  const float* bias_, int sBias_, int M_, int N_, int K_, int batch_,
                  int act_, int mode_, int kSplit_, int aSplit_){
    dim3 grid((N_ + 63)/64, (M_ + 63)/64, batch_*kSplit_);
    gemm_split<<<grid, 256, 0, stream>>>(Ah_, Al_, lda, sA_, Bh_, Bl_, ldb, sB_,
                                         C_, Ch_, Cl_, ldc, sC_, bias_, sBias_,
                                         M_, N_, K_, act_, mode_, kSplit_, aSplit_);
  };

  // ---- weight prep ----
  SplitTable T;
  T.W1 = W1; T.W2 = W2; T.Wg = Wg; T.Wr1 = Wr1; T.Wr2 = Wr2; T.Wr3 = Wr3;
  T.Wf1 = Wf1; T.Wf2 = Wf2; T.Wf3 = Wf3; T.Wo = Wo;
  T.W1h = W1th; T.W1l = W1tl; T.W2h = W2th; T.W2l = W2tl; T.Wgh = Wgth; T.Wgl = Wgtl;
  T.Wr1h = Wr1th; T.Wr1l = Wr1tl; T.Wr2h = Wr2th; T.Wr2l = Wr2tl;
  T.Wr3h = Wr3th; T.Wr3l = Wr3tl; T.Wf1h = Wf1th; T.Wf1l = Wf1tl;
  T.Wf2h = Wf2th; T.Wf2l = Wf2tl; T.Wf3h = Wf3th; T.Wf3l = Wf3tl;
  T.Woh = Woth; T.Wol = Wotl;
  split_all_k<<<(1142784 + 255)/256, 256, 0, stream>>>(T);
  mkattn_k<<<(2060 + 255)/256, 256, 0, stream>>>(W1, a_src1, a_dst1, W2, a_src2, a_dst2,
                                                 AsB, AdB, vs, vd);
  alpha1b_k<<<((2*N) + 255)/256, 256, 0, stream>>>(x1, x2, AsB, AdB, as1b, ad1b, N);

  // ---- batched CSR build (both branches) ----
  const int NB = (N + 1023)/1024;
  fill_int_k<<<((2*N) + 255)/256, 256, 0, stream>>>(deg2, 1, 2*N);
  hist2_k<<<((2*E) + 255)/256, 256, 0, stream>>>(ei1, ei2, E, N, deg2);
  scanA_k<<<dim3(NB, 2), 1024, 0, stream>>>(deg2, rowptr2, bsum, N);
  scanB_k<<<1, 64, 0, stream>>>(bsum, NB);
  scanC_k<<<dim3(NB, 2), 1024, 0, stream>>>(bsum, rowptr2, N, NB, E + N);
  init_cursor_k<<<((2*N) + 255)/256, 256, 0, stream>>>(rowptr2, cursor2, N);
  fill_csr2_k<<<((2*E) + 255)/256, 256, 0, stream>>>(ei1, ei2, E, N, cursor2, csr2);
  self_loop2_k<<<((2*N) + 255)/256, 256, 0, stream>>>(cursor2, csr2, E, N);

  for (int br = 0; br < 2; ++br){
    const float* x   = br ? x2 : x1;
    const int* batch = br ? batch2 : batch1;
    float* vout      = br ? v2 : v1;
    const int* rowptr = rowptr2 + (size_t)br*(N+1);
    const int* csr    = csr2 + (size_t)br*(E+N);
    const float* as1  = as1b + (size_t)br*N*10;
    const float* ad1  = ad1b + (size_t)br*N*10;

    gat1_agg_k<<<N, 64, 0, stream>>>(rowptr, csr, x, as1, ad1, yh, N);
    branch_conv_k<<<MPAD/64, 256, 0, stream>>>(yh, W1th, W1tl, W2th, W2tl,
                                               b1, vs, vd, h2, as2, ad2, N);
    gat2_agg_k<<<N, 64, 0, stream>>>(rowptr, csr, h2, as2, ad2, b2, h2e, N);
    pool_split_k<<<Bg, 128, 0, stream>>>(h2e, batch, N, pooledh, pooledl);
    gemm(pooledh, pooledl, 128, 0, Wgth, Wgtl, 128, 0,
         vout, nullptr, nullptr, 128, 0, bg, 0, Bg, 128, 128, 1, 1, 0, 1, 1);
  }

  // cell MLP
  l2norm_split_k<<<Bg, 256, 0, stream>>>(cell, 954, 960, cnh, cnl);
  gemm(cnh, cnl, 960, 0, Wr1th, Wr1tl, 960, 0, nullptr, c1h, c1l, 2048, 0,
       br1, 0, Bg, 2048, 960, 1, 1, 1, 1, 1);
  hipMemsetAsync(c2f, 0, (size_t)Bg*512*4, stream);
  gemm(c1h, c1l, 2048, 0, Wr2th, Wr2tl, 2048, 0, c2f, nullptr, nullptr, 512, 0,
       br2, 0, Bg, 512, 2048, 1, 0, 2, 4, 1);
  act_split_k<<<((Bg*512) + 255)/256, 256, 0, stream>>>(c2f, c2h, c2l, Bg*512);
  gemm(c2h, c2l, 512, 0, Wr3th, Wr3tl, 512, 0, c3, nullptr, nullptr, 256, 0,
       br3, 0, Bg, 256, 512, 1, 1, 0, 1, 1);

  // final MLP
  concat_k<<<((Bg*512) + 255)/256, 256, 0, stream>>>(v1, v2, c3, xcat, Bg);
  l2norm_split_k<<<Bg, 256, 0, stream>>>(xcat, 512, 512, xcnh, xcnl);
  gemm(xcnh, xcnl, 512, 0, Wf1th, Wf1tl, 512, 0, nullptr, t1h, t1l, 1024, 0,
       bf1, 0, Bg, 1024, 512, 1, 1, 1, 1, 1);
  hipMemsetAsync(t2f, 0, (size_t)Bg*512*4, stream);
  gemm(t1h, t1l, 1024, 0, Wf2th, Wf2tl, 1024, 0, t2f, nullptr, nullptr, 512, 0,
       bf2, 0, Bg, 512, 1024, 1, 0, 2, 4, 1);
  act_split_k<<<((Bg*512) + 255)/256, 256, 0, stream>>>(t2f, t2h, t2l, Bg*512);
  hipMemsetAsync(t3f, 0, (size_t)Bg*128*4, stream);
  gemm(t2h, t2l, 512, 0, Wf3th, Wf3tl, 512, 0, t3f, nullptr, nullptr, 128, 0,
       bf3, 0, Bg, 128, 512, 1, 0, 2, 4, 1);
  act_split_k<<<((Bg*128) + 255)/256, 256, 0, stream>>>(t3f, t3h, t3l, Bg*128);
  gemm(t3h, t3l, 128, 0, Woth, Wotl, 128, 0, out, nullptr, nullptr, 2, 0,
       bo, 0, Bg, 2, 128, 1, 0, 0, 1, 1);
}

// Round 9
// 601.007 us; speedup vs baseline: 5.0965x; 1.1427x over previous
//
#include <hip/hip_runtime.h>
#include <math.h>

typedef unsigned short ushort_t;
typedef __attribute__((ext_vector_type(8))) short short8;
typedef __attribute__((ext_vector_type(8))) unsigned short ushort8v;
typedef __attribute__((ext_vector_type(4))) float float4v;
typedef __attribute__((ext_vector_type(4))) unsigned short ushort4v;

#define MPAD 30016
#define H1STR 136

// ---------------- utility ----------------
__device__ __forceinline__ float lrelu02(float v){ return v > 0.f ? v : 0.2f*v; }
__device__ __forceinline__ float elu_fast(float v){ return v > 0.f ? v : (__expf(v) - 1.f); }

__device__ __forceinline__ ushort_t f2bf(float x){
  unsigned u = __float_as_uint(x);
  return (ushort_t)((u + 0x7fffu + ((u >> 16) & 1u)) >> 16);
}
__device__ __forceinline__ float bf2f(ushort_t h){ return __uint_as_float(((unsigned)h) << 16); }

// monotone float<->unsigned for atomicMax pooling
__device__ __forceinline__ unsigned encf(float f){
  unsigned u = __float_as_uint(f);
  return (u & 0x80000000u) ? ~u : (u | 0x80000000u);
}
__device__ __forceinline__ float decf(unsigned u){
  return __uint_as_float((u >> 31) ? (u & 0x7FFFFFFFu) : ~u);
}

__device__ __forceinline__ void gll16(const void* g, void* l){
  __builtin_amdgcn_global_load_lds((const __attribute__((address_space(1))) void*)g,
                                   (__attribute__((address_space(3))) void*)l, 16, 0, 0);
}

__global__ void fill_int_k(int* p, int v, int n){
  int i = blockIdx.x*blockDim.x + threadIdx.x;
  if (i < n) p[i] = v;
}

// ---------------- batched CSR build (both branches) ----------------
__global__ void hist2_k(const int* __restrict__ ei1, const int* __restrict__ ei2,
                        int E, int N, int* deg){
  int idx = blockIdx.x*blockDim.x + threadIdx.x;
  if (idx < 2*E){
    int br = idx / E, e = idx - br*E;
    const int* ei = br ? ei2 : ei1;
    atomicAdd(&deg[br*N + ei[E + e]], 1);
  }
}

__global__ __launch_bounds__(1024)
void scanA_k(const int* __restrict__ deg, int* __restrict__ rowptr, int* __restrict__ bsum, int n){
  int br = blockIdx.y;
  int t = threadIdx.x;
  int i = blockIdx.x*1024 + t;
  __shared__ int s[1024];
  int v = (i < n) ? deg[br*n + i] : 0;
  s[t] = v; __syncthreads();
  for (int off = 1; off < 1024; off <<= 1){
    int x = (t >= off) ? s[t - off] : 0;
    __syncthreads();
    s[t] += x;
    __syncthreads();
  }
  if (i < n) rowptr[br*(n+1) + i] = s[t] - v;
  if (t == 1023) bsum[br*gridDim.x + blockIdx.x] = s[1023];
}

__global__ void scanB_k(int* bsum, int nb){
  int br = threadIdx.x;
  if (br < 2){
    int run = 0;
    for (int i = 0; i < nb; ++i){ int v = bsum[br*nb + i]; bsum[br*nb + i] = run; run += v; }
  }
}

__global__ __launch_bounds__(1024)
void scanC_k(const int* __restrict__ bsum, int* __restrict__ rowptr, int* __restrict__ cursor,
             int n, int nb, int total){
  int br = blockIdx.y;
  int i = blockIdx.x*1024 + threadIdx.x;
  int add = bsum[br*nb + blockIdx.x];
  if (i < n){
    int nv = rowptr[br*(n+1) + i] + add;
    rowptr[br*(n+1) + i] = nv;
    cursor[br*n + i] = nv;
  }
  if (i == 0) rowptr[br*(n+1) + n] = total;
}

__global__ void fill_csr2_k(const int* __restrict__ ei1, const int* __restrict__ ei2,
                            int E, int N, int* cursor, int* csr){
  int idx = blockIdx.x*blockDim.x + threadIdx.x;
  if (idx < 2*E){
    int br = idx / E, e = idx - br*E;
    const int* ei = br ? ei2 : ei1;
    int dst = ei[E + e];
    int pos = atomicAdd(&cursor[br*N + dst], 1);
    csr[br*(E+N) + pos] = ei[e];
  }
}

__global__ void self_loop2_k(int* cursor, int* csr, int E, int N){
  int idx = blockIdx.x*blockDim.x + threadIdx.x;
  if (idx < 2*N){
    int br = idx / N, i = idx - br*N;
    int pos = atomicAdd(&cursor[br*N + i], 1);
    csr[br*(E+N) + pos] = i;
  }
}

// ---------------- attention score precompute (merged) ----------------
__global__ void mkattn_k(const float* __restrict__ W1, const float* __restrict__ a_src1,
                         const float* __restrict__ a_dst1,
                         const float* __restrict__ W2, const float* __restrict__ a_src2,
                         const float* __restrict__ a_dst2,
                         float* As, float* Ad, float* vs, float* vd){
  int idx = blockIdx.x*blockDim.x + threadIdx.x;
  if (idx < 780){
    int f = idx / 10, h = idx % 10;
    float ss = 0.f, sd = 0.f;
    for (int c = 0; c < 128; ++c){
      float w = W1[f*1280 + h*128 + c];
      ss += w * a_src1[h*128 + c];
      sd += w * a_dst1[h*128 + c];
    }
    As[idx] = ss; Ad[idx] = sd;
  } else if (idx < 2060){
    int k = idx - 780;
    float ss = 0.f, sd = 0.f;
    for (int c = 0; c < 128; ++c){
      float w = W2[k*128 + c];
      ss += w * a_src2[c]; sd += w * a_dst2[c];
    }
    vs[k] = ss; vd[k] = sd;
  }
}

// node-per-thread alpha1 (both branches); As/Ad staged in LDS
__global__ __launch_bounds__(256)
void alpha1b_k(const float* __restrict__ x1, const float* __restrict__ x2,
               const float* __restrict__ As, const float* __restrict__ Ad,
               float* as1, float* ad1, int n){
  __shared__ float sAs[780], sAd[780];
  int t = threadIdx.x;
  for (int k = t; k < 780; k += 256){ sAs[k] = As[k]; sAd[k] = Ad[k]; }
  __syncthreads();
  int idx = blockIdx.x*256 + t;
  if (idx >= 2*n) return;
  int br = idx / n, i = idx - br*n;
  const float* xr = (br ? x2 : x1) + (size_t)i*78;
  float ss[10], sd[10];
  #pragma unroll
  for (int h = 0; h < 10; ++h){ ss[h] = 0.f; sd[h] = 0.f; }
  for (int f = 0; f < 78; ++f){
    float xv = xr[f];
    #pragma unroll
    for (int h = 0; h < 10; ++h){
      ss[h] += xv * sAs[f*10 + h];
      sd[h] += xv * sAd[f*10 + h];
    }
  }
  #pragma unroll
  for (int h = 0; h < 10; ++h){
    as1[(size_t)idx*10 + h] = ss[h];
    ad1[(size_t)idx*10 + h] = sd[h];
  }
}

// ---------------- GATConv1 one-pass softmax + aggregate (both branches) ----------------
// blockIdx.x in [0,2N): br = idx>=N. writes bf16 y[br][h][i][96] (f>=78 zero-padded)
__global__ __launch_bounds__(64)
void gat1_agg_k(const int* __restrict__ rowptr2, const int* __restrict__ csr2,
                const float* __restrict__ x1, const float* __restrict__ x2,
                const float* __restrict__ as1b, const float* __restrict__ ad1b,
                ushort_t* __restrict__ yh, int n, int E){
  int gi = blockIdx.x;
  int br = (gi >= n) ? 1 : 0;
  int i = gi - br*n;
  int t = threadIdx.x;
  const int* rowptr = rowptr2 + (size_t)br*(n+1);
  const int* csr    = csr2 + (size_t)br*(E+n);
  const float* x    = br ? x2 : x1;
  const float* as1  = as1b + (size_t)br*n*10;
  ushort_t* yb      = yh + (size_t)br*10*MPAD*96;

  __shared__ float adi[10], rden[10], wE[10], xs[78];
  int beg = rowptr[i], end = rowptr[i+1];
  if (t < 10) adi[t] = ad1b[(size_t)gi*10 + t];
  __syncthreads();
  float den = 0.f;
  float acc[13];
  int hh[13], cc[13];
  #pragma unroll
  for (int k = 0; k < 13; ++k){
    acc[k] = 0.f;
    int j = t + 64*k;
    hh[k] = (j < 780) ? (j/78) : 0;
    cc[k] = (j < 780) ? (j%78) : 0;
  }
  for (int e = beg; e < end; ++e){
    int s = csr[e];
    if (t < 10){
      float w = __expf(lrelu02(as1[(size_t)s*10 + t] + adi[t]));
      wE[t] = w; den += w;
    }
    for (int c = t; c < 78; c += 64) xs[c] = x[(size_t)s*78 + c];
    __syncthreads();
    #pragma unroll
    for (int k = 0; k < 13; ++k){
      int j = t + 64*k;
      if (j < 780) acc[k] += wE[hh[k]] * xs[cc[k]];
    }
    __syncthreads();
  }
  if (t < 10) rden[t] = 1.f/(den + 1e-16f);
  __syncthreads();
  #pragma unroll
  for (int k = 0; k < 13; ++k){
    int j = t + 64*k;
    if (j < 780) yb[((size_t)hh[k]*MPAD + i)*96 + cc[k]] = f2bf(acc[k]*rden[hh[k]]);
  }
  for (int p = t; p < 180; p += 64){
    int h = p/18, c = 78 + p%18;
    yb[((size_t)h*MPAD + i)*96 + c] = 0;
  }
}

// ---------------- fused branch conv (both branches batched) ----------------
__global__ __launch_bounds__(256)
void branch_conv_k(const ushort_t* __restrict__ yall,
                   const ushort_t* __restrict__ W1h, const ushort_t* __restrict__ W1l,
                   const ushort_t* __restrict__ W2h, const ushort_t* __restrict__ W2l,
                   const float* __restrict__ b1, const float* __restrict__ vs,
                   const float* __restrict__ vd,
                   float* __restrict__ h2all, float* __restrict__ as2all,
                   float* __restrict__ ad2all, int M){
  const int NBLK = MPAD/64;
  int br = blockIdx.x / NBLK;
  int bi = blockIdx.x - br*NBLK;
  const ushort_t* y = yall + (size_t)br*10*MPAD*96;
  float* h2  = h2all + (size_t)br*MPAD*128;
  float* as2 = as2all + (size_t)br*MPAD;
  float* ad2 = ad2all + (size_t)br*MPAD;

  __shared__ ushort_t stage[2][10240];
  __shared__ ushort_t h1t[64*H1STR];
  __shared__ float red[256];

  int tid = threadIdx.x, lane = tid & 63, wave = tid >> 6;
  int row0 = bi*64;
  int wm = (wave & 1)*32, wn = (wave >> 1)*64;
  int lr = lane & 15, quad = lane >> 4;
  int sr = lane >> 2;
  int skc = (((lane & 3) ^ ((lane >> 3) & 3)) * 8);
  int qs  = (quad ^ ((lr >> 1) & 3)) * 8;

  float4v acc2[2][4];
  #pragma unroll
  for (int i = 0; i < 2; ++i)
    #pragma unroll
    for (int j = 0; j < 4; ++j)
      acc2[i][j] = (float4v){0.f, 0.f, 0.f, 0.f};
  float rps[8], rpd[8];
  #pragma unroll
  for (int z = 0; z < 8; ++z){ rps[z] = 0.f; rpd[z] = 0.f; }

  for (int h = 0; h < 10; ++h){
    const ushort_t* gA   = y   + ((size_t)h*MPAD + row0 + wave*16 + sr)*96 + skc;
    const ushort_t* gB0h = W1h + ((size_t)(h*128 + wave*32      + sr))*96 + skc;
    const ushort_t* gB1h = W1h + ((size_t)(h*128 + wave*32 + 16 + sr))*96 + skc;
    const ushort_t* gB0l = W1l + ((size_t)(h*128 + wave*32      + sr))*96 + skc;
    const ushort_t* gB1l = W1l + ((size_t)(h*128 + wave*32 + 16 + sr))*96 + skc;
    const ushort_t* gC0h = W2h + ((size_t)(wave*32      + sr))*1280 + h*128 + skc;
    const ushort_t* gC1h = W2h + ((size_t)(wave*32 + 16 + sr))*1280 + h*128 + skc;
    const ushort_t* gC0l = W2l + ((size_t)(wave*32      + sr))*1280 + h*128 + skc;
    const ushort_t* gC1l = W2l + ((size_t)(wave*32 + 16 + sr))*1280 + h*128 + skc;

    auto issue1 = [&](int p, int kt){
      ushort_t* st = &stage[p][0];
      gll16(gA   + kt, st + wave*512);
      gll16(gB0h + kt, st + 2048 + wave*1024);
      gll16(gB1h + kt, st + 2048 + wave*1024 + 512);
      gll16(gB0l + kt, st + 6144 + wave*1024);
      gll16(gB1l + kt, st + 6144 + wave*1024 + 512);
    };
    auto issue2 = [&](int p, int kt){
      ushort_t* st = &stage[p][0];
      gll16(gC0h + kt, st + 2048 + wave*1024);
      gll16(gC1h + kt, st + 2048 + wave*1024 + 512);
      gll16(gC0l + kt, st + 6144 + wave*1024);
      gll16(gC1l + kt, st + 6144 + wave*1024 + 512);
    };

    // ---- P1: h1e_h = y_h @ W1_h (K=96) ----
    __syncthreads();
    issue1(0, 0);
    float4v acc1[2][4];
    #pragma unroll
    for (int i = 0; i < 2; ++i)
      #pragma unroll
      for (int j = 0; j < 4; ++j)
        acc1[i][j] = (float4v){0.f, 0.f, 0.f, 0.f};
    int p = 0;
    #pragma unroll
    for (int it = 0; it < 3; ++it){
      __syncthreads();
      if (it < 2) issue1(p ^ 1, (it + 1)*32);
      const ushort_t* sm = &stage[p][0];
      short8 af[2], bhf[4], blf[4];
      #pragma unroll
      for (int t2 = 0; t2 < 2; ++t2)
        af[t2] = *(const short8*)&sm[(wm + t2*16 + lr)*32 + qs];
      #pragma unroll
      for (int j = 0; j < 4; ++j){
        int nb = (wn + j*16 + lr)*32 + qs;
        bhf[j] = *(const short8*)&sm[2048 + nb];
        blf[j] = *(const short8*)&sm[6144 + nb];
      }
      #pragma unroll
      for (int i = 0; i < 2; ++i)
        #pragma unroll
        for (int j = 0; j < 4; ++j){
          acc1[i][j] = __builtin_amdgcn_mfma_f32_16x16x32_bf16(af[i], blf[j], acc1[i][j], 0, 0, 0);
          acc1[i][j] = __builtin_amdgcn_mfma_f32_16x16x32_bf16(af[i], bhf[j], acc1[i][j], 0, 0, 0);
        }
      p ^= 1;
    }

    // ---- ELU + bias; write h1t; accumulate alpha2 from fp32 values ----
    #pragma unroll
    for (int j = 0; j < 4; ++j){
      int col = wn + j*16 + lr;
      float bv  = b1[h*128 + col];
      float vsv = vs[h*128 + col];
      float vdv = vd[h*128 + col];
      #pragma unroll
      for (int i = 0; i < 2; ++i){
        #pragma unroll
        for (int r = 0; r < 4; ++r){
          float v = elu_fast(acc1[i][j][r] + bv);
          h1t[(wm + i*16 + quad*4 + r)*H1STR + col] = f2bf(v);
          rps[i*4 + r] += v * vsv;
          rpd[i*4 + r] += v * vdv;
        }
      }
    }
    __syncthreads();

    // ---- P2: h2 += h1e_tile @ W2[h*128:(h+1)*128, :] (K=128) ----
    issue2(0, 0);
    p = 0;
    #pragma unroll
    for (int it = 0; it < 4; ++it){
      __syncthreads();
      if (it < 3) issue2(p ^ 1, (it + 1)*32);
      const ushort_t* sm = &stage[p][0];
      int kt = it*32;
      short8 af[2], bhf[4], blf[4];
      #pragma unroll
      for (int t2 = 0; t2 < 2; ++t2)
        af[t2] = *(const short8*)&h1t[(wm + t2*16 + lr)*H1STR + kt + quad*8];
      #pragma unroll
      for (int j = 0; j < 4; ++j){
        int nb = (wn + j*16 + lr)*32 + qs;
        bhf[j] = *(const short8*)&sm[2048 + nb];
        blf[j] = *(const short8*)&sm[6144 + nb];
      }
      #pragma unroll
      for (int i = 0; i < 2; ++i)
        #pragma unroll
        for (int j = 0; j < 4; ++j){
          acc2[i][j] = __builtin_amdgcn_mfma_f32_16x16x32_bf16(af[i], blf[j], acc2[i][j], 0, 0, 0);
          acc2[i][j] = __builtin_amdgcn_mfma_f32_16x16x32_bf16(af[i], bhf[j], acc2[i][j], 0, 0, 0);
        }
      p ^= 1;
    }
  }

  // ---- h2 store ----
  #pragma unroll
  for (int j = 0; j < 4; ++j){
    int col = wn + j*16 + lr;
    #pragma unroll
    for (int i = 0; i < 2; ++i){
      #pragma unroll
      for (int r = 0; r < 4; ++r){
        int row = row0 + wm + i*16 + quad*4 + r;
        if (row < M) h2[(size_t)row*128 + col] = acc2[i][j][r];
      }
    }
  }
  // ---- alpha2 reduce ----
  __syncthreads();
  #pragma unroll
  for (int z = 0; z < 8; ++z){
    float a = rps[z], d = rpd[z];
    #pragma unroll
    for (int mk = 1; mk <= 8; mk <<= 1){
      a += __shfl_xor(a, mk);
      d += __shfl_xor(d, mk);
    }
    if (lr == 0){
      int i = z >> 2, r = z & 3;
      int row = wm + i*16 + quad*4 + r;
      red[row*2 + (wave >> 1)] = a;
      red[128 + row*2 + (wave >> 1)] = d;
    }
  }
  __syncthreads();
  if (tid < 64){
    int grow = row0 + tid;
    if (grow < M){
      as2[grow] = red[tid*2] + red[tid*2 + 1];
      ad2[grow] = red[128 + tid*2] + red[128 + tid*2 + 1];
    }
  }
}

// ---------------- GATConv2 one-pass softmax + aggregate + atomic pool ----------------
__global__ __launch_bounds__(64)
void gat2_agg_k(const int* __restrict__ rowptr2, const int* __restrict__ csr2,
                const float* __restrict__ h2all, const float* __restrict__ as2all,
                const float* __restrict__ ad2all, const float* __restrict__ b2,
                const int* __restrict__ batch1, const int* __restrict__ batch2,
                unsigned* __restrict__ poolKey, int n, int E, int Bg){
  int gi = blockIdx.x;
  int br = (gi >= n) ? 1 : 0;
  int i = gi - br*n;
  int t = threadIdx.x;
  const int* rowptr = rowptr2 + (size_t)br*(n+1);
  const int* csr    = csr2 + (size_t)br*(E+n);
  const float* h2   = h2all + (size_t)br*MPAD*128;
  const float* as2  = as2all + (size_t)br*MPAD;
  float adi = ad2all[(size_t)br*MPAD + i];
  int beg = rowptr[i], end = rowptr[i+1];
  float den = 0.f, a0 = 0.f, a1 = 0.f;
  for (int e = beg; e < end; ++e){
    int s = csr[e];
    float w = __expf(lrelu02(as2[s] + adi));
    den += w;
    a0 += w * h2[(size_t)s*128 + t];
    a1 += w * h2[(size_t)s*128 + 64 + t];
  }
  float r = 1.f/(den + 1e-16f);
  float o0 = elu_fast(a0*r + b2[t]);
  float o1 = elu_fast(a1*r + b2[64 + t]);
  int g = (br ? batch2 : batch1)[i];
  unsigned* pk = poolKey + ((size_t)br*Bg + g)*128;
  atomicMax(&pk[t], encf(o0));
  atomicMax(&pk[64 + t], encf(o1));
}

// ---------------- pool decode → split bf16 ----------------
__global__ void pool_decode_k(const unsigned* __restrict__ key,
                              ushort_t* __restrict__ ph, ushort_t* __restrict__ pl, int n){
  int i = blockIdx.x*blockDim.x + threadIdx.x;
  if (i < n){
    float v = decf(key[i]);
    ushort_t h = f2bf(v);
    ph[i] = h; pl[i] = f2bf(v - bf2f(h));
  }
}

// ---------------- row-wise L2 normalize → split bf16 (K-padded) ----------------
__global__ __launch_bounds__(256)
void l2norm_split_k(const float* __restrict__ in, int cols, int Kp,
                    ushort_t* __restrict__ oh, ushort_t* __restrict__ ol){
  int r = blockIdx.x, t = threadIdx.x;
  __shared__ float s[256];
  __shared__ float scaleS;
  const float* rp = in + (size_t)r*cols;
  float p = 0.f;
  for (int k = t; k < cols; k += 256){ float v = rp[k]; p += v*v; }
  s[t] = p; __syncthreads();
  for (int o = 128; o > 0; o >>= 1){
    if (t < o) s[t] += s[t+o];
    __syncthreads();
  }
  if (t == 0) scaleS = 1.f / fmaxf(sqrtf(s[0]), 1e-12f);
  __syncthreads();
  float sc = scaleS;
  for (int k = t; k < Kp; k += 256){
    float v = (k < cols) ? rp[k]*sc : 0.f;
    ushort_t h = f2bf(v);
    size_t o2 = (size_t)r*Kp + k;
    oh[o2] = h; ol[o2] = f2bf(v - bf2f(h));
  }
}

// ---------------- fused concat + l2norm + split ----------------
__global__ __launch_bounds__(256)
void catnorm_k(const float* __restrict__ vall, const float* __restrict__ c3,
               ushort_t* __restrict__ oh, ushort_t* __restrict__ ol, int Bg){
  int r = blockIdx.x, t = threadIdx.x;
  __shared__ float s[256];
  __shared__ float scaleS;
  auto val = [&](int c)->float{
    if (c < 128) return vall[(size_t)r*128 + c];
    if (c < 256) return vall[((size_t)Bg + r)*128 + (c - 128)];
    return c3[(size_t)r*256 + (c - 256)];
  };
  float v0 = val(t), v1 = val(t + 256);
  s[t] = v0*v0 + v1*v1; __syncthreads();
  for (int o = 128; o > 0; o >>= 1){
    if (t < o) s[t] += s[t+o];
    __syncthreads();
  }
  if (t == 0) scaleS = 1.f / fmaxf(sqrtf(s[0]), 1e-12f);
  __syncthreads();
  float sc = scaleS;
  float a = v0*sc, b = v1*sc;
  ushort_t ha = f2bf(a), hb = f2bf(b);
  size_t o2 = (size_t)r*512;
  oh[o2 + t] = ha;       ol[o2 + t] = f2bf(a - bf2f(ha));
  oh[o2 + 256 + t] = hb; ol[o2 + 256 + t] = f2bf(b - bf2f(hb));
}

// relu + split (post split-K reduction)
__global__ void act_split_k(const float* __restrict__ in, ushort_t* __restrict__ oh,
                            ushort_t* __restrict__ ol, int n){
  int i = blockIdx.x*blockDim.x + threadIdx.x;
  if (i < n){
    float v = fmaxf(in[i], 0.f);
    ushort_t h = f2bf(v);
    oh[i] = h; ol[i] = f2bf(v - bf2f(h));
  }
}

// ---------------- merged weight transpose + split ----------------
__device__ __forceinline__ void split_one(const float* __restrict__ W, int ldw, int colStride,
                                          int N, int K, int Np, int Kp,
                                          ushort_t* __restrict__ dh, ushort_t* __restrict__ dl,
                                          int idx){
  int n  = idx % Np;
  int r  = idx / Np;
  int k4 = r % (Kp >> 2);
  int b  = r / (Kp >> 2);
  size_t o = ((size_t)b*Np + n)*Kp + (size_t)k4*4;
  ushort4v hv, lv;
  #pragma unroll
  for (int kk = 0; kk < 4; ++kk){
    int k = k4*4 + kk;
    float v = (n < N && k < K) ? W[(size_t)k*ldw + (size_t)b*colStride + n] : 0.f;
    ushort_t h = f2bf(v);
    hv[kk] = h; lv[kk] = f2bf(v - bf2f(h));
  }
  *(ushort4v*)&dh[o] = hv;
  *(ushort4v*)&dl[o] = lv;
}

struct SplitTable {
  const float *W1, *W2, *Wg, *Wr1, *Wr2, *Wr3, *Wf1, *Wf2, *Wf3, *Wo;
  ushort_t *W1h,*W1l,*W2h,*W2l,*Wgh,*Wgl,*Wr1h,*Wr1l,*Wr2h,*Wr2l;
  ushort_t *Wr3h,*Wr3l,*Wf1h,*Wf1l,*Wf2h,*Wf2l,*Wf3h,*Wf3l,*Woh,*Wol;
};

__global__ void split_all_k(SplitTable T){
  int idx = blockIdx.x*blockDim.x + threadIdx.x;
  if      (idx <   30720) split_one(T.W1, 1280, 128, 128,   78,  128,   96, T.W1h, T.W1l, idx);
  else if (idx <   71680) split_one(T.W2,  128,   0, 128, 1280,  128, 1280, T.W2h, T.W2l, idx -   30720);
  else if (idx <   75776) split_one(T.Wg,  128,   0, 128,  128,  128,  128, T.Wgh, T.Wgl, idx -   71680);
  else if (idx <  567296) split_one(T.Wr1,2048,   0,2048,  954, 2048,  960, T.Wr1h,T.Wr1l,idx -   75776);
  else if (idx <  829440) split_one(T.Wr2, 512,   0, 512, 2048,  512, 2048, T.Wr2h,T.Wr2l,idx -  567296);
  else if (idx <  862208) split_one(T.Wr3, 256,   0, 256,  512,  256,  512, T.Wr3h,T.Wr3l,idx -  829440);
  else if (idx <  993280) split_one(T.Wf1,1024,   0,1024,  512, 1024,  512, T.Wf1h,T.Wf1l,idx -  862208);
  else if (idx < 1124352) split_one(T.Wf2, 512,   0, 512, 1024,  512, 1024, T.Wf2h,T.Wf2l,idx -  993280);
  else if (idx < 1140736) split_one(T.Wf3, 128,   0, 128,  512,  128,  512, T.Wf3h,T.Wf3l,idx - 1124352);
  else if (idx < 1142784) split_one(T.Wo,    2,   0,   2,  128,   64,  128, T.Woh, T.Wol, idx - 1140736);
}

// ---------------- split-bf16 MFMA GEMM (MLP path) ----------------
__global__ __launch_bounds__(256)
void gemm_split(const ushort_t* __restrict__ Ahp, const ushort_t* __restrict__ Alp, int lda, long long sA,
                const ushort_t* __restrict__ Bhp, const ushort_t* __restrict__ Blp, int ldb, long long sB,
                float* __restrict__ C, ushort_t* __restrict__ Ch, ushort_t* __restrict__ Cl,
                int ldc, long long sC,
                const float* __restrict__ bias, int sBias,
                int M, int Nc, int K, int act, int outMode, int kSplit, int aSplit){
  int zb = blockIdx.z;
  int b = zb / kSplit, kc = zb - b*kSplit;
  Ahp += (long long)b*sA;
  Bhp += (long long)b*sB; Blp += (long long)b*sB;
  long long cOff = (long long)b*sC;
  int Kc = K / kSplit;
  int kb = kc*Kc;
  int nIter = Kc / 32;

  __shared__ ushort_t smem[18048];

  int tid = threadIdx.x, lane = tid & 63, wave = tid >> 6;
  int row0 = blockIdx.y*64, col0 = blockIdx.x*64;
  int wm = (wave & 1)*32, wn = (wave >> 1)*32;
  int lr = lane & 15, quad = lane >> 4;
  int qs = (quad ^ ((lr >> 1) & 3)) * 8;

  int srow = wave*16 + (lane >> 2);
  int skc  = (((lane & 3) ^ ((lane >> 3) & 3)) * 8);
  const ushort_t* gAh = Ahp + (long long)(row0 + srow)*lda + skc + kb;
  const ushort_t* gAl = aSplit ? (Alp + (long long)b*sA + (long long)(row0 + srow)*lda + skc + kb) : gAh;
  const ushort_t* gBh = Bhp + (long long)(col0 + srow)*ldb + skc + kb;
  const ushort_t* gBl = Blp + (long long)(col0 + srow)*ldb + skc + kb;

  float4v acc[2][2];
  #pragma unroll
  for (int i = 0; i < 2; ++i)
    #pragma unroll
    for (int j = 0; j < 2; ++j)
      acc[i][j] = (float4v){0.f, 0.f, 0.f, 0.f};

  auto issue = [&](int p, int kt){
    ushort_t* base = &smem[p*8192 + wave*512];
    gll16(gAh + kt, base);
    if (aSplit) gll16(gAl + kt, base + 2048);
    gll16(gBh + kt, base + 4096);
    gll16(gBl + kt, base + 6144);
  };

  issue(0, 0);
  int p = 0;
  for (int it = 0; it < nIter; ++it){
    __syncthreads();
    if (it + 1 < nIter) issue(p ^ 1, (it + 1)*32);
    const ushort_t* sm = &smem[p*8192];
    short8 ah[2], al[2], bh[2], bl[2];
    #pragma unroll
    for (int t2 = 0; t2 < 2; ++t2){
      int ao = (wm + t2*16 + lr)*32 + qs;
      int bo = (wn + t2*16 + lr)*32 + qs;
      ah[t2] = *(const short8*)&sm[ao];
      if (aSplit) al[t2] = *(const short8*)&sm[2048 + ao];
      bh[t2] = *(const short8*)&sm[4096 + bo];
      bl[t2] = *(const short8*)&sm[6144 + bo];
    }
    #pragma unroll
    for (int i = 0; i < 2; ++i)
      #pragma unroll
      for (int j = 0; j < 2; ++j){
        if (aSplit)
          acc[i][j] = __builtin_amdgcn_mfma_f32_16x16x32_bf16(al[i], bh[j], acc[i][j], 0, 0, 0);
        acc[i][j] = __builtin_amdgcn_mfma_f32_16x16x32_bf16(ah[i], bl[j], acc[i][j], 0, 0, 0);
        acc[i][j] = __builtin_amdgcn_mfma_f32_16x16x32_bf16(ah[i], bh[j], acc[i][j], 0, 0, 0);
      }
    p ^= 1;
  }
  __syncthreads();

  if (outMode == 0 || outMode == 2){
    #pragma unroll
    for (int j = 0; j < 2; ++j){
      int col = col0 + wn + j*16 + lr;
      if (col >= Nc) continue;
      float bv = (bias && kc == 0) ? bias[(long long)b*sBias + col] : 0.f;
      #pragma unroll
      for (int i = 0; i < 2; ++i){
        #pragma unroll
        for (int r = 0; r < 4; ++r){
          int row = row0 + wm + i*16 + quad*4 + r;
          if (row >= M) continue;
          float v = acc[i][j][r] + bv;
          if (act == 1) v = fmaxf(v, 0.f);
          else if (act == 2) v = elu_fast(v);
          long long o = cOff + (long long)row*ldc + col;
          if (outMode == 0) C[o] = v;
          else atomicAdd(&C[o], v);
        }
      }
    }
  } else {
    float* ftile = (float*)smem;
    #pragma unroll
    for (int i = 0; i < 2; ++i)
      #pragma unroll
      for (int j = 0; j < 2; ++j)
        #pragma unroll
        for (int r = 0; r < 4; ++r)
          ftile[(wm + i*16 + quad*4 + r)*68 + wn + j*16 + lr] = acc[i][j][r];
    __syncthreads();
    int row = tid >> 2, ch = (tid & 3)*16;
    int grow = row0 + row;
    if (grow < M){
      if (col0 + 64 <= Nc){
        long long o = cOff + (long long)grow*ldc + col0 + ch;
        #pragma unroll
        for (int g = 0; g < 2; ++g){
          ushort8v hv, lv;
          #pragma unroll
          for (int c = 0; c < 8; ++c){
            int cc2 = ch + g*8 + c;
            float v = ftile[row*68 + cc2];
            if (bias) v += bias[(long long)b*sBias + col0 + cc2];
            if (act == 1) v = fmaxf(v, 0.f);
            else if (act == 2) v = elu_fast(v);
            hv[c] = f2bf(v);
            lv[c] = f2bf(v - bf2f(hv[c]));
          }
          *(ushort8v*)&Ch[o + g*8] = hv;
          *(ushort8v*)&Cl[o + g*8] = lv;
        }
      } else {
        for (int c = 0; c < 16; ++c){
          int col = col0 + ch + c;
          if (col >= Nc) break;
          float v = ftile[row*68 + ch + c];
          if (bias) v += bias[(long long)b*sBias + col];
          if (act == 1) v = fmaxf(v, 0.f);
          else if (act == 2) v = elu_fast(v);
          long long o = cOff + (long long)grow*ldc + col;
          ushort_t h = f2bf(v);
          Ch[o] = h;
          Cl[o] = f2bf(v - bf2f(h));
        }
      }
    }
  }
}

// ---------------- host launch ----------------
extern "C" void kernel_launch(void* const* d_in, const int* in_sizes, int n_in,
                              void* d_out, int out_size, void* d_ws, size_t ws_size,
                              hipStream_t stream){
  const float* x1     = (const float*)d_in[0];
  const int*   ei1    = (const int*)  d_in[1];
  const int*   batch1 = (const int*)  d_in[2];
  const float* x2     = (const float*)d_in[3];
  const int*   ei2    = (const int*)  d_in[4];
  const int*   batch2 = (const int*)  d_in[5];
  const float* cell   = (const float*)d_in[6];
  const float* W1     = (const float*)d_in[7];
  const float* a_src1 = (const float*)d_in[8];
  const float* a_dst1 = (const float*)d_in[9];
  const float* b1     = (const float*)d_in[10];
  const float* W2     = (const float*)d_in[11];
  const float* a_src2 = (const float*)d_in[12];
  const float* a_dst2 = (const float*)d_in[13];
  const float* b2     = (const float*)d_in[14];
  const float* Wg     = (const float*)d_in[15];
  const float* bg     = (const float*)d_in[16];
  const float* Wr1    = (const float*)d_in[17];
  const float* br1    = (const float*)d_in[18];
  const float* Wr2    = (const float*)d_in[19];
  const float* br2    = (const float*)d_in[20];
  const float* Wr3    = (const float*)d_in[21];
  const float* br3    = (const float*)d_in[22];
  const float* Wf1    = (const float*)d_in[23];
  const float* bf1    = (const float*)d_in[24];
  const float* Wf2    = (const float*)d_in[25];
  const float* bf2    = (const float*)d_in[26];
  const float* Wf3    = (const float*)d_in[27];
  const float* bf3    = (const float*)d_in[28];
  const float* Wo     = (const float*)d_in[29];
  const float* bo     = (const float*)d_in[30];
  float* out = (float*)d_out;
  (void)n_in; (void)out_size; (void)ws_size;

  const int N  = in_sizes[0] / 78;
  const int E  = in_sizes[1] / 2;
  const int Bg = in_sizes[6] / 954;

  char* wsb = (char*)d_ws;
  size_t off = 0;
  auto alloc = [&](size_t bytes)->char*{
    char* p = wsb + off; off += ((bytes + 255)/256)*256; return p;
  };

  // Y region: yh (both branches) during branch phase; MLP bufs (no pre-init) alias after
  char* Yb = alloc((size_t)2*10*MPAD*96*2);
  ushort_t* yh = (ushort_t*)Yb;
  size_t yoff = 0;
  auto yalloc = [&](size_t bytes)->char*{
    char* p = Yb + yoff; yoff += ((bytes + 255)/256)*256; return p;
  };
  ushort_t* cnh  = (ushort_t*)yalloc((size_t)Bg*960*2);
  ushort_t* cnl  = (ushort_t*)yalloc((size_t)Bg*960*2);
  ushort_t* c1h  = (ushort_t*)yalloc((size_t)Bg*2048*2);
  ushort_t* c1l  = (ushort_t*)yalloc((size_t)Bg*2048*2);
  ushort_t* c2h  = (ushort_t*)yalloc((size_t)Bg*512*2);
  ushort_t* c2l  = (ushort_t*)yalloc((size_t)Bg*512*2);
  float*    c3   = (float*)   yalloc((size_t)Bg*256*4);
  ushort_t* xcnh = (ushort_t*)yalloc((size_t)Bg*512*2);
  ushort_t* xcnl = (ushort_t*)yalloc((size_t)Bg*512*2);
  ushort_t* t1h  = (ushort_t*)yalloc((size_t)Bg*1024*2);
  ushort_t* t1l  = (ushort_t*)yalloc((size_t)Bg*1024*2);
  ushort_t* t2h  = (ushort_t*)yalloc((size_t)Bg*512*2);
  ushort_t* t2l  = (ushort_t*)yalloc((size_t)Bg*512*2);
  ushort_t* t3h  = (ushort_t*)yalloc((size_t)Bg*128*2);
  ushort_t* t3l  = (ushort_t*)yalloc((size_t)Bg*128*2);
  ushort_t* pooledh = (ushort_t*)yalloc((size_t)2*Bg*128*2);
  ushort_t* pooledl = (ushort_t*)yalloc((size_t)2*Bg*128*2);
  float*    vall    = (float*)   yalloc((size_t)2*Bg*128*4);

  // zero-init region (single memset): c2f, t2f, t3f, poolKey
  size_t zElems = (size_t)Bg*512 + (size_t)Bg*512 + (size_t)Bg*128 + (size_t)2*Bg*128;
  float* zbase = (float*)alloc(zElems*4);
  float* c2f = zbase;
  float* t2f = c2f + (size_t)Bg*512;
  float* t3f = t2f + (size_t)Bg*512;
  unsigned* poolKey = (unsigned*)(t3f + (size_t)Bg*128);

  float* h2  = (float*)alloc((size_t)2*MPAD*128*4);
  float* as2 = (float*)alloc((size_t)2*MPAD*4);
  float* ad2 = (float*)alloc((size_t)2*MPAD*4);

  // transposed+split weights
  ushort_t* W1th = (ushort_t*)alloc((size_t)10*128*96*2);
  ushort_t* W1tl = (ushort_t*)alloc((size_t)10*128*96*2);
  ushort_t* W2th = (ushort_t*)alloc((size_t)128*1280*2);
  ushort_t* W2tl = (ushort_t*)alloc((size_t)128*1280*2);
  ushort_t* Wgth = (ushort_t*)alloc((size_t)128*128*2);
  ushort_t* Wgtl = (ushort_t*)alloc((size_t)128*128*2);
  ushort_t* Wr1th= (ushort_t*)alloc((size_t)2048*960*2);
  ushort_t* Wr1tl= (ushort_t*)alloc((size_t)2048*960*2);
  ushort_t* Wr2th= (ushort_t*)alloc((size_t)512*2048*2);
  ushort_t* Wr2tl= (ushort_t*)alloc((size_t)512*2048*2);
  ushort_t* Wr3th= (ushort_t*)alloc((size_t)256*512*2);
  ushort_t* Wr3tl= (ushort_t*)alloc((size_t)256*512*2);
  ushort_t* Wf1th= (ushort_t*)alloc((size_t)1024*512*2);
  ushort_t* Wf1tl= (ushort_t*)alloc((size_t)1024*512*2);
  ushort_t* Wf2th= (ushort_t*)alloc((size_t)512*1024*2);
  ushort_t* Wf2tl= (ushort_t*)alloc((size_t)512*1024*2);
  ushort_t* Wf3th= (ushort_t*)alloc((size_t)128*512*2);
  ushort_t* Wf3tl= (ushort_t*)alloc((size_t)128*512*2);
  ushort_t* Woth = (ushort_t*)alloc((size_t)64*128*2);
  ushort_t* Wotl = (ushort_t*)alloc((size_t)64*128*2);

  float* as1b = (float*)alloc((size_t)2*N*10*4);
  float* ad1b = (float*)alloc((size_t)2*N*10*4);
  float* AsB  = (float*)alloc(780*4);
  float* AdB  = (float*)alloc(780*4);
  float* vs   = (float*)alloc(1280*4);
  float* vd   = (float*)alloc(1280*4);
  int* deg2    = (int*)alloc((size_t)2*N*4);
  int* rowptr2 = (int*)alloc((size_t)2*(N+1)*4);
  int* cursor2 = (int*)alloc((size_t)2*N*4);
  int* csr2    = (int*)alloc((size_t)2*(E+N)*4);
  int* bsum    = (int*)alloc((size_t)2*64*4);

  auto gemm = [&](const ushort_t* Ah_, const ushort_t* Al_, int lda, long long sA_,
                  const ushort_t* Bh_, const ushort_t* Bl_, int ldb, long long sB_,
                  float* C_, ushort_t* Ch_, ushort_t* Cl_, int ldc, long long sC_,
                  const float* bias_, int sBias_, int M_, int N_, int K_, int batch_,
                  int act_, int mode_, int kSplit_, int aSplit_){
    dim3 grid((N_ + 63)/64, (M_ + 63)/64, batch_*kSplit_);
    gemm_split<<<grid, 256, 0, stream>>>(Ah_, Al_, lda, sA_, Bh_, Bl_, ldb, sB_,
                                         C_, Ch_, Cl_, ldc, sC_, bias_, sBias_,
                                         M_, N_, K_, act_, mode_, kSplit_, aSplit_);
  };

  // ---- init + weight prep ----
  hipMemsetAsync(zbase, 0, zElems*4, stream);
  SplitTable T;
  T.W1 = W1; T.W2 = W2; T.Wg = Wg; T.Wr1 = Wr1; T.Wr2 = Wr2; T.Wr3 = Wr3;
  T.Wf1 = Wf1; T.Wf2 = Wf2; T.Wf3 = Wf3; T.Wo = Wo;
  T.W1h = W1th; T.W1l = W1tl; T.W2h = W2th; T.W2l = W2tl; T.Wgh = Wgth; T.Wgl = Wgtl;
  T.Wr1h = Wr1th; T.Wr1l = Wr1tl; T.Wr2h = Wr2th; T.Wr2l = Wr2tl;
  T.Wr3h = Wr3th; T.Wr3l = Wr3tl; T.Wf1h = Wf1th; T.Wf1l = Wf1tl;
  T.Wf2h = Wf2th; T.Wf2l = Wf2tl; T.Wf3h = Wf3th; T.Wf3l = Wf3tl;
  T.Woh = Woth; T.Wol = Wotl;
  split_all_k<<<(1142784 + 255)/256, 256, 0, stream>>>(T);
  mkattn_k<<<(2060 + 255)/256, 256, 0, stream>>>(W1, a_src1, a_dst1, W2, a_src2, a_dst2,
                                                 AsB, AdB, vs, vd);
  alpha1b_k<<<((2*N) + 255)/256, 256, 0, stream>>>(x1, x2, AsB, AdB, as1b, ad1b, N);

  // ---- batched CSR build ----
  const int NB = (N + 1023)/1024;
  fill_int_k<<<((2*N) + 255)/256, 256, 0, stream>>>(deg2, 1, 2*N);
  hist2_k<<<((2*E) + 255)/256, 256, 0, stream>>>(ei1, ei2, E, N, deg2);
  scanA_k<<<dim3(NB, 2), 1024, 0, stream>>>(deg2, rowptr2, bsum, N);
  scanB_k<<<1, 64, 0, stream>>>(bsum, NB);
  scanC_k<<<dim3(NB, 2), 1024, 0, stream>>>(bsum, rowptr2, cursor2, N, NB, E + N);
  fill_csr2_k<<<((2*E) + 255)/256, 256, 0, stream>>>(ei1, ei2, E, N, cursor2, csr2);
  self_loop2_k<<<((2*N) + 255)/256, 256, 0, stream>>>(cursor2, csr2, E, N);

  // ---- branches (batched) ----
  gat1_agg_k<<<2*N, 64, 0, stream>>>(rowptr2, csr2, x1, x2, as1b, ad1b, yh, N, E);
  branch_conv_k<<<2*(MPAD/64), 256, 0, stream>>>(yh, W1th, W1tl, W2th, W2tl,
                                                 b1, vs, vd, h2, as2, ad2, N);
  gat2_agg_k<<<2*N, 64, 0, stream>>>(rowptr2, csr2, h2, as2, ad2, b2,
                                     batch1, batch2, poolKey, N, E, Bg);
  pool_decode_k<<<((2*Bg*128) + 255)/256, 256, 0, stream>>>(poolKey, pooledh, pooledl, 2*Bg*128);
  gemm(pooledh, pooledl, 128, 0, Wgth, Wgtl, 128, 0,
       vall, nullptr, nullptr, 128, 0, bg, 0, 2*Bg, 128, 128, 1, 1, 0, 1, 1);

  // ---- cell MLP ----
  l2norm_split_k<<<Bg, 256, 0, stream>>>(cell, 954, 960, cnh, cnl);
  gemm(cnh, cnl, 960, 0, Wr1th, Wr1tl, 960, 0, nullptr, c1h, c1l, 2048, 0,
       br1, 0, Bg, 2048, 960, 1, 1, 1, 1, 1);
  gemm(c1h, c1l, 2048, 0, Wr2th, Wr2tl, 2048, 0, c2f, nullptr, nullptr, 512, 0,
       br2, 0, Bg, 512, 2048, 1, 0, 2, 4, 1);
  act_split_k<<<((Bg*512) + 255)/256, 256, 0, stream>>>(c2f, c2h, c2l, Bg*512);
  gemm(c2h, c2l, 512, 0, Wr3th, Wr3tl, 512, 0, c3, nullptr, nullptr, 256, 0,
       br3, 0, Bg, 256, 512, 1, 1, 0, 1, 1);

  // ---- final MLP ----
  catnorm_k<<<Bg, 256, 0, stream>>>(vall, c3, xcnh, xcnl, Bg);
  gemm(xcnh, xcnl, 512, 0, Wf1th, Wf1tl, 512, 0, nullptr, t1h, t1l, 1024, 0,
       bf1, 0, Bg, 1024, 512, 1, 1, 1, 1, 1);
  gemm(t1h, t1l, 1024, 0, Wf2th, Wf2tl, 1024, 0, t2f, nullptr, nullptr, 512, 0,
       bf2, 0, Bg, 512, 1024, 1, 0, 2, 4, 1);
  act_split_k<<<((Bg*512) + 255)/256, 256, 0, stream>>>(t2f, t2h, t2l, Bg*512);
  gemm(t2h, t2l, 512, 0, Wf3th, Wf3tl, 512, 0, t3f, nullptr, nullptr, 128, 0,
       bf3, 0, Bg, 128, 512, 1, 0, 2, 4, 1);
  act_split_k<<<((Bg*128) + 255)/256, 256, 0, stream>>>(t3f, t3h, t3l, Bg*128);
  gemm(t3h, t3l, 128, 0, Woth, Wotl, 128, 0, out, nullptr, nullptr, 2, 0,
       bo, 0, Bg, 2, 128, 1, 0, 0, 1, 1);
}

// Round 10
// 563.960 us; speedup vs baseline: 5.4313x; 1.0657x over previous
//
#include <hip/hip_runtime.h>
#include <math.h>

typedef unsigned short ushort_t;
typedef __attribute__((ext_vector_type(8))) short short8;
typedef __attribute__((ext_vector_type(8))) unsigned short ushort8v;
typedef __attribute__((ext_vector_type(4))) float float4v;
typedef __attribute__((ext_vector_type(4))) unsigned short ushort4v;

#define MPAD 30016
#define H1STR 136

// ---------------- utility ----------------
__device__ __forceinline__ float lrelu02(float v){ return v > 0.f ? v : 0.2f*v; }
__device__ __forceinline__ float elu_fast(float v){ return v > 0.f ? v : (__expf(v) - 1.f); }

__device__ __forceinline__ ushort_t f2bf(float x){
  unsigned u = __float_as_uint(x);
  return (ushort_t)((u + 0x7fffu + ((u >> 16) & 1u)) >> 16);
}
__device__ __forceinline__ float bf2f(ushort_t h){ return __uint_as_float(((unsigned)h) << 16); }

// monotone float<->unsigned for atomicMax pooling
__device__ __forceinline__ unsigned encf(float f){
  unsigned u = __float_as_uint(f);
  return (u & 0x80000000u) ? ~u : (u | 0x80000000u);
}
__device__ __forceinline__ float decf(unsigned u){
  return __uint_as_float((u >> 31) ? (u & 0x7FFFFFFFu) : ~u);
}

__device__ __forceinline__ void gll16(const void* g, void* l){
  __builtin_amdgcn_global_load_lds((const __attribute__((address_space(1))) void*)g,
                                   (__attribute__((address_space(3))) void*)l, 16, 0, 0);
}

// ---------------- batched CSR build (both branches) ----------------
__global__ void hist2_k(const int* __restrict__ ei1, const int* __restrict__ ei2,
                        int E, int N, int* deg){
  int idx = blockIdx.x*blockDim.x + threadIdx.x;
  if (idx < 2*E){
    int br = idx / E, e = idx - br*E;
    const int* ei = br ? ei2 : ei1;
    atomicAdd(&deg[br*N + ei[E + e]], 1);
  }
}

__global__ __launch_bounds__(1024)
void scanA_k(const int* __restrict__ deg, int* __restrict__ rowptr, int* __restrict__ bsum, int n){
  int br = blockIdx.y;
  int t = threadIdx.x;
  int i = blockIdx.x*1024 + t;
  __shared__ int s[1024];
  int v = (i < n) ? (deg[br*n + i] + 1) : 0;   // +1 = self-loop
  s[t] = v; __syncthreads();
  for (int off = 1; off < 1024; off <<= 1){
    int x = (t >= off) ? s[t - off] : 0;
    __syncthreads();
    s[t] += x;
    __syncthreads();
  }
  if (i < n) rowptr[br*(n+1) + i] = s[t] - v;
  if (t == 1023) bsum[br*gridDim.x + blockIdx.x] = s[1023];
}

__global__ void scanB_k(int* bsum, int nb){
  int br = threadIdx.x;
  if (br < 2){
    int run = 0;
    for (int i = 0; i < nb; ++i){ int v = bsum[br*nb + i]; bsum[br*nb + i] = run; run += v; }
  }
}

__global__ __launch_bounds__(1024)
void scanC_k(const int* __restrict__ bsum, int* __restrict__ rowptr, int* __restrict__ cursor,
             int n, int nb, int total){
  int br = blockIdx.y;
  int i = blockIdx.x*1024 + threadIdx.x;
  int add = bsum[br*nb + blockIdx.x];
  if (i < n){
    int nv = rowptr[br*(n+1) + i] + add;
    rowptr[br*(n+1) + i] = nv;
    cursor[br*n + i] = nv;
  }
  if (i == 0) rowptr[br*(n+1) + n] = total;
}

// edges + self-loops in one pass (order within a row irrelevant)
__global__ void fill_csr2_k(const int* __restrict__ ei1, const int* __restrict__ ei2,
                            int E, int N, int* cursor, int* csr){
  int idx = blockIdx.x*blockDim.x + threadIdx.x;
  if (idx < 2*E){
    int br = idx / E, e = idx - br*E;
    const int* ei = br ? ei2 : ei1;
    int dst = ei[E + e];
    int pos = atomicAdd(&cursor[br*N + dst], 1);
    csr[br*(E+N) + pos] = ei[e];
  } else if (idx < 2*E + 2*N){
    int r = idx - 2*E;
    int br = r / N, i = r - br*N;
    int pos = atomicAdd(&cursor[br*N + i], 1);
    csr[br*(E+N) + pos] = i;
  }
}

// ---------------- attention score precompute (merged) ----------------
__global__ void mkattn_k(const float* __restrict__ W1, const float* __restrict__ a_src1,
                         const float* __restrict__ a_dst1,
                         const float* __restrict__ W2, const float* __restrict__ a_src2,
                         const float* __restrict__ a_dst2,
                         float* As, float* Ad, float* vs, float* vd){
  int idx = blockIdx.x*blockDim.x + threadIdx.x;
  if (idx < 780){
    int f = idx / 10, h = idx % 10;
    float ss = 0.f, sd = 0.f;
    for (int c = 0; c < 128; ++c){
      float w = W1[f*1280 + h*128 + c];
      ss += w * a_src1[h*128 + c];
      sd += w * a_dst1[h*128 + c];
    }
    As[idx] = ss; Ad[idx] = sd;
  } else if (idx < 2060){
    int k = idx - 780;
    float ss = 0.f, sd = 0.f;
    for (int c = 0; c < 128; ++c){
      float w = W2[k*128 + c];
      ss += w * a_src2[c]; sd += w * a_dst2[c];
    }
    vs[k] = ss; vd[k] = sd;
  }
}

// node-per-thread alpha1 (both branches); As/Ad staged in LDS
__global__ __launch_bounds__(256)
void alpha1b_k(const float* __restrict__ x1, const float* __restrict__ x2,
               const float* __restrict__ As, const float* __restrict__ Ad,
               float* as1, float* ad1, int n){
  __shared__ float sAs[780], sAd[780];
  int t = threadIdx.x;
  for (int k = t; k < 780; k += 256){ sAs[k] = As[k]; sAd[k] = Ad[k]; }
  __syncthreads();
  int idx = blockIdx.x*256 + t;
  if (idx >= 2*n) return;
  int br = idx / n, i = idx - br*n;
  const float* xr = (br ? x2 : x1) + (size_t)i*78;
  float ss[10], sd[10];
  #pragma unroll
  for (int h = 0; h < 10; ++h){ ss[h] = 0.f; sd[h] = 0.f; }
  for (int f = 0; f < 78; ++f){
    float xv = xr[f];
    #pragma unroll
    for (int h = 0; h < 10; ++h){
      ss[h] += xv * sAs[f*10 + h];
      sd[h] += xv * sAd[f*10 + h];
    }
  }
  #pragma unroll
  for (int h = 0; h < 10; ++h){
    as1[(size_t)idx*10 + h] = ss[h];
    ad1[(size_t)idx*10 + h] = sd[h];
  }
}

// ---------------- GATConv1 one-pass softmax + aggregate (both branches) ----------------
__global__ __launch_bounds__(64)
void gat1_agg_k(const int* __restrict__ rowptr2, const int* __restrict__ csr2,
                const float* __restrict__ x1, const float* __restrict__ x2,
                const float* __restrict__ as1b, const float* __restrict__ ad1b,
                ushort_t* __restrict__ yh, int n, int E){
  int gi = blockIdx.x;
  int br = (gi >= n) ? 1 : 0;
  int i = gi - br*n;
  int t = threadIdx.x;
  const int* rowptr = rowptr2 + (size_t)br*(n+1);
  const int* csr    = csr2 + (size_t)br*(E+n);
  const float* x    = br ? x2 : x1;
  const float* as1  = as1b + (size_t)br*n*10;
  ushort_t* yb      = yh + (size_t)br*10*MPAD*96;

  __shared__ float adi[10], rden[10], wE[10], xs[78];
  int beg = rowptr[i], end = rowptr[i+1];
  if (t < 10) adi[t] = ad1b[(size_t)gi*10 + t];
  __syncthreads();
  float den = 0.f;
  float acc[13];
  int hh[13], cc[13];
  #pragma unroll
  for (int k = 0; k < 13; ++k){
    acc[k] = 0.f;
    int j = t + 64*k;
    hh[k] = (j < 780) ? (j/78) : 0;
    cc[k] = (j < 780) ? (j%78) : 0;
  }
  for (int e = beg; e < end; ++e){
    int s = csr[e];
    if (t < 10){
      float w = __expf(lrelu02(as1[(size_t)s*10 + t] + adi[t]));
      wE[t] = w; den += w;
    }
    for (int c = t; c < 78; c += 64) xs[c] = x[(size_t)s*78 + c];
    __syncthreads();
    #pragma unroll
    for (int k = 0; k < 13; ++k){
      int j = t + 64*k;
      if (j < 780) acc[k] += wE[hh[k]] * xs[cc[k]];
    }
    __syncthreads();
  }
  if (t < 10) rden[t] = 1.f/(den + 1e-16f);
  __syncthreads();
  #pragma unroll
  for (int k = 0; k < 13; ++k){
    int j = t + 64*k;
    if (j < 780) yb[((size_t)hh[k]*MPAD + i)*96 + cc[k]] = f2bf(acc[k]*rden[hh[k]]);
  }
  for (int p = t; p < 180; p += 64){
    int h = p/18, c = 78 + p%18;
    yb[((size_t)h*MPAD + i)*96 + c] = 0;
  }
}

// ---------------- fused branch conv (both branches; bf16-hi weights; bf16 h2 out) ----------------
__global__ __launch_bounds__(256)
void branch_conv_k(const ushort_t* __restrict__ yall,
                   const ushort_t* __restrict__ W1h, const ushort_t* __restrict__ W2h,
                   const float* __restrict__ b1, const float* __restrict__ vs,
                   const float* __restrict__ vd,
                   ushort_t* __restrict__ h2all, float* __restrict__ as2all,
                   float* __restrict__ ad2all, int M){
  const int NBLK = MPAD/64;
  int br = blockIdx.x / NBLK;
  int bi = blockIdx.x - br*NBLK;
  const ushort_t* y = yall + (size_t)br*10*MPAD*96;
  ushort_t* h2 = h2all + (size_t)br*MPAD*128;
  float* as2 = as2all + (size_t)br*MPAD;
  float* ad2 = ad2all + (size_t)br*MPAD;

  __shared__ ushort_t stage[2][6144];   // [A 2048][Bh 4096]
  __shared__ ushort_t h1t[64*H1STR];
  __shared__ float red[256];

  int tid = threadIdx.x, lane = tid & 63, wave = tid >> 6;
  int row0 = bi*64;
  int wm = (wave & 1)*32, wn = (wave >> 1)*64;
  int lr = lane & 15, quad = lane >> 4;
  int sr = lane >> 2;
  int skc = (((lane & 3) ^ ((lane >> 3) & 3)) * 8);
  int qs  = (quad ^ ((lr >> 1) & 3)) * 8;

  float4v acc2[2][4];
  #pragma unroll
  for (int i = 0; i < 2; ++i)
    #pragma unroll
    for (int j = 0; j < 4; ++j)
      acc2[i][j] = (float4v){0.f, 0.f, 0.f, 0.f};
  float rps[8], rpd[8];
  #pragma unroll
  for (int z = 0; z < 8; ++z){ rps[z] = 0.f; rpd[z] = 0.f; }

  for (int h = 0; h < 10; ++h){
    const ushort_t* gA   = y   + ((size_t)h*MPAD + row0 + wave*16 + sr)*96 + skc;
    const ushort_t* gB0h = W1h + ((size_t)(h*128 + wave*32      + sr))*96 + skc;
    const ushort_t* gB1h = W1h + ((size_t)(h*128 + wave*32 + 16 + sr))*96 + skc;
    const ushort_t* gC0h = W2h + ((size_t)(wave*32      + sr))*1280 + h*128 + skc;
    const ushort_t* gC1h = W2h + ((size_t)(wave*32 + 16 + sr))*1280 + h*128 + skc;

    auto issue1 = [&](int p, int kt){
      ushort_t* st = &stage[p][0];
      gll16(gA   + kt, st + wave*512);
      gll16(gB0h + kt, st + 2048 + wave*1024);
      gll16(gB1h + kt, st + 2048 + wave*1024 + 512);
    };
    auto issue2 = [&](int p, int kt){
      ushort_t* st = &stage[p][0];
      gll16(gC0h + kt, st + 2048 + wave*1024);
      gll16(gC1h + kt, st + 2048 + wave*1024 + 512);
    };

    // ---- P1: h1e_h = y_h @ W1_h (K=96) ----
    __syncthreads();
    issue1(0, 0);
    float4v acc1[2][4];
    #pragma unroll
    for (int i = 0; i < 2; ++i)
      #pragma unroll
      for (int j = 0; j < 4; ++j)
        acc1[i][j] = (float4v){0.f, 0.f, 0.f, 0.f};
    int p = 0;
    #pragma unroll
    for (int it = 0; it < 3; ++it){
      __syncthreads();
      if (it < 2) issue1(p ^ 1, (it + 1)*32);
      const ushort_t* sm = &stage[p][0];
      short8 af[2], bhf[4];
      #pragma unroll
      for (int t2 = 0; t2 < 2; ++t2)
        af[t2] = *(const short8*)&sm[(wm + t2*16 + lr)*32 + qs];
      #pragma unroll
      for (int j = 0; j < 4; ++j)
        bhf[j] = *(const short8*)&sm[2048 + (wn + j*16 + lr)*32 + qs];
      #pragma unroll
      for (int i = 0; i < 2; ++i)
        #pragma unroll
        for (int j = 0; j < 4; ++j)
          acc1[i][j] = __builtin_amdgcn_mfma_f32_16x16x32_bf16(af[i], bhf[j], acc1[i][j], 0, 0, 0);
      p ^= 1;
    }

    // ---- ELU + bias; write h1t; accumulate alpha2 from fp32 values ----
    #pragma unroll
    for (int j = 0; j < 4; ++j){
      int col = wn + j*16 + lr;
      float bv  = b1[h*128 + col];
      float vsv = vs[h*128 + col];
      float vdv = vd[h*128 + col];
      #pragma unroll
      for (int i = 0; i < 2; ++i){
        #pragma unroll
        for (int r = 0; r < 4; ++r){
          float v = elu_fast(acc1[i][j][r] + bv);
          h1t[(wm + i*16 + quad*4 + r)*H1STR + col] = f2bf(v);
          rps[i*4 + r] += v * vsv;
          rpd[i*4 + r] += v * vdv;
        }
      }
    }
    __syncthreads();

    // ---- P2: h2 += h1e_tile @ W2[h*128:(h+1)*128, :] (K=128) ----
    issue2(0, 0);
    p = 0;
    #pragma unroll
    for (int it = 0; it < 4; ++it){
      __syncthreads();
      if (it < 3) issue2(p ^ 1, (it + 1)*32);
      const ushort_t* sm = &stage[p][0];
      int kt = it*32;
      short8 af[2], bhf[4];
      #pragma unroll
      for (int t2 = 0; t2 < 2; ++t2)
        af[t2] = *(const short8*)&h1t[(wm + t2*16 + lr)*H1STR + kt + quad*8];
      #pragma unroll
      for (int j = 0; j < 4; ++j)
        bhf[j] = *(const short8*)&sm[2048 + (wn + j*16 + lr)*32 + qs];
      #pragma unroll
      for (int i = 0; i < 2; ++i)
        #pragma unroll
        for (int j = 0; j < 4; ++j)
          acc2[i][j] = __builtin_amdgcn_mfma_f32_16x16x32_bf16(af[i], bhf[j], acc2[i][j], 0, 0, 0);
      p ^= 1;
    }
  }

  // ---- h2 store (bf16) ----
  #pragma unroll
  for (int j = 0; j < 4; ++j){
    int col = wn + j*16 + lr;
    #pragma unroll
    for (int i = 0; i < 2; ++i){
      #pragma unroll
      for (int r = 0; r < 4; ++r){
        int row = row0 + wm + i*16 + quad*4 + r;
        if (row < M) h2[(size_t)row*128 + col] = f2bf(acc2[i][j][r]);
      }
    }
  }
  // ---- alpha2 reduce ----
  __syncthreads();
  #pragma unroll
  for (int z = 0; z < 8; ++z){
    float a = rps[z], d = rpd[z];
    #pragma unroll
    for (int mk = 1; mk <= 8; mk <<= 1){
      a += __shfl_xor(a, mk);
      d += __shfl_xor(d, mk);
    }
    if (lr == 0){
      int i = z >> 2, r = z & 3;
      int row = wm + i*16 + quad*4 + r;
      red[row*2 + (wave >> 1)] = a;
      red[128 + row*2 + (wave >> 1)] = d;
    }
  }
  __syncthreads();
  if (tid < 64){
    int grow = row0 + tid;
    if (grow < M){
      as2[grow] = red[tid*2] + red[tid*2 + 1];
      ad2[grow] = red[128 + tid*2] + red[128 + tid*2 + 1];
    }
  }
}

// ---------------- GATConv2 one-pass softmax + aggregate + atomic pool (bf16 h2) ----------------
__global__ __launch_bounds__(64)
void gat2_agg_k(const int* __restrict__ rowptr2, const int* __restrict__ csr2,
                const ushort_t* __restrict__ h2all, const float* __restrict__ as2all,
                const float* __restrict__ ad2all, const float* __restrict__ b2,
                const int* __restrict__ batch1, const int* __restrict__ batch2,
                unsigned* __restrict__ poolKey, int n, int E, int Bg){
  int gi = blockIdx.x;
  int br = (gi >= n) ? 1 : 0;
  int i = gi - br*n;
  int t = threadIdx.x;
  const int* rowptr = rowptr2 + (size_t)br*(n+1);
  const int* csr    = csr2 + (size_t)br*(E+n);
  const ushort_t* h2 = h2all + (size_t)br*MPAD*128;
  const float* as2  = as2all + (size_t)br*MPAD;
  float adi = ad2all[(size_t)br*MPAD + i];
  int beg = rowptr[i], end = rowptr[i+1];
  float den = 0.f, a0 = 0.f, a1 = 0.f;
  for (int e = beg; e < end; ++e){
    int s = csr[e];
    float w = __expf(lrelu02(as2[s] + adi));
    den += w;
    unsigned u = *(const unsigned*)&h2[(size_t)s*128 + 2*t];
    a0 += w * bf2f((ushort_t)(u & 0xffffu));
    a1 += w * bf2f((ushort_t)(u >> 16));
  }
  float r = 1.f/(den + 1e-16f);
  float o0 = elu_fast(a0*r + b2[2*t]);
  float o1 = elu_fast(a1*r + b2[2*t + 1]);
  int g = (br ? batch2 : batch1)[i];
  unsigned* pk = poolKey + ((size_t)br*Bg + g)*128;
  atomicMax(&pk[2*t], encf(o0));
  atomicMax(&pk[2*t + 1], encf(o1));
}

// ---------------- pool decode → split bf16 ----------------
__global__ void pool_decode_k(const unsigned* __restrict__ key,
                              ushort_t* __restrict__ ph, ushort_t* __restrict__ pl, int n){
  int i = blockIdx.x*blockDim.x + threadIdx.x;
  if (i < n){
    float v = decf(key[i]);
    ushort_t h = f2bf(v);
    ph[i] = h; pl[i] = f2bf(v - bf2f(h));
  }
}

// ---------------- row-wise L2 normalize → split bf16 (K-padded) ----------------
__global__ __launch_bounds__(256)
void l2norm_split_k(const float* __restrict__ in, int cols, int Kp,
                    ushort_t* __restrict__ oh, ushort_t* __restrict__ ol){
  int r = blockIdx.x, t = threadIdx.x;
  __shared__ float s[256];
  __shared__ float scaleS;
  const float* rp = in + (size_t)r*cols;
  float p = 0.f;
  for (int k = t; k < cols; k += 256){ float v = rp[k]; p += v*v; }
  s[t] = p; __syncthreads();
  for (int o = 128; o > 0; o >>= 1){
    if (t < o) s[t] += s[t+o];
    __syncthreads();
  }
  if (t == 0) scaleS = 1.f / fmaxf(sqrtf(s[0]), 1e-12f);
  __syncthreads();
  float sc = scaleS;
  for (int k = t; k < Kp; k += 256){
    float v = (k < cols) ? rp[k]*sc : 0.f;
    ushort_t h = f2bf(v);
    size_t o2 = (size_t)r*Kp + k;
    oh[o2] = h; ol[o2] = f2bf(v - bf2f(h));
  }
}

// ---------------- fused concat + l2norm + split ----------------
__global__ __launch_bounds__(256)
void catnorm_k(const float* __restrict__ vall, const float* __restrict__ c3,
               ushort_t* __restrict__ oh, ushort_t* __restrict__ ol, int Bg){
  int r = blockIdx.x, t = threadIdx.x;
  __shared__ float s[256];
  __shared__ float scaleS;
  auto val = [&](int c)->float{
    if (c < 128) return vall[(size_t)r*128 + c];
    if (c < 256) return vall[((size_t)Bg + r)*128 + (c - 128)];
    return c3[(size_t)r*256 + (c - 256)];
  };
  float v0 = val(t), v1 = val(t + 256);
  s[t] = v0*v0 + v1*v1; __syncthreads();
  for (int o = 128; o > 0; o >>= 1){
    if (t < o) s[t] += s[t+o];
    __syncthreads();
  }
  if (t == 0) scaleS = 1.f / fmaxf(sqrtf(s[0]), 1e-12f);
  __syncthreads();
  float sc = scaleS;
  float a = v0*sc, b = v1*sc;
  ushort_t ha = f2bf(a), hb = f2bf(b);
  size_t o2 = (size_t)r*512;
  oh[o2 + t] = ha;       ol[o2 + t] = f2bf(a - bf2f(ha));
  oh[o2 + 256 + t] = hb; ol[o2 + 256 + t] = f2bf(b - bf2f(hb));
}

// relu + split (post split-K reduction)
__global__ void act_split_k(const float* __restrict__ in, ushort_t* __restrict__ oh,
                            ushort_t* __restrict__ ol, int n){
  int i = blockIdx.x*blockDim.x + threadIdx.x;
  if (i < n){
    float v = fmaxf(in[i], 0.f);
    ushort_t h = f2bf(v);
    oh[i] = h; ol[i] = f2bf(v - bf2f(h));
  }
}

// ---------------- merged weight transpose + split ----------------
__device__ __forceinline__ void split_one(const float* __restrict__ W, int ldw, int colStride,
                                          int N, int K, int Np, int Kp,
                                          ushort_t* __restrict__ dh, ushort_t* __restrict__ dl,
                                          int idx){
  int n  = idx % Np;
  int r  = idx / Np;
  int k4 = r % (Kp >> 2);
  int b  = r / (Kp >> 2);
  size_t o = ((size_t)b*Np + n)*Kp + (size_t)k4*4;
  ushort4v hv, lv;
  #pragma unroll
  for (int kk = 0; kk < 4; ++kk){
    int k = k4*4 + kk;
    float v = (n < N && k < K) ? W[(size_t)k*ldw + (size_t)b*colStride + n] : 0.f;
    ushort_t h = f2bf(v);
    hv[kk] = h; lv[kk] = f2bf(v - bf2f(h));
  }
  *(ushort4v*)&dh[o] = hv;
  if (dl) *(ushort4v*)&dl[o] = lv;
}

struct SplitTable {
  const float *W1, *W2, *Wg, *Wr1, *Wr2, *Wr3, *Wf1, *Wf2, *Wf3, *Wo;
  ushort_t *W1h,*W2h,*Wgh,*Wgl,*Wr1h,*Wr1l,*Wr2h,*Wr2l;
  ushort_t *Wr3h,*Wr3l,*Wf1h,*Wf1l,*Wf2h,*Wf2l,*Wf3h,*Wf3l,*Woh,*Wol;
};

__global__ void split_all_k(SplitTable T){
  int idx = blockIdx.x*blockDim.x + threadIdx.x;
  if      (idx <   30720) split_one(T.W1, 1280, 128, 128,   78,  128,   96, T.W1h, nullptr, idx);
  else if (idx <   71680) split_one(T.W2,  128,   0, 128, 1280,  128, 1280, T.W2h, nullptr, idx -   30720);
  else if (idx <   75776) split_one(T.Wg,  128,   0, 128,  128,  128,  128, T.Wgh, T.Wgl, idx -   71680);
  else if (idx <  567296) split_one(T.Wr1,2048,   0,2048,  954, 2048,  960, T.Wr1h,T.Wr1l,idx -   75776);
  else if (idx <  829440) split_one(T.Wr2, 512,   0, 512, 2048,  512, 2048, T.Wr2h,T.Wr2l,idx -  567296);
  else if (idx <  862208) split_one(T.Wr3, 256,   0, 256,  512,  256,  512, T.Wr3h,T.Wr3l,idx -  829440);
  else if (idx <  993280) split_one(T.Wf1,1024,   0,1024,  512, 1024,  512, T.Wf1h,T.Wf1l,idx -  862208);
  else if (idx < 1124352) split_one(T.Wf2, 512,   0, 512, 1024,  512, 1024, T.Wf2h,T.Wf2l,idx -  993280);
  else if (idx < 1140736) split_one(T.Wf3, 128,   0, 128,  512,  128,  512, T.Wf3h,T.Wf3l,idx - 1124352);
  else if (idx < 1142784) split_one(T.Wo,    2,   0,   2,  128,   64,  128, T.Woh, T.Wol, idx - 1140736);
}

// ---------------- split-bf16 MFMA GEMM (MLP path) ----------------
__global__ __launch_bounds__(256)
void gemm_split(const ushort_t* __restrict__ Ahp, const ushort_t* __restrict__ Alp, int lda, long long sA,
                const ushort_t* __restrict__ Bhp, const ushort_t* __restrict__ Blp, int ldb, long long sB,
                float* __restrict__ C, ushort_t* __restrict__ Ch, ushort_t* __restrict__ Cl,
                int ldc, long long sC,
                const float* __restrict__ bias, int sBias,
                int M, int Nc, int K, int act, int outMode, int kSplit, int aSplit){
  int zb = blockIdx.z;
  int b = zb / kSplit, kc = zb - b*kSplit;
  Ahp += (long long)b*sA;
  Bhp += (long long)b*sB; Blp += (long long)b*sB;
  long long cOff = (long long)b*sC;
  int Kc = K / kSplit;
  int kb = kc*Kc;
  int nIter = Kc / 32;

  __shared__ ushort_t smem[18048];

  int tid = threadIdx.x, lane = tid & 63, wave = tid >> 6;
  int row0 = blockIdx.y*64, col0 = blockIdx.x*64;
  int wm = (wave & 1)*32, wn = (wave >> 1)*32;
  int lr = lane & 15, quad = lane >> 4;
  int qs = (quad ^ ((lr >> 1) & 3)) * 8;

  int srow = wave*16 + (lane >> 2);
  int skc  = (((lane & 3) ^ ((lane >> 3) & 3)) * 8);
  const ushort_t* gAh = Ahp + (long long)(row0 + srow)*lda + skc + kb;
  const ushort_t* gAl = aSplit ? (Alp + (long long)b*sA + (long long)(row0 + srow)*lda + skc + kb) : gAh;
  const ushort_t* gBh = Bhp + (long long)(col0 + srow)*ldb + skc + kb;
  const ushort_t* gBl = Blp + (long long)(col0 + srow)*ldb + skc + kb;

  float4v acc[2][2];
  #pragma unroll
  for (int i = 0; i < 2; ++i)
    #pragma unroll
    for (int j = 0; j < 2; ++j)
      acc[i][j] = (float4v){0.f, 0.f, 0.f, 0.f};

  auto issue = [&](int p, int kt){
    ushort_t* base = &smem[p*8192 + wave*512];
    gll16(gAh + kt, base);
    if (aSplit) gll16(gAl + kt, base + 2048);
    gll16(gBh + kt, base + 4096);
    gll16(gBl + kt, base + 6144);
  };

  issue(0, 0);
  int p = 0;
  for (int it = 0; it < nIter; ++it){
    __syncthreads();
    if (it + 1 < nIter) issue(p ^ 1, (it + 1)*32);
    const ushort_t* sm = &smem[p*8192];
    short8 ah[2], al[2], bh[2], bl[2];
    #pragma unroll
    for (int t2 = 0; t2 < 2; ++t2){
      int ao = (wm + t2*16 + lr)*32 + qs;
      int bo = (wn + t2*16 + lr)*32 + qs;
      ah[t2] = *(const short8*)&sm[ao];
      if (aSplit) al[t2] = *(const short8*)&sm[2048 + ao];
      bh[t2] = *(const short8*)&sm[4096 + bo];
      bl[t2] = *(const short8*)&sm[6144 + bo];
    }
    #pragma unroll
    for (int i = 0; i < 2; ++i)
      #pragma unroll
      for (int j = 0; j < 2; ++j){
        if (aSplit)
          acc[i][j] = __builtin_amdgcn_mfma_f32_16x16x32_bf16(al[i], bh[j], acc[i][j], 0, 0, 0);
        acc[i][j] = __builtin_amdgcn_mfma_f32_16x16x32_bf16(ah[i], bl[j], acc[i][j], 0, 0, 0);
        acc[i][j] = __builtin_amdgcn_mfma_f32_16x16x32_bf16(ah[i], bh[j], acc[i][j], 0, 0, 0);
      }
    p ^= 1;
  }
  __syncthreads();

  if (outMode == 0 || outMode == 2){
    #pragma unroll
    for (int j = 0; j < 2; ++j){
      int col = col0 + wn + j*16 + lr;
      if (col >= Nc) continue;
      float bv = (bias && kc == 0) ? bias[(long long)b*sBias + col] : 0.f;
      #pragma unroll
      for (int i = 0; i < 2; ++i){
        #pragma unroll
        for (int r = 0; r < 4; ++r){
          int row = row0 + wm + i*16 + quad*4 + r;
          if (row >= M) continue;
          float v = acc[i][j][r] + bv;
          if (act == 1) v = fmaxf(v, 0.f);
          else if (act == 2) v = elu_fast(v);
          long long o = cOff + (long long)row*ldc + col;
          if (outMode == 0) C[o] = v;
          else atomicAdd(&C[o], v);
        }
      }
    }
  } else {
    float* ftile = (float*)smem;
    #pragma unroll
    for (int i = 0; i < 2; ++i)
      #pragma unroll
      for (int j = 0; j < 2; ++j)
        #pragma unroll
        for (int r = 0; r < 4; ++r)
          ftile[(wm + i*16 + quad*4 + r)*68 + wn + j*16 + lr] = acc[i][j][r];
    __syncthreads();
    int row = tid >> 2, ch = (tid & 3)*16;
    int grow = row0 + row;
    if (grow < M){
      if (col0 + 64 <= Nc){
        long long o = cOff + (long long)grow*ldc + col0 + ch;
        #pragma unroll
        for (int g = 0; g < 2; ++g){
          ushort8v hv, lv;
          #pragma unroll
          for (int c = 0; c < 8; ++c){
            int cc2 = ch + g*8 + c;
            float v = ftile[row*68 + cc2];
            if (bias) v += bias[(long long)b*sBias + col0 + cc2];
            if (act == 1) v = fmaxf(v, 0.f);
            else if (act == 2) v = elu_fast(v);
            hv[c] = f2bf(v);
            lv[c] = f2bf(v - bf2f(hv[c]));
          }
          *(ushort8v*)&Ch[o + g*8] = hv;
          *(ushort8v*)&Cl[o + g*8] = lv;
        }
      } else {
        for (int c = 0; c < 16; ++c){
          int col = col0 + ch + c;
          if (col >= Nc) break;
          float v = ftile[row*68 + ch + c];
          if (bias) v += bias[(long long)b*sBias + col];
          if (act == 1) v = fmaxf(v, 0.f);
          else if (act == 2) v = elu_fast(v);
          long long o = cOff + (long long)grow*ldc + col;
          ushort_t h = f2bf(v);
          Ch[o] = h;
          Cl[o] = f2bf(v - bf2f(h));
        }
      }
    }
  }
}

// ---------------- host launch ----------------
extern "C" void kernel_launch(void* const* d_in, const int* in_sizes, int n_in,
                              void* d_out, int out_size, void* d_ws, size_t ws_size,
                              hipStream_t stream){
  const float* x1     = (const float*)d_in[0];
  const int*   ei1    = (const int*)  d_in[1];
  const int*   batch1 = (const int*)  d_in[2];
  const float* x2     = (const float*)d_in[3];
  const int*   ei2    = (const int*)  d_in[4];
  const int*   batch2 = (const int*)  d_in[5];
  const float* cell   = (const float*)d_in[6];
  const float* W1     = (const float*)d_in[7];
  const float* a_src1 = (const float*)d_in[8];
  const float* a_dst1 = (const float*)d_in[9];
  const float* b1     = (const float*)d_in[10];
  const float* W2     = (const float*)d_in[11];
  const float* a_src2 = (const float*)d_in[12];
  const float* a_dst2 = (const float*)d_in[13];
  const float* b2     = (const float*)d_in[14];
  const float* Wg     = (const float*)d_in[15];
  const float* bg     = (const float*)d_in[16];
  const float* Wr1    = (const float*)d_in[17];
  const float* br1    = (const float*)d_in[18];
  const float* Wr2    = (const float*)d_in[19];
  const float* br2    = (const float*)d_in[20];
  const float* Wr3    = (const float*)d_in[21];
  const float* br3    = (const float*)d_in[22];
  const float* Wf1    = (const float*)d_in[23];
  const float* bf1    = (const float*)d_in[24];
  const float* Wf2    = (const float*)d_in[25];
  const float* bf2    = (const float*)d_in[26];
  const float* Wf3    = (const float*)d_in[27];
  const float* bf3    = (const float*)d_in[28];
  const float* Wo     = (const float*)d_in[29];
  const float* bo     = (const float*)d_in[30];
  float* out = (float*)d_out;
  (void)n_in; (void)out_size; (void)ws_size;

  const int N  = in_sizes[0] / 78;
  const int E  = in_sizes[1] / 2;
  const int Bg = in_sizes[6] / 954;

  char* wsb = (char*)d_ws;
  size_t off = 0;
  auto alloc = [&](size_t bytes)->char*{
    char* p = wsb + off; off += ((bytes + 255)/256)*256; return p;
  };

  // Y region: yh (both branches) during branch phase; MLP bufs alias after
  char* Yb = alloc((size_t)2*10*MPAD*96*2);
  ushort_t* yh = (ushort_t*)Yb;
  size_t yoff = 0;
  auto yalloc = [&](size_t bytes)->char*{
    char* p = Yb + yoff; yoff += ((bytes + 255)/256)*256; return p;
  };
  ushort_t* cnh  = (ushort_t*)yalloc((size_t)Bg*960*2);
  ushort_t* cnl  = (ushort_t*)yalloc((size_t)Bg*960*2);
  ushort_t* c1h  = (ushort_t*)yalloc((size_t)Bg*2048*2);
  ushort_t* c1l  = (ushort_t*)yalloc((size_t)Bg*2048*2);
  ushort_t* c2h  = (ushort_t*)yalloc((size_t)Bg*512*2);
  ushort_t* c2l  = (ushort_t*)yalloc((size_t)Bg*512*2);
  float*    c3   = (float*)   yalloc((size_t)Bg*256*4);
  ushort_t* xcnh = (ushort_t*)yalloc((size_t)Bg*512*2);
  ushort_t* xcnl = (ushort_t*)yalloc((size_t)Bg*512*2);
  ushort_t* t1h  = (ushort_t*)yalloc((size_t)Bg*1024*2);
  ushort_t* t1l  = (ushort_t*)yalloc((size_t)Bg*1024*2);
  ushort_t* t2h  = (ushort_t*)yalloc((size_t)Bg*512*2);
  ushort_t* t2l  = (ushort_t*)yalloc((size_t)Bg*512*2);
  ushort_t* t3h  = (ushort_t*)yalloc((size_t)Bg*128*2);
  ushort_t* t3l  = (ushort_t*)yalloc((size_t)Bg*128*2);
  ushort_t* pooledh = (ushort_t*)yalloc((size_t)2*Bg*128*2);
  ushort_t* pooledl = (ushort_t*)yalloc((size_t)2*Bg*128*2);
  float*    vall    = (float*)   yalloc((size_t)2*Bg*128*4);

  // zero-init region (single memset): c2f, t2f, t3f, poolKey, deg2
  size_t zElems = (size_t)Bg*512 + (size_t)Bg*512 + (size_t)Bg*128 + (size_t)2*Bg*128
                + (size_t)2*N;
  float* zbase = (float*)alloc(zElems*4);
  float* c2f = zbase;
  float* t2f = c2f + (size_t)Bg*512;
  float* t3f = t2f + (size_t)Bg*512;
  unsigned* poolKey = (unsigned*)(t3f + (size_t)Bg*128);
  int* deg2 = (int*)(poolKey + (size_t)2*Bg*128);

  ushort_t* h2 = (ushort_t*)alloc((size_t)2*MPAD*128*2);
  float* as2 = (float*)alloc((size_t)2*MPAD*4);
  float* ad2 = (float*)alloc((size_t)2*MPAD*4);

  // transposed weights: W1/W2 hi-only; MLP weights split
  ushort_t* W1th = (ushort_t*)alloc((size_t)10*128*96*2);
  ushort_t* W2th = (ushort_t*)alloc((size_t)128*1280*2);
  ushort_t* Wgth = (ushort_t*)alloc((size_t)128*128*2);
  ushort_t* Wgtl = (ushort_t*)alloc((size_t)128*128*2);
  ushort_t* Wr1th= (ushort_t*)alloc((size_t)2048*960*2);
  ushort_t* Wr1tl= (ushort_t*)alloc((size_t)2048*960*2);
  ushort_t* Wr2th= (ushort_t*)alloc((size_t)512*2048*2);
  ushort_t* Wr2tl= (ushort_t*)alloc((size_t)512*2048*2);
  ushort_t* Wr3th= (ushort_t*)alloc((size_t)256*512*2);
  ushort_t* Wr3tl= (ushort_t*)alloc((size_t)256*512*2);
  ushort_t* Wf1th= (ushort_t*)alloc((size_t)1024*512*2);
  ushort_t* Wf1tl= (ushort_t*)alloc((size_t)1024*512*2);
  ushort_t* Wf2th= (ushort_t*)alloc((size_t)512*1024*2);
  ushort_t* Wf2tl= (ushort_t*)alloc((size_t)512*1024*2);
  ushort_t* Wf3th= (ushort_t*)alloc((size_t)128*512*2);
  ushort_t* Wf3tl= (ushort_t*)alloc((size_t)128*512*2);
  ushort_t* Woth = (ushort_t*)alloc((size_t)64*128*2);
  ushort_t* Wotl = (ushort_t*)alloc((size_t)64*128*2);

  float* as1b = (float*)alloc((size_t)2*N*10*4);
  float* ad1b = (float*)alloc((size_t)2*N*10*4);
  float* AsB  = (float*)alloc(780*4);
  float* AdB  = (float*)alloc(780*4);
  float* vs   = (float*)alloc(1280*4);
  float* vd   = (float*)alloc(1280*4);
  int* rowptr2 = (int*)alloc((size_t)2*(N+1)*4);
  int* cursor2 = (int*)alloc((size_t)2*N*4);
  int* csr2    = (int*)alloc((size_t)2*(E+N)*4);
  int* bsum    = (int*)alloc((size_t)2*64*4);

  auto gemm = [&](const ushort_t* Ah_, const ushort_t* Al_, int lda, long long sA_,
                  const ushort_t* Bh_, const ushort_t* Bl_, int ldb, long long sB_,
                  float* C_, ushort_t* Ch_, ushort_t* Cl_, int ldc, long long sC_,
                  const float* bias_, int sBias_, int M_, int N_, int K_, int batch_,
                  int act_, int mode_, int kSplit_, int aSplit_){
    dim3 grid((N_ + 63)/64, (M_ + 63)/64, batch_*kSplit_);
    gemm_split<<<grid, 256, 0, stream>>>(Ah_, Al_, lda, sA_, Bh_, Bl_, ldb, sB_,
                                         C_, Ch_, Cl_, ldc, sC_, bias_, sBias_,
                                         M_, N_, K_, act_, mode_, kSplit_, aSplit_);
  };

  // ---- init + weight prep ----
  hipMemsetAsync(zbase, 0, zElems*4, stream);
  SplitTable T;
  T.W1 = W1; T.W2 = W2; T.Wg = Wg; T.Wr1 = Wr1; T.Wr2 = Wr2; T.Wr3 = Wr3;
  T.Wf1 = Wf1; T.Wf2 = Wf2; T.Wf3 = Wf3; T.Wo = Wo;
  T.W1h = W1th; T.W2h = W2th; T.Wgh = Wgth; T.Wgl = Wgtl;
  T.Wr1h = Wr1th; T.Wr1l = Wr1tl; T.Wr2h = Wr2th; T.Wr2l = Wr2tl;
  T.Wr3h = Wr3th; T.Wr3l = Wr3tl; T.Wf1h = Wf1th; T.Wf1l = Wf1tl;
  T.Wf2h = Wf2th; T.Wf2l = Wf2tl; T.Wf3h = Wf3th; T.Wf3l = Wf3tl;
  T.Woh = Woth; T.Wol = Wotl;
  split_all_k<<<(1142784 + 255)/256, 256, 0, stream>>>(T);
  mkattn_k<<<(2060 + 255)/256, 256, 0, stream>>>(W1, a_src1, a_dst1, W2, a_src2, a_dst2,
                                                 AsB, AdB, vs, vd);
  alpha1b_k<<<((2*N) + 255)/256, 256, 0, stream>>>(x1, x2, AsB, AdB, as1b, ad1b, N);

  // ---- batched CSR build ----
  const int NB = (N + 1023)/1024;
  hist2_k<<<((2*E) + 255)/256, 256, 0, stream>>>(ei1, ei2, E, N, deg2);
  scanA_k<<<dim3(NB, 2), 1024, 0, stream>>>(deg2, rowptr2, bsum, N);
  scanB_k<<<1, 64, 0, stream>>>(bsum, NB);
  scanC_k<<<dim3(NB, 2), 1024, 0, stream>>>(bsum, rowptr2, cursor2, N, NB, E + N);
  fill_csr2_k<<<((2*E + 2*N) + 255)/256, 256, 0, stream>>>(ei1, ei2, E, N, cursor2, csr2);

  // ---- branches (batched) ----
  gat1_agg_k<<<2*N, 64, 0, stream>>>(rowptr2, csr2, x1, x2, as1b, ad1b, yh, N, E);
  branch_conv_k<<<2*(MPAD/64), 256, 0, stream>>>(yh, W1th, W2th,
                                                 b1, vs, vd, h2, as2, ad2, N);
  gat2_agg_k<<<2*N, 64, 0, stream>>>(rowptr2, csr2, h2, as2, ad2, b2,
                                     batch1, batch2, poolKey, N, E, Bg);
  pool_decode_k<<<((2*Bg*128) + 255)/256, 256, 0, stream>>>(poolKey, pooledh, pooledl, 2*Bg*128);
  gemm(pooledh, pooledl, 128, 0, Wgth, Wgtl, 128, 0,
       vall, nullptr, nullptr, 128, 0, bg, 0, 2*Bg, 128, 128, 1, 1, 0, 1, 1);

  // ---- cell MLP ----
  l2norm_split_k<<<Bg, 256, 0, stream>>>(cell, 954, 960, cnh, cnl);
  gemm(cnh, cnl, 960, 0, Wr1th, Wr1tl, 960, 0, nullptr, c1h, c1l, 2048, 0,
       br1, 0, Bg, 2048, 960, 1, 1, 1, 1, 1);
  gemm(c1h, c1l, 2048, 0, Wr2th, Wr2tl, 2048, 0, c2f, nullptr, nullptr, 512, 0,
       br2, 0, Bg, 512, 2048, 1, 0, 2, 4, 1);
  act_split_k<<<((Bg*512) + 255)/256, 256, 0, stream>>>(c2f, c2h, c2l, Bg*512);
  gemm(c2h, c2l, 512, 0, Wr3th, Wr3tl, 512, 0, c3, nullptr, nullptr, 256, 0,
       br3, 0, Bg, 256, 512, 1, 1, 0, 1, 1);

  // ---- final MLP ----
  catnorm_k<<<Bg, 256, 0, stream>>>(vall, c3, xcnh, xcnl, Bg);
  gemm(xcnh, xcnl, 512, 0, Wf1th, Wf1tl, 512, 0, nullptr, t1h, t1l, 1024, 0,
       bf1, 0, Bg, 1024, 512, 1, 1, 1, 1, 1);
  gemm(t1h, t1l, 1024, 0, Wf2th, Wf2tl, 1024, 0, t2f, nullptr, nullptr, 512, 0,
       bf2, 0, Bg, 512, 1024, 1, 0, 2, 4, 1);
  act_split_k<<<((Bg*512) + 255)/256, 256, 0, stream>>>(t2f, t2h, t2l, Bg*512);
  gemm(t2h, t2l, 512, 0, Wf3th, Wf3tl, 512, 0, t3f, nullptr, nullptr, 128, 0,
       bf3, 0, Bg, 128, 512, 1, 0, 2, 4, 1);
  act_split_k<<<((Bg*128) + 255)/256, 256, 0, stream>>>(t3f, t3h, t3l, Bg*128);
  gemm(t3h, t3l, 128, 0, Woth, Wotl, 128, 0, out, nullptr, nullptr, 2, 0,
       bo, 0, Bg, 2, 128, 1, 0, 0, 1, 1);
}